// Round 3
// baseline (886.318 us; speedup 1.0000x reference)
//
#include <hip/hip_runtime.h>
#include <hip/hip_bf16.h>
#include <math.h>

// TimeBERT forward on MI355X.
// Inputs arrive fp32 (reference dtype); we keep a runtime dtype detector as
// insurance (converts bf16->fp32 if the dataset ever casts). All internal math
// fp32. OUTPUT IS FP32: [cls_pooling (8,128) | last_hidden (8,512,128)].

static constexpr int B_ = 8, L_ = 512, DIM_ = 8, ET_ = 128, HID_ = 128, H_ = 2;

using bf = __hip_bfloat16;

__device__ __forceinline__ float wave_reduce_sum(float v) {
    #pragma unroll
    for (int off = 32; off >= 1; off >>= 1) v += __shfl_xor(v, off);
    return v;
}
__device__ __forceinline__ float wave_reduce_max(float v) {
    #pragma unroll
    for (int off = 32; off >= 1; off >>= 1) v = fmaxf(v, __shfl_xor(v, off));
    return v;
}

// ---------------------------------------------------------------------------
// dtype detection: ln1_g == ones. bf16 ones -> u16[0]=0x3F80; fp32 ones ->
// u16[0]=0x0000 (LE low half of 0x3F800000).
__global__ void detect_kernel(const unsigned short* ln1_g_raw, int* flag) {
    if (threadIdx.x == 0 && blockIdx.x == 0)
        *flag = (ln1_g_raw[0] == 0x3F80u) ? 1 : 0;
}

struct ConvArgs {
    const void* src[32];
    int n[32];
    int dstoff[32];
};
__global__ void convert_inputs_kernel(ConvArgs a, float* dst, const int* flag) {
    int which = blockIdx.y;
    int n = a.n[which];
    int i = blockIdx.x * 256 + threadIdx.x;
    if (i >= n) return;
    float v;
    if (*flag) v = __bfloat162float(((const bf*)a.src[which])[i]);
    else       v = ((const float*)a.src[which])[i];
    dst[a.dstoff[which] + i] = v;
}

// ---------------------------------------------------------------------------
__global__ void time_emb_kernel(const float* ts, const float* w_per, const float* b_per,
                                const float* w_lin, const float* b_lin,
                                float* out, int cls_mode) {
    int row = blockIdx.x, j = threadIdx.x;  // 128 threads
    float t = cls_mode ? (float)row * (1.0f / 127.0f) : ts[row];
    float v;
    if (j == 0) v = t * w_lin[0] + b_lin[0];
    else        v = sinf(t * w_per[j - 1] + b_per[j - 1]);
    out[row * 128 + j] = v;
}

// ---------------------------------------------------------------------------
// C[m,n] = act( A[m,:K] @ W[K,128] + bias[n] ); one block per row, 128 threads.
__global__ void gemm_bias_kernel(const float* A, int lda, const float* W, const float* bias,
                                 float* C, int ldc, int K, int act) {
    __shared__ float a[128];
    int m = blockIdx.x, n = threadIdx.x;
    if (n < K) a[n] = A[(size_t)m * lda + n];
    __syncthreads();
    float acc = bias[n];
    for (int k = 0; k < K; ++k) acc = fmaf(a[k], W[(size_t)k * 128 + n], acc);
    if (act == 1) acc = fmaxf(acc, 0.f);
    C[(size_t)m * ldc + n] = acc;
}

// ---------------------------------------------------------------------------
// mta attention: per (qi,h,b) block, 256 threads.
// x: fp32 (B,512,16) — cols 0..15 values, cols 8..15 masks {0,1}.
// att out: (B, Lq, 32), layout [b,qi, h*16 + d].
__global__ void mta_att_kernel(const float* qp, int q_batched, const float* kp,
                               const float* x, float* att, int Lq) {
    int qi = blockIdx.x, h = blockIdx.y, b = blockIdx.z;
    int tid = threadIdx.x;  // 256
    __shared__ float qv[64];
    __shared__ float ek[512];
    __shared__ float xv[512 * 17];  // padded stride 17
    __shared__ float redm[4];

    const float* qrow = qp + ((size_t)(q_batched ? (b * Lq + qi) : qi)) * 128 + h * 64;
    if (tid < 64) qv[tid] = qrow[tid] * 0.125f;  // fold 1/sqrt(64)
    for (int idx = tid; idx < 512 * 16; idx += 256) {
        int k = idx >> 4, c = idx & 15;
        xv[k * 17 + c] = x[(size_t)b * 8192 + idx];
    }
    __syncthreads();

    int k0 = tid, k1 = tid + 256;
    const float* kr0 = kp + ((size_t)(b * 512 + k0)) * 128 + h * 64;
    const float* kr1 = kp + ((size_t)(b * 512 + k1)) * 128 + h * 64;
    float s0 = 0.f, s1 = 0.f;
    #pragma unroll
    for (int j = 0; j < 64; ++j) {
        s0 = fmaf(qv[j], kr0[j], s0);
        s1 = fmaf(qv[j], kr1[j], s1);
    }
    // global max — ratio-identical to reference's per-d masked softmax
    float lm = wave_reduce_max(fmaxf(s0, s1));
    if ((tid & 63) == 0) redm[tid >> 6] = lm;
    __syncthreads();
    float M = fmaxf(fmaxf(redm[0], redm[1]), fmaxf(redm[2], redm[3]));
    ek[k0] = expf(s0 - M);
    ek[k1] = expf(s1 - M);
    __syncthreads();

    int lane = tid & 63, wave = tid >> 6;
    int d = wave * 4 + (lane >> 4);
    int sub = lane & 15;
    int dm = 8 + (d & 7);
    float num = 0.f, den = 0.f;
    for (int k = sub; k < 512; k += 16) {
        float e = ek[k];
        float m = xv[k * 17 + dm];
        float v = xv[k * 17 + d];
        float em = e * m;
        den += em;
        num = fmaf(em, v, num);
    }
    #pragma unroll
    for (int off = 8; off >= 1; off >>= 1) {
        num += __shfl_xor(num, off);
        den += __shfl_xor(den, off);
    }
    if (sub == 0) att[((size_t)(b * Lq + qi)) * 32 + h * 16 + d] = num / den;
}

// ---------------------------------------------------------------------------
__global__ void tb_att_kernel(const float* qp, const float* kp, const float* vp,
                              float* outp, int Lq) {
    int qi = blockIdx.x, h = blockIdx.y, b = blockIdx.z;
    int lane = threadIdx.x;  // 64
    __shared__ float qv[64];
    __shared__ float ek[513];
    size_t rowq = ((size_t)(b * Lq + qi)) * 128 + h * 64;
    qv[lane] = qp[rowq + lane] * 0.125f;
    __syncthreads();
    float smax = -1e30f;
    for (int k = lane; k < Lq; k += 64) {
        const float* kr = kp + ((size_t)(b * Lq + k)) * 128 + h * 64;
        float s = 0.f;
        #pragma unroll
        for (int j = 0; j < 64; ++j) s = fmaf(qv[j], kr[j], s);
        ek[k] = s;
        smax = fmaxf(smax, s);
    }
    smax = wave_reduce_max(smax);
    float ssum = 0.f;
    for (int k = lane; k < Lq; k += 64) {
        float e = expf(ek[k] - smax);
        ek[k] = e;
        ssum += e;
    }
    ssum = wave_reduce_sum(ssum);
    __syncthreads();
    float acc = 0.f;
    for (int k = 0; k < Lq; ++k)
        acc = fmaf(ek[k], vp[((size_t)(b * Lq + k)) * 128 + h * 64 + lane], acc);
    outp[rowq + lane] = acc / ssum;
}

// ---------------------------------------------------------------------------
__global__ void add_ln_kernel(const float* xin, const float* resid,
                              const float* g, const float* bt, float* out) {
    int row = blockIdx.x, j = threadIdx.x;
    size_t off = (size_t)row * 128 + j;
    float v = xin[off] + resid[off];
    __shared__ float red[2];
    int wave = j >> 6, lane = j & 63;
    float s = wave_reduce_sum(v);
    if (lane == 0) red[wave] = s;
    __syncthreads();
    float mean = (red[0] + red[1]) * 0.0078125f;
    float d = v - mean;
    __syncthreads();
    float s2 = wave_reduce_sum(d * d);
    if (lane == 0) red[wave] = s2;
    __syncthreads();
    float var = (red[0] + red[1]) * 0.0078125f;
    out[off] = d * rsqrtf(var + 1e-5f) * g[j] + bt[j];
}

// ---------------------------------------------------------------------------
__global__ void assemble_kernel(float* dst, const float* cls_emb, const float* body,
                                const float* pos, int Lbody, int use_pos) {
    int r = blockIdx.x;   // 0..Lbody
    int b = blockIdx.y;
    int j = threadIdx.x;  // 128
    float v = (r == 0) ? cls_emb[j] : body[((size_t)b * Lbody + (r - 1)) * 128 + j];
    if (use_pos) v += pos[r * 128 + j];
    dst[((size_t)b * (Lbody + 1) + r) * 128 + j] = v;
}

// ---------------------------------------------------------------------------
// FP32 output: out[0:1024] = tanh(clsraw); out[1024:] = h2 body rows.
__global__ void finalize_kernel(const float* clsraw, const float* h2, float* out, int total) {
    int idx = blockIdx.x * 256 + threadIdx.x;
    if (idx >= total) return;
    float v;
    if (idx < 1024) {
        v = tanhf(clsraw[idx]);
    } else {
        int t = idx - 1024;
        int b = t >> 16;          // /(512*128)
        int rem = t & 65535;
        int i = rem >> 7, j = rem & 127;
        v = h2[((size_t)(b * 513 + 1 + i)) * 128 + j];
    }
    out[idx] = v;
}

// ---------------------------------------------------------------------------
extern "C" void kernel_launch(void* const* d_in, const int* in_sizes, int n_in,
                              void* d_out, int out_size, void* d_ws, size_t ws_size,
                              hipStream_t stream) {
    float* w = (float*)d_ws;
    size_t off = 0;
    auto alloc = [&](size_t n) { float* p = w + off; off += n; return p; };

    int* flag = (int*)alloc(1);

    ConvArgs ca;
    int nn = n_in < 32 ? n_in : 32;
    int max_n = 0;
    float* fin[32];
    for (int i = 0; i < nn; ++i) {
        ca.src[i] = d_in[i];
        ca.n[i] = in_sizes[i];
        fin[i] = alloc(in_sizes[i]);
        ca.dstoff[i] = (int)(fin[i] - w);
        if (in_sizes[i] > max_n) max_n = in_sizes[i];
    }
    for (int i = nn; i < 32; ++i) { ca.src[i] = nullptr; ca.n[i] = 0; ca.dstoff[i] = 0; }

    const float* x     = fin[0];
    const float* ts    = fin[1];
    const float* w_per = fin[2];  const float* b_per = fin[3];
    const float* w_lin = fin[4];  const float* b_lin = fin[5];
    const float* Wq_t  = fin[6];  const float* bq_t  = fin[7];
    const float* Wk_t  = fin[8];  const float* bk_t  = fin[9];
    const float* Wo_t  = fin[10]; const float* bo_t  = fin[11];
    const float* pos_emb = fin[12]; const float* cls_emb = fin[13];
    const float* tWq = fin[14]; const float* tbq = fin[15];
    const float* tWk = fin[16]; const float* tbk = fin[17];
    const float* tWv = fin[18]; const float* tbv = fin[19];
    const float* tWo = fin[20]; const float* tbo = fin[21];
    const float* ln1_g = fin[22]; const float* ln1_b = fin[23];
    const float* fW1 = fin[24]; const float* fb1 = fin[25];
    const float* fW2 = fin[26]; const float* fb2 = fin[27];
    const float* ln2_g = fin[28]; const float* ln2_b = fin[29];
    const float* pW = fin[30]; const float* pb = fin[31];

    float* key_e   = alloc(4096 * 128);
    float* cls_e   = alloc(128 * 128);
    float* qp_main = alloc(4096 * 128);
    float* kp_main = alloc(4096 * 128);
    float* qp_cls  = alloc(128 * 128);
    float* att_cls = alloc(8 * 128 * 32);
    float* att_mn  = alloc(8 * 512 * 32);
    float* mta_cls = key_e;    // alias: key_e dead after projections
    float* mta_out = qp_main;  // alias: qp_main dead after mta attention
    float* xin_c   = alloc(8 * 129 * 128);
    float* xin_m   = alloc(8 * 513 * 128);
    float* tb_q    = alloc(8 * 513 * 128);
    float* tb_k    = alloc(8 * 513 * 128);
    float* tb_v    = alloc(8 * 513 * 128);
    float* tb_a    = alloc(8 * 513 * 128);
    float* tb_o    = tb_q;     // alias: tb_q dead after tb_att
    float* tb_x1   = alloc(8 * 513 * 128);
    float* tb_f1   = tb_k;     // alias
    float* tb_f2   = tb_v;     // alias
    float* x2_c    = alloc(8 * 129 * 128);
    float* x2_m    = alloc(8 * 513 * 128);
    float* clsraw  = alloc(8 * 128);
    (void)ws_size;

    detect_kernel<<<1, 1, 0, stream>>>((const unsigned short*)d_in[22], flag);
    convert_inputs_kernel<<<dim3((max_n + 255) / 256, 32), 256, 0, stream>>>(ca, w, flag);

    auto gemm = [&](const float* A, int lda, const float* W, const float* bias,
                    float* C, int ldc, int Mrows, int K, int act) {
        gemm_bias_kernel<<<Mrows, 128, 0, stream>>>(A, lda, W, bias, C, ldc, K, act);
    };

    time_emb_kernel<<<4096, 128, 0, stream>>>(ts, w_per, b_per, w_lin, b_lin, key_e, 0);
    time_emb_kernel<<<128, 128, 0, stream>>>(ts, w_per, b_per, w_lin, b_lin, cls_e, 1);

    gemm(key_e, 128, Wk_t, bk_t, kp_main, 128, 4096, 128, 0);
    gemm(key_e, 128, Wq_t, bq_t, qp_main, 128, 4096, 128, 0);
    gemm(cls_e, 128, Wq_t, bq_t, qp_cls, 128, 128, 128, 0);

    mta_att_kernel<<<dim3(128, 2, 8), 256, 0, stream>>>(qp_cls, 0, kp_main, x, att_cls, 128);
    mta_att_kernel<<<dim3(512, 2, 8), 256, 0, stream>>>(qp_main, 1, kp_main, x, att_mn, 512);

    gemm(att_cls, 32, Wo_t, bo_t, mta_cls, 128, 8 * 128, 32, 0);
    gemm(att_mn, 32, Wo_t, bo_t, mta_out, 128, 8 * 512, 32, 0);

    assemble_kernel<<<dim3(129, 8), 128, 0, stream>>>(xin_c, cls_emb, mta_cls, pos_emb, 128, 0);
    assemble_kernel<<<dim3(513, 8), 128, 0, stream>>>(xin_m, cls_emb, mta_out, pos_emb, 512, 1);

    auto tblock = [&](const float* xin, float* x2, int Lq) {
        int Mr = 8 * Lq;
        gemm(xin, 128, tWq, tbq, tb_q, 128, Mr, 128, 0);
        gemm(xin, 128, tWk, tbk, tb_k, 128, Mr, 128, 0);
        gemm(xin, 128, tWv, tbv, tb_v, 128, Mr, 128, 0);
        tb_att_kernel<<<dim3(Lq, 2, 8), 64, 0, stream>>>(tb_q, tb_k, tb_v, tb_a, Lq);
        gemm(tb_a, 128, tWo, tbo, tb_o, 128, Mr, 128, 0);
        add_ln_kernel<<<Mr, 128, 0, stream>>>(xin, tb_o, ln1_g, ln1_b, tb_x1);
        gemm(tb_x1, 128, fW1, fb1, tb_f1, 128, Mr, 128, 1);
        gemm(tb_f1, 128, fW2, fb2, tb_f2, 128, Mr, 128, 0);
        add_ln_kernel<<<Mr, 128, 0, stream>>>(tb_x1, tb_f2, ln2_g, ln2_b, x2);
    };

    tblock(xin_c, x2_c, 129);
    tblock(xin_m, x2_m, 513);

    gemm(x2_c, 129 * 128, pW, pb, clsraw, 128, 8, 128, 0);

    finalize_kernel<<<(out_size + 255) / 256, 256, 0, stream>>>(clsraw, x2_m, (float*)d_out, out_size);
}

// Round 4
// 726.806 us; speedup vs baseline: 1.2195x; 1.2195x over previous
//
#include <hip/hip_runtime.h>
#include <hip/hip_bf16.h>
#include <math.h>

// TimeBERT forward on MI355X. Inputs fp32 (runtime bf16 detector kept as
// insurance). Internal math fp32. OUTPUT FP32:
// [cls_pooling (8,128) | last_hidden (8,512,128)].
//
// R4: tiled attention kernels (LDS-staged K/V, coalesced) replacing the
// lane-walks-a-row pattern that left tb_att at 320us with VALUBusy=8%.
// GEMMs: 16 rows/block, A-tile in LDS, float4 weight loads.

static constexpr int B_ = 8, L_ = 512, DIM_ = 8, ET_ = 128, HID_ = 128, H_ = 2;

using bf = __hip_bfloat16;

__device__ __forceinline__ float wave_reduce_sum(float v) {
    #pragma unroll
    for (int off = 32; off >= 1; off >>= 1) v += __shfl_xor(v, off);
    return v;
}
__device__ __forceinline__ float wave_reduce_max(float v) {
    #pragma unroll
    for (int off = 32; off >= 1; off >>= 1) v = fmaxf(v, __shfl_xor(v, off));
    return v;
}

// ---------------------------------------------------------------------------
__global__ void detect_kernel(const unsigned short* ln1_g_raw, int* flag) {
    if (threadIdx.x == 0 && blockIdx.x == 0)
        *flag = (ln1_g_raw[0] == 0x3F80u) ? 1 : 0;
}

struct ConvArgs {
    const void* src[32];
    int n[32];
    int dstoff[32];
};
__global__ void convert_inputs_kernel(ConvArgs a, float* dst, const int* flag) {
    int which = blockIdx.y;
    int n = a.n[which];
    int i = blockIdx.x * 256 + threadIdx.x;
    if (i >= n) return;
    float v;
    if (*flag) v = __bfloat162float(((const bf*)a.src[which])[i]);
    else       v = ((const float*)a.src[which])[i];
    dst[a.dstoff[which] + i] = v;
}

// ---------------------------------------------------------------------------
__global__ void time_emb_kernel(const float* ts, const float* w_per, const float* b_per,
                                const float* w_lin, const float* b_lin,
                                float* out, int cls_mode) {
    int row = blockIdx.x, j = threadIdx.x;  // 128 threads
    float t = cls_mode ? (float)row * (1.0f / 127.0f) : ts[row];
    float v;
    if (j == 0) v = t * w_lin[0] + b_lin[0];
    else        v = sinf(t * w_per[j - 1] + b_per[j - 1]);
    out[row * 128 + j] = v;
}

// ---------------------------------------------------------------------------
// GEMM: C[m,n] = act(A[m,:K] @ W[K,128] + bias[n]), 16 rows/block, 256 thr.
// Thread (r = tid>>4, g = tid&15) computes cols g*8..g*8+7 of row m0+r.
__global__ void gemm16_kernel(const float* A, int lda, const float* W, const float* bias,
                              float* C, int ldc, int M, int K, int act) {
    __shared__ float As[16][132];
    int m0 = blockIdx.x * 16;
    int tid = threadIdx.x;
    int r = tid >> 4, g = tid & 15, c0 = g * 8;
    // stage A tile (rows guarded)
    for (int c = g; c < K; c += 16) {
        float v = 0.f;
        if (m0 + r < M) v = A[(size_t)(m0 + r) * lda + c];
        As[r][c] = v;
    }
    __syncthreads();
    float acc[8];
    #pragma unroll
    for (int j = 0; j < 8; ++j) acc[j] = bias[c0 + j];
    for (int k = 0; k < K; ++k) {
        float a = As[r][k];
        const float4 w0 = *(const float4*)(W + (size_t)k * 128 + c0);
        const float4 w1 = *(const float4*)(W + (size_t)k * 128 + c0 + 4);
        acc[0] = fmaf(a, w0.x, acc[0]); acc[1] = fmaf(a, w0.y, acc[1]);
        acc[2] = fmaf(a, w0.z, acc[2]); acc[3] = fmaf(a, w0.w, acc[3]);
        acc[4] = fmaf(a, w1.x, acc[4]); acc[5] = fmaf(a, w1.y, acc[5]);
        acc[6] = fmaf(a, w1.z, acc[6]); acc[7] = fmaf(a, w1.w, acc[7]);
    }
    if (act == 1) {
        #pragma unroll
        for (int j = 0; j < 8; ++j) acc[j] = fmaxf(acc[j], 0.f);
    }
    if (m0 + r < M) {
        float4 o0 = make_float4(acc[0], acc[1], acc[2], acc[3]);
        float4 o1 = make_float4(acc[4], acc[5], acc[6], acc[7]);
        *(float4*)(C + (size_t)(m0 + r) * ldc + c0) = o0;
        *(float4*)(C + (size_t)(m0 + r) * ldc + c0 + 4) = o1;
    }
}

// ---------------------------------------------------------------------------
// mta attention, tiled: block = 256 thr handles (b, h, 8 q-rows).
// Keys always 512. x: (B,512,16) cols 0..15 values, 8..15 masks {0,1}.
// att out: (B, Lq, 32), [b,qi, h*16+d].
__global__ void mta_att_kernel(const float* qp, int q_batched, const float* kp,
                               const float* x, float* att, int Lq) {
    int qt = blockIdx.x, h = blockIdx.y, b = blockIdx.z;
    int tid = threadIdx.x;  // 256
    __shared__ float qs[8][64];
    __shared__ float ks[64][65];
    __shared__ float s[8][520];
    __shared__ float xv[512 * 17];
    int q0 = qt * 8;

    for (int i = tid; i < 8 * 64; i += 256) {
        int r = i >> 6, c = i & 63;
        int qr = q0 + r;
        const float* qrow = qp + ((size_t)(q_batched ? (b * Lq + qr) : qr)) * 128 + h * 64;
        qs[r][c] = qrow[c] * 0.125f;
    }
    for (int idx = tid; idx < 512 * 16; idx += 256) {
        int k = idx >> 4, c = idx & 15;
        xv[k * 17 + c] = x[(size_t)b * 8192 + idx];
    }
    __syncthreads();

    // scores: 8 K-tiles of 64
    for (int kt = 0; kt < 8; ++kt) {
        int k0 = kt * 64;
        for (int i = tid; i < 64 * 64; i += 256) {
            int r = i >> 6, c = i & 63;
            ks[r][c] = kp[((size_t)(b * 512 + k0 + r)) * 128 + h * 64 + c];
        }
        __syncthreads();
        for (int i = tid; i < 8 * 64; i += 256) {
            int r = i >> 6, kk = i & 63;
            float acc = 0.f;
            #pragma unroll
            for (int e = 0; e < 64; ++e) acc = fmaf(qs[r][e], ks[kk][e], acc);
            s[r][k0 + kk] = acc;
        }
        __syncthreads();
    }

    // per-row max + exp (ratio-identical to ref's per-d masked softmax)
    int wv = tid >> 6, lane = tid & 63;
    for (int r = wv; r < 8; r += 4) {
        float m = -1e30f;
        for (int k = lane; k < 512; k += 64) m = fmaxf(m, s[r][k]);
        m = wave_reduce_max(m);
        for (int k = lane; k < 512; k += 64) s[r][k] = expf(s[r][k] - m);
    }
    __syncthreads();

    // per-d masked sums: d = tid>>4 (16), sub = tid&15
    int d = tid >> 4, sub = tid & 15;
    int dm = 8 + (d & 7);
    for (int q = 0; q < 8; ++q) {
        float num = 0.f, den = 0.f;
        for (int k = sub; k < 512; k += 16) {
            float e = s[q][k];
            float mk = xv[k * 17 + dm];
            float vv = xv[k * 17 + d];
            float em = e * mk;
            den += em;
            num = fmaf(em, vv, num);
        }
        #pragma unroll
        for (int off2 = 8; off2 >= 1; off2 >>= 1) {
            num += __shfl_xor(num, off2);
            den += __shfl_xor(den, off2);
        }
        if (sub == 0) att[((size_t)(b * Lq + q0 + q)) * 32 + h * 16 + d] = num / den;
    }
}

// ---------------------------------------------------------------------------
// tblock attention, tiled two-pass: block = 256 thr handles (b, h, 16 q-rows).
// Lq up to 513 -> score buffer padded to 584.
__global__ void tb_att_kernel(const float* qp, const float* kp, const float* vp,
                              float* outp, int Lq) {
    int qt = blockIdx.x, h = blockIdx.y, b = blockIdx.z;
    int tid = threadIdx.x;  // 256
    __shared__ float qs[16][64];
    __shared__ float s[16][584];
    __shared__ float kv[64][65];
    int q0 = qt * 16;
    int nkt = (Lq + 63) >> 6;

    for (int i = tid; i < 16 * 64; i += 256) {
        int r = i >> 6, c = i & 63;
        int qr = q0 + r;
        float v = 0.f;
        if (qr < Lq) v = qp[((size_t)(b * Lq + qr)) * 128 + h * 64 + c] * 0.125f;
        qs[r][c] = v;
    }
    __syncthreads();

    // pass A: scores
    for (int kt = 0; kt < nkt; ++kt) {
        int k0 = kt * 64;
        for (int i = tid; i < 64 * 64; i += 256) {
            int r = i >> 6, c = i & 63;
            int krow = k0 + r;
            kv[r][c] = (krow < Lq) ? kp[((size_t)(b * Lq + krow)) * 128 + h * 64 + c] : 0.f;
        }
        __syncthreads();
        for (int i = tid; i < 16 * 64; i += 256) {
            int r = i >> 6, kk = i & 63;
            float acc = 0.f;
            #pragma unroll
            for (int e = 0; e < 64; ++e) acc = fmaf(qs[r][e], kv[kk][e], acc);
            s[r][k0 + kk] = (k0 + kk < Lq) ? acc : -1e30f;
        }
        __syncthreads();
    }

    // pass B: softmax rows (wave per row group), normalize in place
    int wv = tid >> 6, lane = tid & 63;
    for (int r = wv; r < 16; r += 4) {
        float m = -1e30f;
        for (int k = lane; k < nkt * 64; k += 64) m = fmaxf(m, s[r][k]);
        m = wave_reduce_max(m);
        float sum = 0.f;
        for (int k = lane; k < nkt * 64; k += 64) {
            float e = expf(s[r][k] - m);
            s[r][k] = e;
            sum += e;
        }
        sum = wave_reduce_sum(sum);
        float inv = 1.f / sum;
        for (int k = lane; k < nkt * 64; k += 64) s[r][k] *= inv;
    }
    __syncthreads();

    // pass C: PV. wave wv owns rows r0..r0+3; lane owns output dim.
    int r0 = wv * 4;
    float o0 = 0.f, o1 = 0.f, o2 = 0.f, o3 = 0.f;
    for (int kt = 0; kt < nkt; ++kt) {
        int k0 = kt * 64;
        for (int i = tid; i < 64 * 64; i += 256) {
            int r = i >> 6, c = i & 63;
            int krow = k0 + r;
            kv[r][c] = (krow < Lq) ? vp[((size_t)(b * Lq + krow)) * 128 + h * 64 + c] : 0.f;
        }
        __syncthreads();
        for (int kk = 0; kk < 64; ++kk) {
            float vv = kv[kk][lane];
            o0 = fmaf(s[r0 + 0][k0 + kk], vv, o0);
            o1 = fmaf(s[r0 + 1][k0 + kk], vv, o1);
            o2 = fmaf(s[r0 + 2][k0 + kk], vv, o2);
            o3 = fmaf(s[r0 + 3][k0 + kk], vv, o3);
        }
        __syncthreads();
    }
    float ov[4] = {o0, o1, o2, o3};
    #pragma unroll
    for (int j = 0; j < 4; ++j) {
        int qr = q0 + r0 + j;
        if (qr < Lq) outp[((size_t)(b * Lq + qr)) * 128 + h * 64 + lane] = ov[j];
    }
}

// ---------------------------------------------------------------------------
__global__ void add_ln_kernel(const float* xin, const float* resid,
                              const float* g, const float* bt, float* out) {
    int row = blockIdx.x, j = threadIdx.x;
    size_t off = (size_t)row * 128 + j;
    float v = xin[off] + resid[off];
    __shared__ float red[2];
    int wave = j >> 6, lane = j & 63;
    float s = wave_reduce_sum(v);
    if (lane == 0) red[wave] = s;
    __syncthreads();
    float mean = (red[0] + red[1]) * 0.0078125f;
    float d = v - mean;
    __syncthreads();
    float s2 = wave_reduce_sum(d * d);
    if (lane == 0) red[wave] = s2;
    __syncthreads();
    float var = (red[0] + red[1]) * 0.0078125f;
    out[off] = d * rsqrtf(var + 1e-5f) * g[j] + bt[j];
}

// ---------------------------------------------------------------------------
__global__ void assemble_kernel(float* dst, const float* cls_emb, const float* body,
                                const float* pos, int Lbody, int use_pos) {
    int r = blockIdx.x;
    int b = blockIdx.y;
    int j = threadIdx.x;  // 128
    float v = (r == 0) ? cls_emb[j] : body[((size_t)b * Lbody + (r - 1)) * 128 + j];
    if (use_pos) v += pos[r * 128 + j];
    dst[((size_t)b * (Lbody + 1) + r) * 128 + j] = v;
}

// ---------------------------------------------------------------------------
__global__ void finalize_kernel(const float* clsraw, const float* h2, float* out, int total) {
    int idx = blockIdx.x * 256 + threadIdx.x;
    if (idx >= total) return;
    float v;
    if (idx < 1024) {
        v = tanhf(clsraw[idx]);
    } else {
        int t = idx - 1024;
        int b = t >> 16;
        int rem = t & 65535;
        int i = rem >> 7, j = rem & 127;
        v = h2[((size_t)(b * 513 + 1 + i)) * 128 + j];
    }
    out[idx] = v;
}

// ---------------------------------------------------------------------------
extern "C" void kernel_launch(void* const* d_in, const int* in_sizes, int n_in,
                              void* d_out, int out_size, void* d_ws, size_t ws_size,
                              hipStream_t stream) {
    float* w = (float*)d_ws;
    size_t off = 0;
    auto alloc = [&](size_t n) {
        float* p = w + off;
        off += (n + 3) & ~(size_t)3;  // keep 16B alignment for float4
        return p;
    };

    int* flag = (int*)alloc(4);

    ConvArgs ca;
    int nn = n_in < 32 ? n_in : 32;
    int max_n = 0;
    float* fin[32];
    for (int i = 0; i < nn; ++i) {
        ca.src[i] = d_in[i];
        ca.n[i] = in_sizes[i];
        fin[i] = alloc(in_sizes[i]);
        ca.dstoff[i] = (int)(fin[i] - w);
        if (in_sizes[i] > max_n) max_n = in_sizes[i];
    }
    for (int i = nn; i < 32; ++i) { ca.src[i] = nullptr; ca.n[i] = 0; ca.dstoff[i] = 0; }

    const float* x     = fin[0];
    const float* ts    = fin[1];
    const float* w_per = fin[2];  const float* b_per = fin[3];
    const float* w_lin = fin[4];  const float* b_lin = fin[5];
    const float* Wq_t  = fin[6];  const float* bq_t  = fin[7];
    const float* Wk_t  = fin[8];  const float* bk_t  = fin[9];
    const float* Wo_t  = fin[10]; const float* bo_t  = fin[11];
    const float* pos_emb = fin[12]; const float* cls_emb = fin[13];
    const float* tWq = fin[14]; const float* tbq = fin[15];
    const float* tWk = fin[16]; const float* tbk = fin[17];
    const float* tWv = fin[18]; const float* tbv = fin[19];
    const float* tWo = fin[20]; const float* tbo = fin[21];
    const float* ln1_g = fin[22]; const float* ln1_b = fin[23];
    const float* fW1 = fin[24]; const float* fb1 = fin[25];
    const float* fW2 = fin[26]; const float* fb2 = fin[27];
    const float* ln2_g = fin[28]; const float* ln2_b = fin[29];
    const float* pW = fin[30]; const float* pb = fin[31];

    float* key_e   = alloc(4096 * 128);
    float* cls_e   = alloc(128 * 128);
    float* qp_main = alloc(4096 * 128);
    float* kp_main = alloc(4096 * 128);
    float* qp_cls  = alloc(128 * 128);
    float* att_cls = alloc(8 * 128 * 32);
    float* att_mn  = alloc(8 * 512 * 32);
    float* mta_cls = key_e;    // alias: key_e dead after projections
    float* mta_out = qp_main;  // alias: qp_main dead after mta attention
    float* xin_c   = alloc(8 * 129 * 128);
    float* xin_m   = alloc(8 * 513 * 128);
    float* tb_q    = alloc(8 * 513 * 128);
    float* tb_k    = alloc(8 * 513 * 128);
    float* tb_v    = alloc(8 * 513 * 128);
    float* tb_a    = alloc(8 * 513 * 128);
    float* tb_o    = tb_q;     // alias
    float* tb_x1   = alloc(8 * 513 * 128);
    float* tb_f1   = tb_k;     // alias
    float* tb_f2   = tb_v;     // alias
    float* x2_c    = alloc(8 * 129 * 128);
    float* x2_m    = alloc(8 * 513 * 128);
    float* clsraw  = alloc(8 * 128);
    (void)ws_size;

    detect_kernel<<<1, 1, 0, stream>>>((const unsigned short*)d_in[22], flag);
    convert_inputs_kernel<<<dim3((max_n + 255) / 256, 32), 256, 0, stream>>>(ca, w, flag);

    auto gemm = [&](const float* A, int lda, const float* W, const float* bias,
                    float* C, int ldc, int Mrows, int K, int act) {
        gemm16_kernel<<<(Mrows + 15) / 16, 256, 0, stream>>>(A, lda, W, bias, C, ldc, Mrows, K, act);
    };

    time_emb_kernel<<<4096, 128, 0, stream>>>(ts, w_per, b_per, w_lin, b_lin, key_e, 0);
    time_emb_kernel<<<128, 128, 0, stream>>>(ts, w_per, b_per, w_lin, b_lin, cls_e, 1);

    gemm(key_e, 128, Wk_t, bk_t, kp_main, 128, 4096, 128, 0);
    gemm(key_e, 128, Wq_t, bq_t, qp_main, 128, 4096, 128, 0);
    gemm(cls_e, 128, Wq_t, bq_t, qp_cls, 128, 128, 128, 0);

    mta_att_kernel<<<dim3(16, 2, 8), 256, 0, stream>>>(qp_cls, 0, kp_main, x, att_cls, 128);
    mta_att_kernel<<<dim3(64, 2, 8), 256, 0, stream>>>(qp_main, 1, kp_main, x, att_mn, 512);

    gemm(att_cls, 32, Wo_t, bo_t, mta_cls, 128, 8 * 128, 32, 0);
    gemm(att_mn, 32, Wo_t, bo_t, mta_out, 128, 8 * 512, 32, 0);

    assemble_kernel<<<dim3(129, 8), 128, 0, stream>>>(xin_c, cls_emb, mta_cls, pos_emb, 128, 0);
    assemble_kernel<<<dim3(513, 8), 128, 0, stream>>>(xin_m, cls_emb, mta_out, pos_emb, 512, 1);

    auto tblock = [&](const float* xin, float* x2, int Lq) {
        int Mr = 8 * Lq;
        gemm(xin, 128, tWq, tbq, tb_q, 128, Mr, 128, 0);
        gemm(xin, 128, tWk, tbk, tb_k, 128, Mr, 128, 0);
        gemm(xin, 128, tWv, tbv, tb_v, 128, Mr, 128, 0);
        tb_att_kernel<<<dim3((Lq + 15) / 16, 2, 8), 256, 0, stream>>>(tb_q, tb_k, tb_v, tb_a, Lq);
        gemm(tb_a, 128, tWo, tbo, tb_o, 128, Mr, 128, 0);
        add_ln_kernel<<<Mr, 128, 0, stream>>>(xin, tb_o, ln1_g, ln1_b, tb_x1);
        gemm(tb_x1, 128, fW1, fb1, tb_f1, 128, Mr, 128, 1);
        gemm(tb_f1, 128, fW2, fb2, tb_f2, 128, Mr, 128, 0);
        add_ln_kernel<<<Mr, 128, 0, stream>>>(tb_x1, tb_f2, ln2_g, ln2_b, x2);
    };

    tblock(xin_c, x2_c, 129);
    tblock(xin_m, x2_m, 513);

    gemm(x2_c, 129 * 128, pW, pb, clsraw, 128, 8, 128, 0);

    finalize_kernel<<<(out_size + 255) / 256, 256, 0, stream>>>(clsraw, x2_m, (float*)d_out, out_size);
}

// Round 5
// 659.492 us; speedup vs baseline: 1.3439x; 1.1021x over previous
//
#include <hip/hip_runtime.h>
#include <hip/hip_bf16.h>
#include <math.h>

// TimeBERT forward on MI355X. Inputs fp32 (runtime bf16 detector kept).
// Internal fp32. OUTPUT FP32: [cls_pooling (8,128) | last_hidden (8,512,128)].
//
// R5: LDS-read-amortized attention (1 row x 4 cols register blocking,
// stride-65 padding -> 2-way-free banks), mta d>=8 == 1.0 shortcut,
// batched/merged small kernels.

static constexpr int B_ = 8, L_ = 512, DIM_ = 8, ET_ = 128, HID_ = 128, H_ = 2;

using bf = __hip_bfloat16;

__device__ __forceinline__ float wave_reduce_sum(float v) {
    #pragma unroll
    for (int off = 32; off >= 1; off >>= 1) v += __shfl_xor(v, off);
    return v;
}
__device__ __forceinline__ float wave_reduce_max(float v) {
    #pragma unroll
    for (int off = 32; off >= 1; off >>= 1) v = fmaxf(v, __shfl_xor(v, off));
    return v;
}
__device__ __forceinline__ float half_reduce_sum(float v) {  // across 32 lanes
    #pragma unroll
    for (int off = 16; off >= 1; off >>= 1) v += __shfl_xor(v, off);
    return v;
}

// ---------------------------------------------------------------------------
__global__ void detect_kernel(const unsigned short* ln1_g_raw, int* flag) {
    if (threadIdx.x == 0 && blockIdx.x == 0)
        *flag = (ln1_g_raw[0] == 0x3F80u) ? 1 : 0;
}

struct ConvArgs {
    const void* src[32];
    int n[32];
    int dstoff[32];
};
__global__ void convert_inputs_kernel(ConvArgs a, float* dst, const int* flag) {
    int which = blockIdx.y;
    int n = a.n[which];
    int i = blockIdx.x * 256 + threadIdx.x;
    if (i >= n) return;
    float v;
    if (*flag) v = __bfloat162float(((const bf*)a.src[which])[i]);
    else       v = ((const float*)a.src[which])[i];
    dst[a.dstoff[which] + i] = v;
}

// ---------------------------------------------------------------------------
// rows 0..4095 -> key_e (t = ts[row]); rows 4096..4223 -> cls_e (t = r/127).
__global__ void time_emb_kernel(const float* ts, const float* w_per, const float* b_per,
                                const float* w_lin, const float* b_lin,
                                float* key_e, float* cls_e) {
    int row = blockIdx.x, j = threadIdx.x;  // 128 threads
    float t;
    float* out;
    if (row < 4096) { t = ts[row]; out = key_e + (size_t)row * 128; }
    else { t = (float)(row - 4096) * (1.0f / 127.0f); out = cls_e + (size_t)(row - 4096) * 128; }
    float v;
    if (j == 0) v = t * w_lin[0] + b_lin[0];
    else        v = sinf(t * w_per[j - 1] + b_per[j - 1]);
    out[j] = v;
}

// ---------------------------------------------------------------------------
// Batched GEMM: up to 3 sub-gemms selected by blockIdx.y.
// C[m,n] = act(A[m,:K] @ W[K,128] + bias[n]); 16 rows/block, 256 thr.
struct GemmBatch {
    const float* A[3]; const float* W[3]; const float* bias[3]; float* C[3];
    int lda[3], ldc[3], M[3], K[3], act[3];
};
__global__ void gemm16b_kernel(GemmBatch p) {
    int y = blockIdx.y;
    const float* A = p.A[y]; const float* W = p.W[y]; const float* bias = p.bias[y];
    float* C = p.C[y];
    int lda = p.lda[y], ldc = p.ldc[y], M = p.M[y], K = p.K[y], act = p.act[y];
    int m0 = blockIdx.x * 16;
    if (m0 >= M) return;
    __shared__ float As[16][132];
    int tid = threadIdx.x;
    int r = tid >> 4, g = tid & 15, c0 = g * 8;
    for (int c = g; c < K; c += 16) {
        float v = 0.f;
        if (m0 + r < M) v = A[(size_t)(m0 + r) * lda + c];
        As[r][c] = v;
    }
    __syncthreads();
    float acc[8];
    #pragma unroll
    for (int j = 0; j < 8; ++j) acc[j] = bias[c0 + j];
    for (int k = 0; k < K; ++k) {
        float a = As[r][k];
        const float4 w0 = *(const float4*)(W + (size_t)k * 128 + c0);
        const float4 w1 = *(const float4*)(W + (size_t)k * 128 + c0 + 4);
        acc[0] = fmaf(a, w0.x, acc[0]); acc[1] = fmaf(a, w0.y, acc[1]);
        acc[2] = fmaf(a, w0.z, acc[2]); acc[3] = fmaf(a, w0.w, acc[3]);
        acc[4] = fmaf(a, w1.x, acc[4]); acc[5] = fmaf(a, w1.y, acc[5]);
        acc[6] = fmaf(a, w1.z, acc[6]); acc[7] = fmaf(a, w1.w, acc[7]);
    }
    if (act == 1) {
        #pragma unroll
        for (int j = 0; j < 8; ++j) acc[j] = fmaxf(acc[j], 0.f);
    }
    if (m0 + r < M) {
        *(float4*)(C + (size_t)(m0 + r) * ldc + c0) = make_float4(acc[0], acc[1], acc[2], acc[3]);
        *(float4*)(C + (size_t)(m0 + r) * ldc + c0 + 4) = make_float4(acc[4], acc[5], acc[6], acc[7]);
    }
}

// ---------------------------------------------------------------------------
// mta attention, merged cls+main. Grid: x in [0,40): x<32 main (Lq=512),
// x>=32 cls (Lq=128, q unbatched); y=h; z=b. 256 threads, 16 q-rows/block.
// Keys always 512 (kp). x: (B,512,16) cols 0..7 vals, 8..15 masks {0,1}.
// Output cols h*16+d: d<8 computed, d in 8..15 == 1.0 exactly (val col == mask col).
__global__ void mta_att_kernel(const float* qp_cls, const float* qp_main, const float* kp,
                               const float* x, float* att_cls, float* att_mn) {
    int is_cls = (blockIdx.x >= 32);
    int qt = is_cls ? (blockIdx.x - 32) : blockIdx.x;
    int h = blockIdx.y, b = blockIdx.z;
    int tid = threadIdx.x;  // 256
    __shared__ float qs[16][68];   // reused as xv[64][17] in masked pass
    __shared__ float kv[64][65];
    __shared__ float s[16][516];
    float* xv = &qs[0][0];
    int q0 = qt * 16;

    // load q (16 rows x 64), scaled by 1/8
    {
        int r = tid >> 4, c0 = (tid & 15) * 4;
        const float* qrow = is_cls ? (qp_cls + (size_t)(q0 + r) * 128 + h * 64)
                                   : (qp_main + (size_t)(b * 512 + q0 + r) * 128 + h * 64);
        float4 v = *(const float4*)(qrow + c0);
        qs[r][c0] = v.x * 0.125f; qs[r][c0 + 1] = v.y * 0.125f;
        qs[r][c0 + 2] = v.z * 0.125f; qs[r][c0 + 3] = v.w * 0.125f;
    }
    __syncthreads();

    int r = tid >> 4, kg = tid & 15;
    // pass A: scores, 8 K-tiles of 64
    for (int kt = 0; kt < 8; ++kt) {
        int k0 = kt * 64;
        {   // stage K tile coalesced: t -> kk=t>>4 (+16 strides), e0=(t&15)*4
            int kk = tid >> 4, e0 = (tid & 15) * 4;
            #pragma unroll
            for (int it = 0; it < 4; ++it, kk += 16) {
                float4 v = *(const float4*)(kp + (size_t)(b * 512 + k0 + kk) * 128 + h * 64 + e0);
                kv[kk][e0] = v.x; kv[kk][e0 + 1] = v.y; kv[kk][e0 + 2] = v.z; kv[kk][e0 + 3] = v.w;
            }
        }
        __syncthreads();
        float a0 = 0.f, a1 = 0.f, a2 = 0.f, a3 = 0.f;
        int kk0 = kg * 4;
        #pragma unroll 4
        for (int e = 0; e < 64; ++e) {
            float qe = qs[r][e];
            a0 = fmaf(qe, kv[kk0][e], a0);
            a1 = fmaf(qe, kv[kk0 + 1][e], a1);
            a2 = fmaf(qe, kv[kk0 + 2][e], a2);
            a3 = fmaf(qe, kv[kk0 + 3][e], a3);
        }
        s[r][k0 + kk0] = a0; s[r][k0 + kk0 + 1] = a1;
        s[r][k0 + kk0 + 2] = a2; s[r][k0 + kk0 + 3] = a3;
        __syncthreads();
    }

    // pass B: max + exp in place (ratio-invariant global max per row)
    int wv = tid >> 6, lane = tid & 63;
    for (int rr = wv; rr < 16; rr += 4) {
        float m = -1e30f;
        for (int k = lane; k < 512; k += 64) m = fmaxf(m, s[rr][k]);
        m = wave_reduce_max(m);
        for (int k = lane; k < 512; k += 64) s[rr][k] = expf(s[rr][k] - m);
    }
    __syncthreads();

    // masked sums: d = tid>>5 (0..7), sub = tid&31; xv tile in qs buffer
    int d = tid >> 5, sub = tid & 31;
    float num[16], den[16];
    #pragma unroll
    for (int q = 0; q < 16; ++q) { num[q] = 0.f; den[q] = 0.f; }
    for (int kt = 0; kt < 8; ++kt) {
        int k0 = kt * 64;
        __syncthreads();
        {   // stage x tile: 64 rows x 16 cols, coalesced
            int kk = tid >> 2, c0 = (tid & 3) * 4;
            float4 v = *(const float4*)(x + (size_t)(b * 512 + k0 + kk) * 16 + c0);
            xv[kk * 17 + c0] = v.x; xv[kk * 17 + c0 + 1] = v.y;
            xv[kk * 17 + c0 + 2] = v.z; xv[kk * 17 + c0 + 3] = v.w;
        }
        __syncthreads();
        #pragma unroll
        for (int i = 0; i < 2; ++i) {
            int kk = sub + 32 * i;
            float mk = xv[kk * 17 + 8 + d];
            float vv = xv[kk * 17 + d];
            #pragma unroll
            for (int q = 0; q < 16; ++q) {
                float em = s[q][k0 + kk] * mk;
                den[q] += em;
                num[q] = fmaf(em, vv, num[q]);
            }
        }
    }
    #pragma unroll
    for (int q = 0; q < 16; ++q) {
        float n2 = half_reduce_sum(num[q]);
        float d2 = half_reduce_sum(den[q]);
        if (sub == 0) {
            int row = q0 + q;
            float* dst = is_cls ? (att_cls + (size_t)(b * 128 + row) * 32)
                                : (att_mn + (size_t)(b * 512 + row) * 32);
            dst[h * 16 + d] = n2 / d2;
            dst[h * 16 + 8 + d] = 1.0f;
        }
    }
}

// ---------------------------------------------------------------------------
// tblock attention: 256 thr, 16 q-rows/block, register-blocked 1x4.
__global__ void tb_att_kernel(const float* qp, const float* kp, const float* vp,
                              float* outp, int Lq) {
    int qt = blockIdx.x, h = blockIdx.y, b = blockIdx.z;
    int tid = threadIdx.x;  // 256
    __shared__ float qs[16][68];
    __shared__ float kv[64][65];
    __shared__ float s[16][580];
    int q0 = qt * 16;
    int nkt = (Lq + 63) >> 6;

    {   // load q
        int r = tid >> 4, c0 = (tid & 15) * 4;
        int qr = q0 + r;
        float4 v = make_float4(0.f, 0.f, 0.f, 0.f);
        if (qr < Lq) v = *(const float4*)(qp + (size_t)(b * Lq + qr) * 128 + h * 64 + c0);
        qs[r][c0] = v.x * 0.125f; qs[r][c0 + 1] = v.y * 0.125f;
        qs[r][c0 + 2] = v.z * 0.125f; qs[r][c0 + 3] = v.w * 0.125f;
    }
    __syncthreads();

    int r = tid >> 4, kg = tid & 15;
    // pass A: scores
    for (int kt = 0; kt < nkt; ++kt) {
        int k0 = kt * 64;
        {
            int kk = tid >> 4, e0 = (tid & 15) * 4;
            #pragma unroll
            for (int it = 0; it < 4; ++it, kk += 16) {
                int krow = k0 + kk;
                float4 v = make_float4(0.f, 0.f, 0.f, 0.f);
                if (krow < Lq) v = *(const float4*)(kp + (size_t)(b * Lq + krow) * 128 + h * 64 + e0);
                kv[kk][e0] = v.x; kv[kk][e0 + 1] = v.y; kv[kk][e0 + 2] = v.z; kv[kk][e0 + 3] = v.w;
            }
        }
        __syncthreads();
        float a0 = 0.f, a1 = 0.f, a2 = 0.f, a3 = 0.f;
        int kk0 = kg * 4;
        #pragma unroll 4
        for (int e = 0; e < 64; ++e) {
            float qe = qs[r][e];
            a0 = fmaf(qe, kv[kk0][e], a0);
            a1 = fmaf(qe, kv[kk0 + 1][e], a1);
            a2 = fmaf(qe, kv[kk0 + 2][e], a2);
            a3 = fmaf(qe, kv[kk0 + 3][e], a3);
        }
        int kb = k0 + kk0;
        s[r][kb]     = (kb < Lq)     ? a0 : -1e30f;
        s[r][kb + 1] = (kb + 1 < Lq) ? a1 : -1e30f;
        s[r][kb + 2] = (kb + 2 < Lq) ? a2 : -1e30f;
        s[r][kb + 3] = (kb + 3 < Lq) ? a3 : -1e30f;
        __syncthreads();
    }

    // pass B: softmax rows, normalized in place
    int wv = tid >> 6, lane = tid & 63;
    int kend = nkt * 64;
    for (int rr = wv; rr < 16; rr += 4) {
        float m = -1e30f;
        for (int k = lane; k < kend; k += 64) m = fmaxf(m, s[rr][k]);
        m = wave_reduce_max(m);
        float sum = 0.f;
        for (int k = lane; k < kend; k += 64) {
            float e = expf(s[rr][k] - m);
            s[rr][k] = e;
            sum += e;
        }
        sum = wave_reduce_sum(sum);
        float inv = 1.f / sum;
        for (int k = lane; k < kend; k += 64) s[rr][k] *= inv;
    }

    // pass C: PV, thread = (row r, 4 dims d0..d0+3)
    int dg = tid & 15, d0 = dg * 4;
    float o0 = 0.f, o1 = 0.f, o2 = 0.f, o3 = 0.f;
    for (int kt = 0; kt < nkt; ++kt) {
        int k0 = kt * 64;
        __syncthreads();
        {
            int kk = tid >> 4, e0 = (tid & 15) * 4;
            #pragma unroll
            for (int it = 0; it < 4; ++it, kk += 16) {
                int krow = k0 + kk;
                float4 v = make_float4(0.f, 0.f, 0.f, 0.f);
                if (krow < Lq) v = *(const float4*)(vp + (size_t)(b * Lq + krow) * 128 + h * 64 + e0);
                kv[kk][e0] = v.x; kv[kk][e0 + 1] = v.y; kv[kk][e0 + 2] = v.z; kv[kk][e0 + 3] = v.w;
            }
        }
        __syncthreads();
        #pragma unroll 4
        for (int kk = 0; kk < 64; ++kk) {
            float p = s[r][k0 + kk];
            o0 = fmaf(p, kv[kk][d0], o0);
            o1 = fmaf(p, kv[kk][d0 + 1], o1);
            o2 = fmaf(p, kv[kk][d0 + 2], o2);
            o3 = fmaf(p, kv[kk][d0 + 3], o3);
        }
    }
    int qr = q0 + r;
    if (qr < Lq)
        *(float4*)(outp + (size_t)(b * Lq + qr) * 128 + h * 64 + d0) = make_float4(o0, o1, o2, o3);
}

// ---------------------------------------------------------------------------
__global__ void add_ln_kernel(const float* xin, const float* resid,
                              const float* g, const float* bt, float* out) {
    int row = blockIdx.x, j = threadIdx.x;
    size_t off = (size_t)row * 128 + j;
    float v = xin[off] + resid[off];
    __shared__ float red[2];
    int wave = j >> 6, lane = j & 63;
    float s = wave_reduce_sum(v);
    if (lane == 0) red[wave] = s;
    __syncthreads();
    float mean = (red[0] + red[1]) * 0.0078125f;
    float d = v - mean;
    __syncthreads();
    float s2 = wave_reduce_sum(d * d);
    if (lane == 0) red[wave] = s2;
    __syncthreads();
    float var = (red[0] + red[1]) * 0.0078125f;
    out[off] = d * rsqrtf(var + 1e-5f) * g[j] + bt[j];
}

// ---------------------------------------------------------------------------
__global__ void assemble_kernel(float* dst, const float* cls_emb, const float* body,
                                const float* pos, int Lbody, int use_pos) {
    int r = blockIdx.x;
    int b = blockIdx.y;
    int j = threadIdx.x;  // 128
    float v = (r == 0) ? cls_emb[j] : body[((size_t)b * Lbody + (r - 1)) * 128 + j];
    if (use_pos) v += pos[r * 128 + j];
    dst[((size_t)b * (Lbody + 1) + r) * 128 + j] = v;
}

// ---------------------------------------------------------------------------
__global__ void finalize_kernel(const float* clsraw, const float* h2, float* out, int total) {
    int idx = blockIdx.x * 256 + threadIdx.x;
    if (idx >= total) return;
    float v;
    if (idx < 1024) {
        v = tanhf(clsraw[idx]);
    } else {
        int t = idx - 1024;
        int b = t >> 16;
        int rem = t & 65535;
        int i = rem >> 7, j = rem & 127;
        v = h2[((size_t)(b * 513 + 1 + i)) * 128 + j];
    }
    out[idx] = v;
}

// ---------------------------------------------------------------------------
extern "C" void kernel_launch(void* const* d_in, const int* in_sizes, int n_in,
                              void* d_out, int out_size, void* d_ws, size_t ws_size,
                              hipStream_t stream) {
    float* w = (float*)d_ws;
    size_t off = 0;
    auto alloc = [&](size_t n) {
        float* p = w + off;
        off += (n + 3) & ~(size_t)3;
        return p;
    };

    int* flag = (int*)alloc(4);

    ConvArgs ca;
    int nn = n_in < 32 ? n_in : 32;
    int max_n = 0;
    float* fin[32];
    for (int i = 0; i < nn; ++i) {
        ca.src[i] = d_in[i];
        ca.n[i] = in_sizes[i];
        fin[i] = alloc(in_sizes[i]);
        ca.dstoff[i] = (int)(fin[i] - w);
        if (in_sizes[i] > max_n) max_n = in_sizes[i];
    }
    for (int i = nn; i < 32; ++i) { ca.src[i] = nullptr; ca.n[i] = 0; ca.dstoff[i] = 0; }

    const float* x     = fin[0];
    const float* ts    = fin[1];
    const float* w_per = fin[2];  const float* b_per = fin[3];
    const float* w_lin = fin[4];  const float* b_lin = fin[5];
    const float* Wq_t  = fin[6];  const float* bq_t  = fin[7];
    const float* Wk_t  = fin[8];  const float* bk_t  = fin[9];
    const float* Wo_t  = fin[10]; const float* bo_t  = fin[11];
    const float* pos_emb = fin[12]; const float* cls_emb = fin[13];
    const float* tWq = fin[14]; const float* tbq = fin[15];
    const float* tWk = fin[16]; const float* tbk = fin[17];
    const float* tWv = fin[18]; const float* tbv = fin[19];
    const float* tWo = fin[20]; const float* tbo = fin[21];
    const float* ln1_g = fin[22]; const float* ln1_b = fin[23];
    const float* fW1 = fin[24]; const float* fb1 = fin[25];
    const float* fW2 = fin[26]; const float* fb2 = fin[27];
    const float* ln2_g = fin[28]; const float* ln2_b = fin[29];
    const float* pW = fin[30]; const float* pb = fin[31];

    float* key_e   = alloc(4096 * 128);
    float* cls_e   = alloc(128 * 128);
    float* qp_main = alloc(4096 * 128);
    float* kp_main = alloc(4096 * 128);
    float* qp_cls  = alloc(128 * 128);
    float* att_all = alloc(5120 * 32);            // rows: 1024 cls | 4096 main
    float* att_cls = att_all;
    float* att_mn  = att_all + 1024 * 32;
    float* mta_all = qp_main;                     // alias: qp/kp dead after mta_att
    float* mta_cls = mta_all;                     // 1024 x 128
    float* mta_out = mta_all + 1024 * 128;        // 4096 x 128
    float* xin_c   = alloc(8 * 129 * 128);
    float* xin_m   = alloc(8 * 513 * 128);
    float* tb_q    = alloc(8 * 513 * 128);
    float* tb_k    = alloc(8 * 513 * 128);
    float* tb_v    = alloc(8 * 513 * 128);
    float* tb_a    = alloc(8 * 513 * 128);
    float* tb_o    = tb_q;     // alias
    float* tb_x1   = alloc(8 * 513 * 128);
    float* tb_f1   = tb_k;     // alias
    float* tb_f2   = tb_v;     // alias
    float* x2_c    = alloc(8 * 129 * 128);
    float* x2_m    = alloc(8 * 513 * 128);
    float* clsraw  = alloc(8 * 128);
    (void)ws_size;

    detect_kernel<<<1, 1, 0, stream>>>((const unsigned short*)d_in[22], flag);
    convert_inputs_kernel<<<dim3((max_n + 255) / 256, 32), 256, 0, stream>>>(ca, w, flag);

    time_emb_kernel<<<4224, 128, 0, stream>>>(ts, w_per, b_per, w_lin, b_lin, key_e, cls_e);

    // mta projections: k(4096), q(4096), q_cls(128) in one batched launch
    {
        GemmBatch p{};
        p.A[0] = key_e; p.W[0] = Wk_t; p.bias[0] = bk_t; p.C[0] = kp_main;
        p.lda[0] = 128; p.ldc[0] = 128; p.M[0] = 4096; p.K[0] = 128; p.act[0] = 0;
        p.A[1] = key_e; p.W[1] = Wq_t; p.bias[1] = bq_t; p.C[1] = qp_main;
        p.lda[1] = 128; p.ldc[1] = 128; p.M[1] = 4096; p.K[1] = 128; p.act[1] = 0;
        p.A[2] = cls_e; p.W[2] = Wq_t; p.bias[2] = bq_t; p.C[2] = qp_cls;
        p.lda[2] = 128; p.ldc[2] = 128; p.M[2] = 128; p.K[2] = 128; p.act[2] = 0;
        gemm16b_kernel<<<dim3(256, 3), 256, 0, stream>>>(p);
    }

    // mta attention: cls + main merged
    mta_att_kernel<<<dim3(40, 2, 8), 256, 0, stream>>>(qp_cls, qp_main, kp_main, x, att_cls, att_mn);

    // mta out-projection over contiguous 5120 rows (K=32)
    {
        GemmBatch p{};
        p.A[0] = att_all; p.W[0] = Wo_t; p.bias[0] = bo_t; p.C[0] = mta_all;
        p.lda[0] = 32; p.ldc[0] = 128; p.M[0] = 5120; p.K[0] = 32; p.act[0] = 0;
        gemm16b_kernel<<<dim3(320, 1), 256, 0, stream>>>(p);
    }

    assemble_kernel<<<dim3(129, 8), 128, 0, stream>>>(xin_c, cls_emb, mta_cls, pos_emb, 128, 0);
    assemble_kernel<<<dim3(513, 8), 128, 0, stream>>>(xin_m, cls_emb, mta_out, pos_emb, 512, 1);

    auto single_gemm = [&](const float* A, int lda, const float* W, const float* bias,
                           float* C, int ldc, int M, int K, int act) {
        GemmBatch p{};
        p.A[0] = A; p.W[0] = W; p.bias[0] = bias; p.C[0] = C;
        p.lda[0] = lda; p.ldc[0] = ldc; p.M[0] = M; p.K[0] = K; p.act[0] = act;
        gemm16b_kernel<<<dim3((M + 15) / 16, 1), 256, 0, stream>>>(p);
    };

    auto tblock = [&](const float* xin, float* x2, int Lq) {
        int Mr = 8 * Lq;
        {   // QKV batched
            GemmBatch p{};
            const float* Ws[3] = {tWq, tWk, tWv};
            const float* bs[3] = {tbq, tbk, tbv};
            float* Cs[3] = {tb_q, tb_k, tb_v};
            for (int y = 0; y < 3; ++y) {
                p.A[y] = xin; p.W[y] = Ws[y]; p.bias[y] = bs[y]; p.C[y] = Cs[y];
                p.lda[y] = 128; p.ldc[y] = 128; p.M[y] = Mr; p.K[y] = 128; p.act[y] = 0;
            }
            gemm16b_kernel<<<dim3((Mr + 15) / 16, 3), 256, 0, stream>>>(p);
        }
        tb_att_kernel<<<dim3((Lq + 15) / 16, 2, 8), 256, 0, stream>>>(tb_q, tb_k, tb_v, tb_a, Lq);
        single_gemm(tb_a, 128, tWo, tbo, tb_o, 128, Mr, 128, 0);
        add_ln_kernel<<<Mr, 128, 0, stream>>>(xin, tb_o, ln1_g, ln1_b, tb_x1);
        single_gemm(tb_x1, 128, fW1, fb1, tb_f1, 128, Mr, 128, 1);
        single_gemm(tb_f1, 128, fW2, fb2, tb_f2, 128, Mr, 128, 0);
        add_ln_kernel<<<Mr, 128, 0, stream>>>(tb_x1, tb_f2, ln2_g, ln2_b, x2);
    };

    tblock(xin_c, x2_c, 129);
    tblock(xin_m, x2_m, 513);

    single_gemm(x2_c, 129 * 128, pW, pb, clsraw, 128, 8, 128, 0);

    finalize_kernel<<<(out_size + 255) / 256, 256, 0, stream>>>(clsraw, x2_m, (float*)d_out, out_size);
}

// Round 7
// 490.544 us; speedup vs baseline: 1.8068x; 1.3444x over previous
//
#include <hip/hip_runtime.h>
#include <hip/hip_bf16.h>
#include <math.h>

// TimeBERT forward on MI355X. Inputs fp32 (runtime bf16 detector kept).
// Internal fp32. OUTPUT FP32: [cls_pooling (8,128) | last_hidden (8,512,128)].
//
// R7: fix R6's tb_att score-buffer overflow (s stride 520 < kend 576 for
// Lq=513 -> row aliasing). s[16][584]; 584 % 32 == 8 keeps stores 2-way-free.

static constexpr int B_ = 8, L_ = 512, DIM_ = 8, ET_ = 128, HID_ = 128, H_ = 2;

using bf = __hip_bfloat16;

__device__ __forceinline__ float wave_reduce_sum(float v) {
    #pragma unroll
    for (int off = 32; off >= 1; off >>= 1) v += __shfl_xor(v, off);
    return v;
}
__device__ __forceinline__ float wave_reduce_max(float v) {
    #pragma unroll
    for (int off = 32; off >= 1; off >>= 1) v = fmaxf(v, __shfl_xor(v, off));
    return v;
}

// ---------------------------------------------------------------------------
__global__ void detect_kernel(const unsigned short* ln1_g_raw, int* flag) {
    if (threadIdx.x == 0 && blockIdx.x == 0)
        *flag = (ln1_g_raw[0] == 0x3F80u) ? 1 : 0;
}

struct ConvArgs {
    const void* src[32];
    int n[32];
    int dstoff[32];
};
__global__ void convert_inputs_kernel(ConvArgs a, float* dst, const int* flag) {
    int which = blockIdx.y;
    int n = a.n[which];
    int i = blockIdx.x * 256 + threadIdx.x;
    if (i >= n) return;
    float v;
    if (*flag) v = __bfloat162float(((const bf*)a.src[which])[i]);
    else       v = ((const float*)a.src[which])[i];
    dst[a.dstoff[which] + i] = v;
}

// ---------------------------------------------------------------------------
__global__ void time_emb_kernel(const float* ts, const float* w_per, const float* b_per,
                                const float* w_lin, const float* b_lin,
                                float* key_e, float* cls_e) {
    int row = blockIdx.x, j = threadIdx.x;  // 128 threads
    float t;
    float* out;
    if (row < 4096) { t = ts[row]; out = key_e + (size_t)row * 128; }
    else { t = (float)(row - 4096) * (1.0f / 127.0f); out = cls_e + (size_t)(row - 4096) * 128; }
    float v;
    if (j == 0) v = t * w_lin[0] + b_lin[0];
    else        v = sinf(t * w_per[j - 1] + b_per[j - 1]);
    out[j] = v;
}

// ---------------------------------------------------------------------------
struct GemmBatch {
    const float* A[3]; const float* W[3]; const float* bias[3]; float* C[3];
    int lda[3], ldc[3], M[3], K[3], act[3];
};
__global__ void gemm16b_kernel(GemmBatch p) {
    int y = blockIdx.y;
    const float* A = p.A[y]; const float* W = p.W[y]; const float* bias = p.bias[y];
    float* C = p.C[y];
    int lda = p.lda[y], ldc = p.ldc[y], M = p.M[y], K = p.K[y], act = p.act[y];
    int m0 = blockIdx.x * 16;
    if (m0 >= M) return;
    __shared__ float As[16][132];
    int tid = threadIdx.x;
    int r = tid >> 4, g = tid & 15, c0 = g * 8;
    for (int c = g; c < K; c += 16) {
        float v = 0.f;
        if (m0 + r < M) v = A[(size_t)(m0 + r) * lda + c];
        As[r][c] = v;
    }
    __syncthreads();
    float acc[8];
    #pragma unroll
    for (int j = 0; j < 8; ++j) acc[j] = bias[c0 + j];
    for (int k = 0; k < K; ++k) {
        float a = As[r][k];
        const float4 w0 = *(const float4*)(W + (size_t)k * 128 + c0);
        const float4 w1 = *(const float4*)(W + (size_t)k * 128 + c0 + 4);
        acc[0] = fmaf(a, w0.x, acc[0]); acc[1] = fmaf(a, w0.y, acc[1]);
        acc[2] = fmaf(a, w0.z, acc[2]); acc[3] = fmaf(a, w0.w, acc[3]);
        acc[4] = fmaf(a, w1.x, acc[4]); acc[5] = fmaf(a, w1.y, acc[5]);
        acc[6] = fmaf(a, w1.z, acc[6]); acc[7] = fmaf(a, w1.w, acc[7]);
    }
    if (act == 1) {
        #pragma unroll
        for (int j = 0; j < 8; ++j) acc[j] = fmaxf(acc[j], 0.f);
    }
    if (m0 + r < M) {
        *(float4*)(C + (size_t)(m0 + r) * ldc + c0) = make_float4(acc[0], acc[1], acc[2], acc[3]);
        *(float4*)(C + (size_t)(m0 + r) * ldc + c0 + 4) = make_float4(acc[4], acc[5], acc[6], acc[7]);
    }
}

// ---------------------------------------------------------------------------
// mta attention, merged cls+main. Grid x<32: main (Lq=512); x>=32: cls.
// 256 threads, 16 q-rows/block. Output col d<8 computed; d in 8..15 == 1.0
// exactly (value col == mask col => sum p*m/sum p*m = 1).
__global__ void __launch_bounds__(256, 2)
mta_att_kernel(const float* qp_cls, const float* qp_main, const float* kp,
               const float* x, float* att_cls, float* att_mn) {
    int is_cls = (blockIdx.x >= 32);
    int qt = is_cls ? (blockIdx.x - 32) : blockIdx.x;
    int h = blockIdx.y, b = blockIdx.z;
    int tid = threadIdx.x;  // 256
    __shared__ float qs[16][68];   // reused as xv[64][17] in masked pass
    __shared__ float kv[64][68];
    __shared__ float s[16][520];   // 512 cols used; 520 % 32 == 8 -> 2-way stores
    float* xv = &qs[0][0];
    int q0 = qt * 16;

    {   // load q (16 x 64), scaled 1/8
        int r = tid >> 4, c0 = (tid & 15) * 4;
        const float* qrow = is_cls ? (qp_cls + (size_t)(q0 + r) * 128 + h * 64)
                                   : (qp_main + (size_t)(b * 512 + q0 + r) * 128 + h * 64);
        float4 v = *(const float4*)(qrow + c0);
        qs[r][c0] = v.x * 0.125f; qs[r][c0 + 1] = v.y * 0.125f;
        qs[r][c0 + 2] = v.z * 0.125f; qs[r][c0 + 3] = v.w * 0.125f;
    }
    __syncthreads();

    int r = tid >> 4, kg = tid & 15;
    // pass A: scores; thread covers k = k0 + kg + 16j
    for (int kt = 0; kt < 8; ++kt) {
        int k0 = kt * 64;
        {   // stage K tile (float4, stride 68)
            int kk = tid >> 4, e0 = (tid & 15) * 4;
            #pragma unroll
            for (int it = 0; it < 4; ++it, kk += 16) {
                float4 v = *(const float4*)(kp + (size_t)(b * 512 + k0 + kk) * 128 + h * 64 + e0);
                *(float4*)&kv[kk][e0] = v;
            }
        }
        __syncthreads();
        float a[4] = {0.f, 0.f, 0.f, 0.f};
        #pragma unroll 4
        for (int e4 = 0; e4 < 64; e4 += 4) {
            float4 q4 = *(const float4*)&qs[r][e4];
            #pragma unroll
            for (int j = 0; j < 4; ++j) {
                float4 k4 = *(const float4*)&kv[kg + 16 * j][e4];
                a[j] = fmaf(q4.x, k4.x, a[j]);
                a[j] = fmaf(q4.y, k4.y, a[j]);
                a[j] = fmaf(q4.z, k4.z, a[j]);
                a[j] = fmaf(q4.w, k4.w, a[j]);
            }
        }
        #pragma unroll
        for (int j = 0; j < 4; ++j) s[r][k0 + kg + 16 * j] = a[j];
        __syncthreads();
    }

    // pass B: global-max + exp in place (ratio-identical to ref)
    int wv = tid >> 6, lane = tid & 63;
    for (int rr = wv; rr < 16; rr += 4) {
        float m = -1e30f;
        for (int k = lane; k < 512; k += 64) m = fmaxf(m, s[rr][k]);
        m = wave_reduce_max(m);
        for (int k = lane; k < 512; k += 64) s[rr][k] = expf(s[rr][k] - m);
    }

    // masked sums: wave -> 4 q-rows; lane = (d = lane>>3, sub = lane&7).
    int d = lane >> 3, sub = lane & 7;
    int qb = wv * 4;
    float num[4] = {0.f, 0.f, 0.f, 0.f}, den[4] = {0.f, 0.f, 0.f, 0.f};
    for (int kt = 0; kt < 8; ++kt) {
        int k0 = kt * 64;
        __syncthreads();
        {   // stage x tile 64x16 into qs buffer (stride 17)
            int kk = tid >> 2, c0 = (tid & 3) * 4;
            float4 v = *(const float4*)(x + (size_t)(b * 512 + k0 + kk) * 16 + c0);
            xv[kk * 17 + c0] = v.x; xv[kk * 17 + c0 + 1] = v.y;
            xv[kk * 17 + c0 + 2] = v.z; xv[kk * 17 + c0 + 3] = v.w;
        }
        __syncthreads();
        #pragma unroll
        for (int i = 0; i < 8; ++i) {
            int kk = sub + 8 * i;
            float mk = xv[kk * 17 + 8 + d];
            float vv = xv[kk * 17 + d];
            #pragma unroll
            for (int q = 0; q < 4; ++q) {
                float em = s[qb + q][k0 + kk] * mk;
                den[q] += em;
                num[q] = fmaf(em, vv, num[q]);
            }
        }
    }
    #pragma unroll
    for (int q = 0; q < 4; ++q) {
        #pragma unroll
        for (int off2 = 4; off2 >= 1; off2 >>= 1) {
            num[q] += __shfl_xor(num[q], off2);
            den[q] += __shfl_xor(den[q], off2);
        }
        if (sub == 0) {
            int row = q0 + qb + q;
            float* dst = is_cls ? (att_cls + (size_t)(b * 128 + row) * 32)
                                : (att_mn + (size_t)(b * 512 + row) * 32);
            dst[h * 16 + d] = num[q] / den[q];
            dst[h * 16 + 8 + d] = 1.0f;
        }
    }
}

// ---------------------------------------------------------------------------
// tblock attention: 256 thr, 16 q-rows/block. s stride 584 >= kend(576) for
// Lq=513, and 584 % 32 == 8 keeps score stores 2-way-conflict-free.
__global__ void __launch_bounds__(256, 2)
tb_att_kernel(const float* qp, const float* kp, const float* vp,
              float* outp, int Lq) {
    int qt = blockIdx.x, h = blockIdx.y, b = blockIdx.z;
    int tid = threadIdx.x;  // 256
    __shared__ float qs[16][68];
    __shared__ float kv[64][68];
    __shared__ float s[16][584];
    int q0 = qt * 16;
    int nkt = (Lq + 63) >> 6;

    {   // load q
        int r = tid >> 4, c0 = (tid & 15) * 4;
        int qr = q0 + r;
        float4 v = make_float4(0.f, 0.f, 0.f, 0.f);
        if (qr < Lq) v = *(const float4*)(qp + (size_t)(b * Lq + qr) * 128 + h * 64 + c0);
        qs[r][c0] = v.x * 0.125f; qs[r][c0 + 1] = v.y * 0.125f;
        qs[r][c0 + 2] = v.z * 0.125f; qs[r][c0 + 3] = v.w * 0.125f;
    }
    __syncthreads();

    int r = tid >> 4, kg = tid & 15;
    // pass A: scores; thread covers k = k0 + kg + 16j
    for (int kt = 0; kt < nkt; ++kt) {
        int k0 = kt * 64;
        {
            int kk = tid >> 4, e0 = (tid & 15) * 4;
            #pragma unroll
            for (int it = 0; it < 4; ++it, kk += 16) {
                int krow = k0 + kk;
                float4 v = make_float4(0.f, 0.f, 0.f, 0.f);
                if (krow < Lq) v = *(const float4*)(kp + (size_t)(b * Lq + krow) * 128 + h * 64 + e0);
                *(float4*)&kv[kk][e0] = v;
            }
        }
        __syncthreads();
        float a[4] = {0.f, 0.f, 0.f, 0.f};
        #pragma unroll 4
        for (int e4 = 0; e4 < 64; e4 += 4) {
            float4 q4 = *(const float4*)&qs[r][e4];
            #pragma unroll
            for (int j = 0; j < 4; ++j) {
                float4 k4 = *(const float4*)&kv[kg + 16 * j][e4];
                a[j] = fmaf(q4.x, k4.x, a[j]);
                a[j] = fmaf(q4.y, k4.y, a[j]);
                a[j] = fmaf(q4.z, k4.z, a[j]);
                a[j] = fmaf(q4.w, k4.w, a[j]);
            }
        }
        #pragma unroll
        for (int j = 0; j < 4; ++j) {
            int kb = k0 + kg + 16 * j;
            s[r][kb] = (kb < Lq) ? a[j] : -1e30f;
        }
        __syncthreads();
    }

    // pass B: softmax, normalized in place
    int wv = tid >> 6, lane = tid & 63;
    int kend = nkt * 64;
    for (int rr = wv; rr < 16; rr += 4) {
        float m = -1e30f;
        for (int k = lane; k < kend; k += 64) m = fmaxf(m, s[rr][k]);
        m = wave_reduce_max(m);
        float sum = 0.f;
        for (int k = lane; k < kend; k += 64) {
            float e = expf(s[rr][k] - m);
            s[rr][k] = e;
            sum += e;
        }
        sum = wave_reduce_sum(sum);
        float inv = 1.f / sum;
        for (int k = lane; k < kend; k += 64) s[rr][k] *= inv;
    }

    // pass C: PV; thread = (row r, dims d0..d0+3)
    int dg = tid & 15, d0 = dg * 4;
    float o0 = 0.f, o1 = 0.f, o2 = 0.f, o3 = 0.f;
    for (int kt = 0; kt < nkt; ++kt) {
        int k0 = kt * 64;
        __syncthreads();
        {
            int kk = tid >> 4, e0 = (tid & 15) * 4;
            #pragma unroll
            for (int it = 0; it < 4; ++it, kk += 16) {
                int krow = k0 + kk;
                float4 v = make_float4(0.f, 0.f, 0.f, 0.f);
                if (krow < Lq) v = *(const float4*)(vp + (size_t)(b * Lq + krow) * 128 + h * 64 + e0);
                *(float4*)&kv[kk][e0] = v;
            }
        }
        __syncthreads();
        #pragma unroll 4
        for (int kk = 0; kk < 64; ++kk) {
            float p = s[r][k0 + kk];
            float4 v4 = *(const float4*)&kv[kk][d0];
            o0 = fmaf(p, v4.x, o0);
            o1 = fmaf(p, v4.y, o1);
            o2 = fmaf(p, v4.z, o2);
            o3 = fmaf(p, v4.w, o3);
        }
    }
    int qr = q0 + r;
    if (qr < Lq)
        *(float4*)(outp + (size_t)(b * Lq + qr) * 128 + h * 64 + d0) = make_float4(o0, o1, o2, o3);
}

// ---------------------------------------------------------------------------
__global__ void add_ln_kernel(const float* xin, const float* resid,
                              const float* g, const float* bt, float* out) {
    int row = blockIdx.x, j = threadIdx.x;
    size_t off = (size_t)row * 128 + j;
    float v = xin[off] + resid[off];
    __shared__ float red[2];
    int wave = j >> 6, lane = j & 63;
    float s = wave_reduce_sum(v);
    if (lane == 0) red[wave] = s;
    __syncthreads();
    float mean = (red[0] + red[1]) * 0.0078125f;
    float d = v - mean;
    __syncthreads();
    float s2 = wave_reduce_sum(d * d);
    if (lane == 0) red[wave] = s2;
    __syncthreads();
    float var = (red[0] + red[1]) * 0.0078125f;
    out[off] = d * rsqrtf(var + 1e-5f) * g[j] + bt[j];
}

// ---------------------------------------------------------------------------
__global__ void assemble_kernel(float* dst, const float* cls_emb, const float* body,
                                const float* pos, int Lbody, int use_pos) {
    int r = blockIdx.x;
    int b = blockIdx.y;
    int j = threadIdx.x;  // 128
    float v = (r == 0) ? cls_emb[j] : body[((size_t)b * Lbody + (r - 1)) * 128 + j];
    if (use_pos) v += pos[r * 128 + j];
    dst[((size_t)b * (Lbody + 1) + r) * 128 + j] = v;
}

// ---------------------------------------------------------------------------
__global__ void finalize_kernel(const float* clsraw, const float* h2, float* out, int total) {
    int idx = blockIdx.x * 256 + threadIdx.x;
    if (idx >= total) return;
    float v;
    if (idx < 1024) {
        v = tanhf(clsraw[idx]);
    } else {
        int t = idx - 1024;
        int b = t >> 16;
        int rem = t & 65535;
        int i = rem >> 7, j = rem & 127;
        v = h2[((size_t)(b * 513 + 1 + i)) * 128 + j];
    }
    out[idx] = v;
}

// ---------------------------------------------------------------------------
extern "C" void kernel_launch(void* const* d_in, const int* in_sizes, int n_in,
                              void* d_out, int out_size, void* d_ws, size_t ws_size,
                              hipStream_t stream) {
    float* w = (float*)d_ws;
    size_t off = 0;
    auto alloc = [&](size_t n) {
        float* p = w + off;
        off += (n + 3) & ~(size_t)3;
        return p;
    };

    int* flag = (int*)alloc(4);

    ConvArgs ca;
    int nn = n_in < 32 ? n_in : 32;
    int max_n = 0;
    float* fin[32];
    for (int i = 0; i < nn; ++i) {
        ca.src[i] = d_in[i];
        ca.n[i] = in_sizes[i];
        fin[i] = alloc(in_sizes[i]);
        ca.dstoff[i] = (int)(fin[i] - w);
        if (in_sizes[i] > max_n) max_n = in_sizes[i];
    }
    for (int i = nn; i < 32; ++i) { ca.src[i] = nullptr; ca.n[i] = 0; ca.dstoff[i] = 0; }

    const float* x     = fin[0];
    const float* ts    = fin[1];
    const float* w_per = fin[2];  const float* b_per = fin[3];
    const float* w_lin = fin[4];  const float* b_lin = fin[5];
    const float* Wq_t  = fin[6];  const float* bq_t  = fin[7];
    const float* Wk_t  = fin[8];  const float* bk_t  = fin[9];
    const float* Wo_t  = fin[10]; const float* bo_t  = fin[11];
    const float* pos_emb = fin[12]; const float* cls_emb = fin[13];
    const float* tWq = fin[14]; const float* tbq = fin[15];
    const float* tWk = fin[16]; const float* tbk = fin[17];
    const float* tWv = fin[18]; const float* tbv = fin[19];
    const float* tWo = fin[20]; const float* tbo = fin[21];
    const float* ln1_g = fin[22]; const float* ln1_b = fin[23];
    const float* fW1 = fin[24]; const float* fb1 = fin[25];
    const float* fW2 = fin[26]; const float* fb2 = fin[27];
    const float* ln2_g = fin[28]; const float* ln2_b = fin[29];
    const float* pW = fin[30]; const float* pb = fin[31];

    float* key_e   = alloc(4096 * 128);
    float* cls_e   = alloc(128 * 128);
    float* qp_main = alloc(4096 * 128);
    float* kp_main = alloc(4096 * 128);
    float* qp_cls  = alloc(128 * 128);
    float* att_all = alloc(5120 * 32);
    float* att_cls = att_all;
    float* att_mn  = att_all + 1024 * 32;
    float* mta_all = qp_main;                 // alias: qp/kp dead after mta_att
    float* mta_cls = mta_all;
    float* mta_out = mta_all + 1024 * 128;
    float* xin_c   = alloc(8 * 129 * 128);
    float* xin_m   = alloc(8 * 513 * 128);
    float* tb_q    = alloc(8 * 513 * 128);
    float* tb_k    = alloc(8 * 513 * 128);
    float* tb_v    = alloc(8 * 513 * 128);
    float* tb_a    = alloc(8 * 513 * 128);
    float* tb_o    = tb_q;     // alias
    float* tb_x1   = alloc(8 * 513 * 128);
    float* tb_f1   = tb_k;     // alias
    float* tb_f2   = tb_v;     // alias
    float* x2_c    = alloc(8 * 129 * 128);
    float* x2_m    = alloc(8 * 513 * 128);
    float* clsraw  = alloc(8 * 128);
    (void)ws_size;

    detect_kernel<<<1, 1, 0, stream>>>((const unsigned short*)d_in[22], flag);
    convert_inputs_kernel<<<dim3((max_n + 255) / 256, 32), 256, 0, stream>>>(ca, w, flag);

    time_emb_kernel<<<4224, 128, 0, stream>>>(ts, w_per, b_per, w_lin, b_lin, key_e, cls_e);

    {   // mta projections batched
        GemmBatch p{};
        p.A[0] = key_e; p.W[0] = Wk_t; p.bias[0] = bk_t; p.C[0] = kp_main;
        p.lda[0] = 128; p.ldc[0] = 128; p.M[0] = 4096; p.K[0] = 128; p.act[0] = 0;
        p.A[1] = key_e; p.W[1] = Wq_t; p.bias[1] = bq_t; p.C[1] = qp_main;
        p.lda[1] = 128; p.ldc[1] = 128; p.M[1] = 4096; p.K[1] = 128; p.act[1] = 0;
        p.A[2] = cls_e; p.W[2] = Wq_t; p.bias[2] = bq_t; p.C[2] = qp_cls;
        p.lda[2] = 128; p.ldc[2] = 128; p.M[2] = 128; p.K[2] = 128; p.act[2] = 0;
        gemm16b_kernel<<<dim3(256, 3), 256, 0, stream>>>(p);
    }

    mta_att_kernel<<<dim3(40, 2, 8), 256, 0, stream>>>(qp_cls, qp_main, kp_main, x, att_cls, att_mn);

    {   // mta out-projection, 5120 contiguous rows (K=32)
        GemmBatch p{};
        p.A[0] = att_all; p.W[0] = Wo_t; p.bias[0] = bo_t; p.C[0] = mta_all;
        p.lda[0] = 32; p.ldc[0] = 128; p.M[0] = 5120; p.K[0] = 32; p.act[0] = 0;
        gemm16b_kernel<<<dim3(320, 1), 256, 0, stream>>>(p);
    }

    assemble_kernel<<<dim3(129, 8), 128, 0, stream>>>(xin_c, cls_emb, mta_cls, pos_emb, 128, 0);
    assemble_kernel<<<dim3(513, 8), 128, 0, stream>>>(xin_m, cls_emb, mta_out, pos_emb, 512, 1);

    auto single_gemm = [&](const float* A, int lda, const float* W, const float* bias,
                           float* C, int ldc, int M, int K, int act) {
        GemmBatch p{};
        p.A[0] = A; p.W[0] = W; p.bias[0] = bias; p.C[0] = C;
        p.lda[0] = lda; p.ldc[0] = ldc; p.M[0] = M; p.K[0] = K; p.act[0] = act;
        gemm16b_kernel<<<dim3((M + 15) / 16, 1), 256, 0, stream>>>(p);
    };

    auto tblock = [&](const float* xin, float* x2, int Lq) {
        int Mr = 8 * Lq;
        {
            GemmBatch p{};
            const float* Ws[3] = {tWq, tWk, tWv};
            const float* bs[3] = {tbq, tbk, tbv};
            float* Cs[3] = {tb_q, tb_k, tb_v};
            for (int y = 0; y < 3; ++y) {
                p.A[y] = xin; p.W[y] = Ws[y]; p.bias[y] = bs[y]; p.C[y] = Cs[y];
                p.lda[y] = 128; p.ldc[y] = 128; p.M[y] = Mr; p.K[y] = 128; p.act[y] = 0;
            }
            gemm16b_kernel<<<dim3((Mr + 15) / 16, 3), 256, 0, stream>>>(p);
        }
        tb_att_kernel<<<dim3((Lq + 15) / 16, 2, 8), 256, 0, stream>>>(tb_q, tb_k, tb_v, tb_a, Lq);
        single_gemm(tb_a, 128, tWo, tbo, tb_o, 128, Mr, 128, 0);
        add_ln_kernel<<<Mr, 128, 0, stream>>>(xin, tb_o, ln1_g, ln1_b, tb_x1);
        single_gemm(tb_x1, 128, fW1, fb1, tb_f1, 128, Mr, 128, 1);
        single_gemm(tb_f1, 128, fW2, fb2, tb_f2, 128, Mr, 128, 0);
        add_ln_kernel<<<Mr, 128, 0, stream>>>(tb_x1, tb_f2, ln2_g, ln2_b, x2);
    };

    tblock(xin_c, x2_c, 129);
    tblock(xin_m, x2_m, 513);

    single_gemm(x2_c, 129 * 128, pW, pb, clsraw, 128, 8, 128, 0);

    finalize_kernel<<<(out_size + 255) / 256, 256, 0, stream>>>(clsraw, x2_m, (float*)d_out, out_size);
}

// Round 8
// 382.672 us; speedup vs baseline: 2.3161x; 1.2819x over previous
//
#include <hip/hip_runtime.h>
#include <hip/hip_bf16.h>
#include <math.h>

// TimeBERT forward on MI355X. Inputs fp32 (runtime bf16 detector kept).
// Internal fp32 (attention p-weights stored bf16 in LDS). OUTPUT FP32:
// [cls_pooling (8,128) | last_hidden (8,512,128)].
//
// R8: (1) tb_att score buffer -> bf16 ushort (LDS 59->41 KB, 3 blocks/CU);
// (2) cls+main tblocks merged into one 5136-row pipeline (1 launch per op).

static constexpr int B_ = 8, L_ = 512, DIM_ = 8, ET_ = 128, HID_ = 128, H_ = 2;
static constexpr int NM_ = 8 * 513;           // 4104 main rows
static constexpr int NC_ = 8 * 129;           // 1032 cls rows
static constexpr int NT_ = NM_ + NC_;         // 5136 total

using bf = __hip_bfloat16;

__device__ __forceinline__ float wave_reduce_sum(float v) {
    #pragma unroll
    for (int off = 32; off >= 1; off >>= 1) v += __shfl_xor(v, off);
    return v;
}
__device__ __forceinline__ float wave_reduce_max(float v) {
    #pragma unroll
    for (int off = 32; off >= 1; off >>= 1) v = fmaxf(v, __shfl_xor(v, off));
    return v;
}
__device__ __forceinline__ float u2f(unsigned short u) {
    return __uint_as_float(((unsigned)u) << 16);
}
__device__ __forceinline__ unsigned short f2u(float f) {
    return (unsigned short)(__float_as_uint(f) >> 16);
}

// ---------------------------------------------------------------------------
__global__ void detect_kernel(const unsigned short* ln1_g_raw, int* flag) {
    if (threadIdx.x == 0 && blockIdx.x == 0)
        *flag = (ln1_g_raw[0] == 0x3F80u) ? 1 : 0;
}

struct ConvArgs {
    const void* src[32];
    int n[32];
    int dstoff[32];
};
__global__ void convert_inputs_kernel(ConvArgs a, float* dst, const int* flag) {
    int which = blockIdx.y;
    int n = a.n[which];
    int i = blockIdx.x * 256 + threadIdx.x;
    if (i >= n) return;
    float v;
    if (*flag) v = __bfloat162float(((const bf*)a.src[which])[i]);
    else       v = ((const float*)a.src[which])[i];
    dst[a.dstoff[which] + i] = v;
}

// ---------------------------------------------------------------------------
__global__ void time_emb_kernel(const float* ts, const float* w_per, const float* b_per,
                                const float* w_lin, const float* b_lin,
                                float* key_e, float* cls_e) {
    int row = blockIdx.x, j = threadIdx.x;  // 128 threads
    float t;
    float* out;
    if (row < 4096) { t = ts[row]; out = key_e + (size_t)row * 128; }
    else { t = (float)(row - 4096) * (1.0f / 127.0f); out = cls_e + (size_t)(row - 4096) * 128; }
    float v;
    if (j == 0) v = t * w_lin[0] + b_lin[0];
    else        v = sinf(t * w_per[j - 1] + b_per[j - 1]);
    out[j] = v;
}

// ---------------------------------------------------------------------------
struct GemmBatch {
    const float* A[3]; const float* W[3]; const float* bias[3]; float* C[3];
    int lda[3], ldc[3], M[3], K[3], act[3];
};
__global__ void gemm16b_kernel(GemmBatch p) {
    int y = blockIdx.y;
    const float* A = p.A[y]; const float* W = p.W[y]; const float* bias = p.bias[y];
    float* C = p.C[y];
    int lda = p.lda[y], ldc = p.ldc[y], M = p.M[y], K = p.K[y], act = p.act[y];
    int m0 = blockIdx.x * 16;
    if (m0 >= M) return;
    __shared__ float As[16][132];
    int tid = threadIdx.x;
    int r = tid >> 4, g = tid & 15, c0 = g * 8;
    for (int c = g; c < K; c += 16) {
        float v = 0.f;
        if (m0 + r < M) v = A[(size_t)(m0 + r) * lda + c];
        As[r][c] = v;
    }
    __syncthreads();
    float acc[8];
    #pragma unroll
    for (int j = 0; j < 8; ++j) acc[j] = bias[c0 + j];
    for (int k = 0; k < K; ++k) {
        float a = As[r][k];
        const float4 w0 = *(const float4*)(W + (size_t)k * 128 + c0);
        const float4 w1 = *(const float4*)(W + (size_t)k * 128 + c0 + 4);
        acc[0] = fmaf(a, w0.x, acc[0]); acc[1] = fmaf(a, w0.y, acc[1]);
        acc[2] = fmaf(a, w0.z, acc[2]); acc[3] = fmaf(a, w0.w, acc[3]);
        acc[4] = fmaf(a, w1.x, acc[4]); acc[5] = fmaf(a, w1.y, acc[5]);
        acc[6] = fmaf(a, w1.z, acc[6]); acc[7] = fmaf(a, w1.w, acc[7]);
    }
    if (act == 1) {
        #pragma unroll
        for (int j = 0; j < 8; ++j) acc[j] = fmaxf(acc[j], 0.f);
    }
    if (m0 + r < M) {
        *(float4*)(C + (size_t)(m0 + r) * ldc + c0) = make_float4(acc[0], acc[1], acc[2], acc[3]);
        *(float4*)(C + (size_t)(m0 + r) * ldc + c0 + 4) = make_float4(acc[4], acc[5], acc[6], acc[7]);
    }
}

// ---------------------------------------------------------------------------
// mta attention (unchanged from R7): merged cls+main, 16 q-rows/block.
__global__ void __launch_bounds__(256, 2)
mta_att_kernel(const float* qp_cls, const float* qp_main, const float* kp,
               const float* x, float* att_cls, float* att_mn) {
    int is_cls = (blockIdx.x >= 32);
    int qt = is_cls ? (blockIdx.x - 32) : blockIdx.x;
    int h = blockIdx.y, b = blockIdx.z;
    int tid = threadIdx.x;  // 256
    __shared__ float qs[16][68];   // reused as xv[64][17] in masked pass
    __shared__ float kv[64][68];
    __shared__ float s[16][520];
    float* xv = &qs[0][0];
    int q0 = qt * 16;

    {
        int r = tid >> 4, c0 = (tid & 15) * 4;
        const float* qrow = is_cls ? (qp_cls + (size_t)(q0 + r) * 128 + h * 64)
                                   : (qp_main + (size_t)(b * 512 + q0 + r) * 128 + h * 64);
        float4 v = *(const float4*)(qrow + c0);
        qs[r][c0] = v.x * 0.125f; qs[r][c0 + 1] = v.y * 0.125f;
        qs[r][c0 + 2] = v.z * 0.125f; qs[r][c0 + 3] = v.w * 0.125f;
    }
    __syncthreads();

    int r = tid >> 4, kg = tid & 15;
    for (int kt = 0; kt < 8; ++kt) {
        int k0 = kt * 64;
        {
            int kk = tid >> 4, e0 = (tid & 15) * 4;
            #pragma unroll
            for (int it = 0; it < 4; ++it, kk += 16) {
                float4 v = *(const float4*)(kp + (size_t)(b * 512 + k0 + kk) * 128 + h * 64 + e0);
                *(float4*)&kv[kk][e0] = v;
            }
        }
        __syncthreads();
        float a[4] = {0.f, 0.f, 0.f, 0.f};
        #pragma unroll 4
        for (int e4 = 0; e4 < 64; e4 += 4) {
            float4 q4 = *(const float4*)&qs[r][e4];
            #pragma unroll
            for (int j = 0; j < 4; ++j) {
                float4 k4 = *(const float4*)&kv[kg + 16 * j][e4];
                a[j] = fmaf(q4.x, k4.x, a[j]);
                a[j] = fmaf(q4.y, k4.y, a[j]);
                a[j] = fmaf(q4.z, k4.z, a[j]);
                a[j] = fmaf(q4.w, k4.w, a[j]);
            }
        }
        #pragma unroll
        for (int j = 0; j < 4; ++j) s[r][k0 + kg + 16 * j] = a[j];
        __syncthreads();
    }

    int wv = tid >> 6, lane = tid & 63;
    for (int rr = wv; rr < 16; rr += 4) {
        float m = -1e30f;
        for (int k = lane; k < 512; k += 64) m = fmaxf(m, s[rr][k]);
        m = wave_reduce_max(m);
        for (int k = lane; k < 512; k += 64) s[rr][k] = expf(s[rr][k] - m);
    }

    int d = lane >> 3, sub = lane & 7;
    int qb = wv * 4;
    float num[4] = {0.f, 0.f, 0.f, 0.f}, den[4] = {0.f, 0.f, 0.f, 0.f};
    for (int kt = 0; kt < 8; ++kt) {
        int k0 = kt * 64;
        __syncthreads();
        {
            int kk = tid >> 2, c0 = (tid & 3) * 4;
            float4 v = *(const float4*)(x + (size_t)(b * 512 + k0 + kk) * 16 + c0);
            xv[kk * 17 + c0] = v.x; xv[kk * 17 + c0 + 1] = v.y;
            xv[kk * 17 + c0 + 2] = v.z; xv[kk * 17 + c0 + 3] = v.w;
        }
        __syncthreads();
        #pragma unroll
        for (int i = 0; i < 8; ++i) {
            int kk = sub + 8 * i;
            float mk = xv[kk * 17 + 8 + d];
            float vv = xv[kk * 17 + d];
            #pragma unroll
            for (int q = 0; q < 4; ++q) {
                float em = s[qb + q][k0 + kk] * mk;
                den[q] += em;
                num[q] = fmaf(em, vv, num[q]);
            }
        }
    }
    #pragma unroll
    for (int q = 0; q < 4; ++q) {
        #pragma unroll
        for (int off2 = 4; off2 >= 1; off2 >>= 1) {
            num[q] += __shfl_xor(num[q], off2);
            den[q] += __shfl_xor(den[q], off2);
        }
        if (sub == 0) {
            int row = q0 + qb + q;
            float* dst = is_cls ? (att_cls + (size_t)(b * 128 + row) * 32)
                                : (att_mn + (size_t)(b * 512 + row) * 32);
            dst[h * 16 + d] = num[q] / den[q];
            dst[h * 16 + 8 + d] = 1.0f;
        }
    }
}

// ---------------------------------------------------------------------------
// tblock attention, merged main(Lq=513, x<33) + cls(Lq=129, x>=33).
// Rows: main at base b*513; cls at 4104 + b*129. Scores/p stored bf16 in LDS
// (41 KB total -> 3 blocks/CU). Normalization via rinv applied at the end.
__global__ void __launch_bounds__(256, 3)
tb_att_kernel(const float* qp, const float* kp, const float* vp, float* outp) {
    int is_cls = (blockIdx.x >= 33);
    int qt = is_cls ? blockIdx.x - 33 : blockIdx.x;
    int h = blockIdx.y, b = blockIdx.z;
    int Lq = is_cls ? 129 : 513;
    int base = is_cls ? (4104 + b * 129) : (b * 513);
    int nkt = is_cls ? 3 : 9;
    int tid = threadIdx.x;  // 256
    __shared__ float qs[16][68];
    __shared__ float kv[64][68];
    __shared__ unsigned short sp[16][584];
    __shared__ float rinv[16];
    int q0 = qt * 16;

    {   // load q
        int r = tid >> 4, c0 = (tid & 15) * 4;
        int qr = q0 + r;
        float4 v = make_float4(0.f, 0.f, 0.f, 0.f);
        if (qr < Lq) v = *(const float4*)(qp + (size_t)(base + qr) * 128 + h * 64 + c0);
        qs[r][c0] = v.x * 0.125f; qs[r][c0 + 1] = v.y * 0.125f;
        qs[r][c0 + 2] = v.z * 0.125f; qs[r][c0 + 3] = v.w * 0.125f;
    }
    __syncthreads();

    int r = tid >> 4, kg = tid & 15;
    // pass A: scores -> bf16
    for (int kt = 0; kt < nkt; ++kt) {
        int k0 = kt * 64;
        {
            int kk = tid >> 4, e0 = (tid & 15) * 4;
            #pragma unroll
            for (int it = 0; it < 4; ++it, kk += 16) {
                int krow = k0 + kk;
                float4 v = make_float4(0.f, 0.f, 0.f, 0.f);
                if (krow < Lq) v = *(const float4*)(kp + (size_t)(base + krow) * 128 + h * 64 + e0);
                *(float4*)&kv[kk][e0] = v;
            }
        }
        __syncthreads();
        float a[4] = {0.f, 0.f, 0.f, 0.f};
        #pragma unroll 4
        for (int e4 = 0; e4 < 64; e4 += 4) {
            float4 q4 = *(const float4*)&qs[r][e4];
            #pragma unroll
            for (int j = 0; j < 4; ++j) {
                float4 k4 = *(const float4*)&kv[kg + 16 * j][e4];
                a[j] = fmaf(q4.x, k4.x, a[j]);
                a[j] = fmaf(q4.y, k4.y, a[j]);
                a[j] = fmaf(q4.z, k4.z, a[j]);
                a[j] = fmaf(q4.w, k4.w, a[j]);
            }
        }
        #pragma unroll
        for (int j = 0; j < 4; ++j) {
            int kb = k0 + kg + 16 * j;
            sp[r][kb] = f2u((kb < Lq) ? a[j] : -1e30f);
        }
        __syncthreads();
    }

    // pass B: max + exp (unnormalized e stored bf16); rinv[row] = 1/sum
    int wv = tid >> 6, lane = tid & 63;
    int kend = nkt * 64;
    for (int rr = wv; rr < 16; rr += 4) {
        float m = -1e30f;
        for (int k = lane; k < kend; k += 64) m = fmaxf(m, u2f(sp[rr][k]));
        m = wave_reduce_max(m);
        float sum = 0.f;
        for (int k = lane; k < kend; k += 64) {
            float e = expf(u2f(sp[rr][k]) - m);
            sp[rr][k] = f2u(e);
            sum += e;
        }
        sum = wave_reduce_sum(sum);
        if (lane == 0) rinv[rr] = 1.f / sum;
    }
    __syncthreads();

    // pass C: PV; thread = (row r, dims d0..d0+3); p read as ushort4 -> f32
    int dg = tid & 15, d0 = dg * 4;
    float o0 = 0.f, o1 = 0.f, o2 = 0.f, o3 = 0.f;
    for (int kt = 0; kt < nkt; ++kt) {
        int k0 = kt * 64;
        __syncthreads();
        {
            int kk = tid >> 4, e0 = (tid & 15) * 4;
            #pragma unroll
            for (int it = 0; it < 4; ++it, kk += 16) {
                int krow = k0 + kk;
                float4 v = make_float4(0.f, 0.f, 0.f, 0.f);
                if (krow < Lq) v = *(const float4*)(vp + (size_t)(base + krow) * 128 + h * 64 + e0);
                *(float4*)&kv[kk][e0] = v;
            }
        }
        __syncthreads();
        #pragma unroll 4
        for (int kk = 0; kk < 64; kk += 4) {
            ushort4 pu = *(const ushort4*)&sp[r][k0 + kk];
            float p0 = u2f(pu.x), p1 = u2f(pu.y), p2 = u2f(pu.z), p3 = u2f(pu.w);
            float4 v0 = *(const float4*)&kv[kk][d0];
            float4 v1 = *(const float4*)&kv[kk + 1][d0];
            float4 v2 = *(const float4*)&kv[kk + 2][d0];
            float4 v3 = *(const float4*)&kv[kk + 3][d0];
            o0 = fmaf(p0, v0.x, fmaf(p1, v1.x, fmaf(p2, v2.x, fmaf(p3, v3.x, o0))));
            o1 = fmaf(p0, v0.y, fmaf(p1, v1.y, fmaf(p2, v2.y, fmaf(p3, v3.y, o1))));
            o2 = fmaf(p0, v0.z, fmaf(p1, v1.z, fmaf(p2, v2.z, fmaf(p3, v3.z, o2))));
            o3 = fmaf(p0, v0.w, fmaf(p1, v1.w, fmaf(p2, v2.w, fmaf(p3, v3.w, o3))));
        }
    }
    float inv = rinv[r];
    int qr = q0 + r;
    if (qr < Lq)
        *(float4*)(outp + (size_t)(base + qr) * 128 + h * 64 + d0) =
            make_float4(o0 * inv, o1 * inv, o2 * inv, o3 * inv);
}

// ---------------------------------------------------------------------------
__global__ void add_ln_kernel(const float* xin, const float* resid,
                              const float* g, const float* bt, float* out) {
    int row = blockIdx.x, j = threadIdx.x;
    size_t off = (size_t)row * 128 + j;
    float v = xin[off] + resid[off];
    __shared__ float red[2];
    int wave = j >> 6, lane = j & 63;
    float s = wave_reduce_sum(v);
    if (lane == 0) red[wave] = s;
    __syncthreads();
    float mean = (red[0] + red[1]) * 0.0078125f;
    float d = v - mean;
    __syncthreads();
    float s2 = wave_reduce_sum(d * d);
    if (lane == 0) red[wave] = s2;
    __syncthreads();
    float var = (red[0] + red[1]) * 0.0078125f;
    out[off] = d * rsqrtf(var + 1e-5f) * g[j] + bt[j];
}

// ---------------------------------------------------------------------------
// Build merged xin: rows [0,4104) = main (cls_emb/mta_out + pos);
// rows [4104,5136) = cls problem (cls_emb/mta_cls, no pos).
__global__ void assemble_kernel(float* xin, const float* cls_emb, const float* mta_cls,
                                const float* mta_out, const float* pos) {
    int xr = blockIdx.x;  // 0..641
    int b = blockIdx.y;
    int j = threadIdx.x;  // 128
    if (xr < 513) {
        int r = xr;
        float v = (r == 0) ? cls_emb[j] : mta_out[(size_t)(b * 512 + r - 1) * 128 + j];
        v += pos[r * 128 + j];
        xin[(size_t)(b * 513 + r) * 128 + j] = v;
    } else {
        int r = xr - 513;
        float v = (r == 0) ? cls_emb[j] : mta_cls[(size_t)(b * 128 + r - 1) * 128 + j];
        xin[(size_t)(4104 + b * 129 + r) * 128 + j] = v;
    }
}

// ---------------------------------------------------------------------------
__global__ void finalize_kernel(const float* clsraw, const float* h2, float* out, int total) {
    int idx = blockIdx.x * 256 + threadIdx.x;
    if (idx >= total) return;
    float v;
    if (idx < 1024) {
        v = tanhf(clsraw[idx]);
    } else {
        int t = idx - 1024;
        int b = t >> 16;
        int rem = t & 65535;
        int i = rem >> 7, j = rem & 127;
        v = h2[((size_t)(b * 513 + 1 + i)) * 128 + j];
    }
    out[idx] = v;
}

// ---------------------------------------------------------------------------
extern "C" void kernel_launch(void* const* d_in, const int* in_sizes, int n_in,
                              void* d_out, int out_size, void* d_ws, size_t ws_size,
                              hipStream_t stream) {
    float* w = (float*)d_ws;
    size_t off = 0;
    auto alloc = [&](size_t n) {
        float* p = w + off;
        off += (n + 3) & ~(size_t)3;
        return p;
    };

    int* flag = (int*)alloc(4);

    ConvArgs ca;
    int nn = n_in < 32 ? n_in : 32;
    int max_n = 0;
    float* fin[32];
    for (int i = 0; i < nn; ++i) {
        ca.src[i] = d_in[i];
        ca.n[i] = in_sizes[i];
        fin[i] = alloc(in_sizes[i]);
        ca.dstoff[i] = (int)(fin[i] - w);
        if (in_sizes[i] > max_n) max_n = in_sizes[i];
    }
    for (int i = nn; i < 32; ++i) { ca.src[i] = nullptr; ca.n[i] = 0; ca.dstoff[i] = 0; }

    const float* x     = fin[0];
    const float* ts    = fin[1];
    const float* w_per = fin[2];  const float* b_per = fin[3];
    const float* w_lin = fin[4];  const float* b_lin = fin[5];
    const float* Wq_t  = fin[6];  const float* bq_t  = fin[7];
    const float* Wk_t  = fin[8];  const float* bk_t  = fin[9];
    const float* Wo_t  = fin[10]; const float* bo_t  = fin[11];
    const float* pos_emb = fin[12]; const float* cls_emb = fin[13];
    const float* tWq = fin[14]; const float* tbq = fin[15];
    const float* tWk = fin[16]; const float* tbk = fin[17];
    const float* tWv = fin[18]; const float* tbv = fin[19];
    const float* tWo = fin[20]; const float* tbo = fin[21];
    const float* ln1_g = fin[22]; const float* ln1_b = fin[23];
    const float* fW1 = fin[24]; const float* fb1 = fin[25];
    const float* fW2 = fin[26]; const float* fb2 = fin[27];
    const float* ln2_g = fin[28]; const float* ln2_b = fin[29];
    const float* pW = fin[30]; const float* pb = fin[31];

    float* key_e   = alloc(4096 * 128);
    float* cls_e   = alloc(128 * 128);
    float* qp_main = alloc(4096 * 128);
    float* kp_main = alloc(4096 * 128);   // must stay adjacent after qp_main (mta_all overlay)
    float* qp_cls  = alloc(128 * 128);
    float* att_all = alloc(5120 * 32);
    float* att_cls = att_all;
    float* att_mn  = att_all + 1024 * 32;
    float* mta_all = qp_main;             // 5120x128 overlay: qp_main + head of kp_main (both dead)
    float* mta_cls = mta_all;
    float* mta_out = mta_all + 1024 * 128;
    float* xin     = alloc((size_t)NT_ * 128);
    float* tb_q    = alloc((size_t)NT_ * 128);
    float* tb_k    = alloc((size_t)NT_ * 128);
    float* tb_v    = alloc((size_t)NT_ * 128);
    float* tb_a    = alloc((size_t)NT_ * 128);
    float* tb_o    = tb_q;     // alias
    float* tb_x1   = alloc((size_t)NT_ * 128);
    float* tb_f1   = tb_k;     // alias
    float* tb_f2   = tb_v;     // alias
    float* x2      = alloc((size_t)NT_ * 128);
    float* clsraw  = alloc(8 * 128);
    (void)ws_size;

    detect_kernel<<<1, 1, 0, stream>>>((const unsigned short*)d_in[22], flag);
    convert_inputs_kernel<<<dim3((max_n + 255) / 256, 32), 256, 0, stream>>>(ca, w, flag);

    time_emb_kernel<<<4224, 128, 0, stream>>>(ts, w_per, b_per, w_lin, b_lin, key_e, cls_e);

    {   // mta projections batched
        GemmBatch p{};
        p.A[0] = key_e; p.W[0] = Wk_t; p.bias[0] = bk_t; p.C[0] = kp_main;
        p.lda[0] = 128; p.ldc[0] = 128; p.M[0] = 4096; p.K[0] = 128; p.act[0] = 0;
        p.A[1] = key_e; p.W[1] = Wq_t; p.bias[1] = bq_t; p.C[1] = qp_main;
        p.lda[1] = 128; p.ldc[1] = 128; p.M[1] = 4096; p.K[1] = 128; p.act[1] = 0;
        p.A[2] = cls_e; p.W[2] = Wq_t; p.bias[2] = bq_t; p.C[2] = qp_cls;
        p.lda[2] = 128; p.ldc[2] = 128; p.M[2] = 128; p.K[2] = 128; p.act[2] = 0;
        gemm16b_kernel<<<dim3(256, 3), 256, 0, stream>>>(p);
    }

    mta_att_kernel<<<dim3(40, 2, 8), 256, 0, stream>>>(qp_cls, qp_main, kp_main, x, att_cls, att_mn);

    {   // mta out-projection, 5120 contiguous rows (K=32)
        GemmBatch p{};
        p.A[0] = att_all; p.W[0] = Wo_t; p.bias[0] = bo_t; p.C[0] = mta_all;
        p.lda[0] = 32; p.ldc[0] = 128; p.M[0] = 5120; p.K[0] = 32; p.act[0] = 0;
        gemm16b_kernel<<<dim3(320, 1), 256, 0, stream>>>(p);
    }

    assemble_kernel<<<dim3(642, 8), 128, 0, stream>>>(xin, cls_emb, mta_cls, mta_out, pos_emb);

    auto single_gemm = [&](const float* A, int lda, const float* W, const float* bias,
                           float* C, int ldc, int M, int K, int act) {
        GemmBatch p{};
        p.A[0] = A; p.W[0] = W; p.bias[0] = bias; p.C[0] = C;
        p.lda[0] = lda; p.ldc[0] = ldc; p.M[0] = M; p.K[0] = K; p.act[0] = act;
        gemm16b_kernel<<<dim3((M + 15) / 16, 1), 256, 0, stream>>>(p);
    };

    // --- merged tblock over 5136 rows ---
    {   // QKV batched
        GemmBatch p{};
        const float* Ws[3] = {tWq, tWk, tWv};
        const float* bs[3] = {tbq, tbk, tbv};
        float* Cs[3] = {tb_q, tb_k, tb_v};
        for (int y = 0; y < 3; ++y) {
            p.A[y] = xin; p.W[y] = Ws[y]; p.bias[y] = bs[y]; p.C[y] = Cs[y];
            p.lda[y] = 128; p.ldc[y] = 128; p.M[y] = NT_; p.K[y] = 128; p.act[y] = 0;
        }
        gemm16b_kernel<<<dim3((NT_ + 15) / 16, 3), 256, 0, stream>>>(p);
    }
    tb_att_kernel<<<dim3(42, 2, 8), 256, 0, stream>>>(tb_q, tb_k, tb_v, tb_a);
    single_gemm(tb_a, 128, tWo, tbo, tb_o, 128, NT_, 128, 0);
    add_ln_kernel<<<NT_, 128, 0, stream>>>(xin, tb_o, ln1_g, ln1_b, tb_x1);
    single_gemm(tb_x1, 128, fW1, fb1, tb_f1, 128, NT_, 128, 1);
    single_gemm(tb_f1, 128, fW2, fb2, tb_f2, 128, NT_, 128, 0);
    add_ln_kernel<<<NT_, 128, 0, stream>>>(tb_x1, tb_f2, ln2_g, ln2_b, x2);

    // cls pooling: rows x2[4104 + b*129 + 0]
    single_gemm(x2 + (size_t)4104 * 128, 129 * 128, pW, pb, clsraw, 128, 8, 128, 0);

    finalize_kernel<<<(out_size + 255) / 256, 256, 0, stream>>>(clsraw, x2, (float*)d_out, out_size);
}

// Round 9
// 288.660 us; speedup vs baseline: 3.0705x; 1.3257x over previous
//
#include <hip/hip_runtime.h>
#include <hip/hip_bf16.h>
#include <math.h>

// TimeBERT forward on MI355X. Inputs fp32 (runtime bf16 detector kept).
// OUTPUT FP32: [cls_pooling (8,128) | last_hidden (8,512,128)].
//
// R9: (1) all K=128 GEMMs moved to MFMA 16x16x32_bf16 (weights pre-swizzled
// to B-frag order, A staged bf16 in LDS, fp32 accum, bias/relu epilogue);
// (2) mta_att score buffer -> bf16 (LDS 55->38 KB, 4 blocks/CU);
// (3) bf16 rounding = RNE everywhere (was trunc).

static constexpr int B_ = 8, L_ = 512, DIM_ = 8, ET_ = 128, HID_ = 128, H_ = 2;
static constexpr int NM_ = 8 * 513;           // 4104 main rows
static constexpr int NC_ = 8 * 129;           // 1032 cls rows
static constexpr int NT_ = NM_ + NC_;         // 5136 total

using bf = __hip_bfloat16;
typedef __attribute__((ext_vector_type(8))) short bf16x8;
typedef __attribute__((ext_vector_type(4))) float floatx4;

__device__ __forceinline__ float wave_reduce_sum(float v) {
    #pragma unroll
    for (int off = 32; off >= 1; off >>= 1) v += __shfl_xor(v, off);
    return v;
}
__device__ __forceinline__ float wave_reduce_max(float v) {
    #pragma unroll
    for (int off = 32; off >= 1; off >>= 1) v = fmaxf(v, __shfl_xor(v, off));
    return v;
}
__device__ __forceinline__ float u2f(unsigned short u) {
    return __uint_as_float(((unsigned)u) << 16);
}
// RNE float->bf16 (values here are finite; no NaN guard needed)
__device__ __forceinline__ unsigned short f2u(float f) {
    unsigned u = __float_as_uint(f);
    return (unsigned short)((u + 0x7FFF + ((u >> 16) & 1)) >> 16);
}

// ---------------------------------------------------------------------------
__global__ void detect_kernel(const unsigned short* ln1_g_raw, int* flag) {
    if (threadIdx.x == 0 && blockIdx.x == 0)
        *flag = (ln1_g_raw[0] == 0x3F80u) ? 1 : 0;
}

struct ConvArgs {
    const void* src[32];
    int n[32];
    int dstoff[32];
};
__global__ void convert_inputs_kernel(ConvArgs a, float* dst, const int* flag) {
    int which = blockIdx.y;
    int n = a.n[which];
    int i = blockIdx.x * 256 + threadIdx.x;
    if (i >= n) return;
    float v;
    if (*flag) v = __bfloat162float(((const bf*)a.src[which])[i]);
    else       v = ((const float*)a.src[which])[i];
    dst[a.dstoff[which] + i] = v;
}

// ---------------------------------------------------------------------------
__global__ void time_emb_kernel(const float* ts, const float* w_per, const float* b_per,
                                const float* w_lin, const float* b_lin,
                                float* key_e, float* cls_e) {
    int row = blockIdx.x, j = threadIdx.x;  // 128 threads
    float t;
    float* out;
    if (row < 4096) { t = ts[row]; out = key_e + (size_t)row * 128; }
    else { t = (float)(row - 4096) * (1.0f / 127.0f); out = cls_e + (size_t)(row - 4096) * 128; }
    float v;
    if (j == 0) v = t * w_lin[0] + b_lin[0];
    else        v = sinf(t * w_per[j - 1] + b_per[j - 1]);
    out[j] = v;
}

// ---------------------------------------------------------------------------
// Pre-swizzle 128x128 fp32 weights into MFMA B-frag order, bf16:
// chunk c = ks*8 + ntile (512 elems): elem (lane l, j) = W[ks*32+(l>>4)*8+j][ntile*16+(l&15)]
struct PrepArgs { const float* src[8]; unsigned short* dst[8]; };
__global__ void prep_weights_kernel(PrepArgs p) {
    int m = blockIdx.y;
    const float* W = p.src[m];
    unsigned short* D = p.dst[m];
    int idx = blockIdx.x * 256 + threadIdx.x;   // 0..16383
    int c = idx >> 9;
    int l = (idx >> 3) & 63;
    int j = idx & 7;
    int k = (c >> 3) * 32 + (l >> 4) * 8 + j;
    int n = (c & 7) * 16 + (l & 15);
    D[idx] = f2u(W[k * 128 + n]);
}

// ---------------------------------------------------------------------------
// MFMA GEMM: C[m,n] = act(A[m,:128] @ W + bias), 16 rows/block, 256 thr.
// A fp32 (lda=128), W pre-swizzled bf16, C fp32 (ldc=128). Up to 3 sub-gemms.
struct GemmM {
    const float* A[3]; const unsigned short* W[3]; const float* bias[3]; float* C[3];
    int M[3]; int act[3];
};
__global__ void __launch_bounds__(256)
gemm_mfma_kernel(GemmM p) {
    int y = blockIdx.y;
    const float* A = p.A[y]; const unsigned short* Wsw = p.W[y];
    const float* bias = p.bias[y]; float* C = p.C[y];
    int M = p.M[y], act = p.act[y];
    int m0 = blockIdx.x * 16;
    if (m0 >= M) return;
    __shared__ unsigned short As[16][136];   // stride 136 -> 16B-aligned frag reads
    int tid = threadIdx.x;
    {   // stage A -> bf16
        int r = tid >> 4, c0 = (tid & 15) * 8;
        float4 v0 = make_float4(0.f, 0.f, 0.f, 0.f), v1 = v0;
        if (m0 + r < M) {
            v0 = *(const float4*)(A + (size_t)(m0 + r) * 128 + c0);
            v1 = *(const float4*)(A + (size_t)(m0 + r) * 128 + c0 + 4);
        }
        ushort4 u0 = make_ushort4(f2u(v0.x), f2u(v0.y), f2u(v0.z), f2u(v0.w));
        ushort4 u1 = make_ushort4(f2u(v1.x), f2u(v1.y), f2u(v1.z), f2u(v1.w));
        *(ushort4*)&As[r][c0] = u0;
        *(ushort4*)&As[r][c0 + 4] = u1;
    }
    __syncthreads();

    int wv = tid >> 6, lane = tid & 63;
    floatx4 acc0 = {0.f, 0.f, 0.f, 0.f}, acc1 = acc0;
    int am = lane & 15, aq = lane >> 4;
    #pragma unroll
    for (int ks = 0; ks < 4; ++ks) {
        bf16x8 af = *(bf16x8*)&As[am][ks * 32 + aq * 8];
        const unsigned short* base = Wsw + ((size_t)ks * 8 + 2 * wv) * 512 + lane * 8;
        bf16x8 b0 = *(const bf16x8*)(base);
        bf16x8 b1 = *(const bf16x8*)(base + 512);
        acc0 = __builtin_amdgcn_mfma_f32_16x16x32_bf16(af, b0, acc0, 0, 0, 0);
        acc1 = __builtin_amdgcn_mfma_f32_16x16x32_bf16(af, b1, acc1, 0, 0, 0);
    }

    // epilogue: C/D map col=lane&15, row=(lane>>4)*4+reg
    int col = lane & 15, rowb = (lane >> 4) * 4;
    #pragma unroll
    for (int t = 0; t < 2; ++t) {
        floatx4 acc = t ? acc1 : acc0;
        int n = wv * 32 + t * 16 + col;
        float bv = bias[n];
        #pragma unroll
        for (int rg = 0; rg < 4; ++rg) {
            int m = m0 + rowb + rg;
            if (m < M) {
                float o = acc[rg] + bv;
                if (act) o = fmaxf(o, 0.f);
                C[(size_t)m * 128 + n] = o;
            }
        }
    }
}

// ---------------------------------------------------------------------------
// Legacy VALU GEMM (kept for K=32 mta-out and the tiny pooling gemm).
struct GemmBatch {
    const float* A[3]; const float* W[3]; const float* bias[3]; float* C[3];
    int lda[3], ldc[3], M[3], K[3], act[3];
};
__global__ void gemm16b_kernel(GemmBatch p) {
    int y = blockIdx.y;
    const float* A = p.A[y]; const float* W = p.W[y]; const float* bias = p.bias[y];
    float* C = p.C[y];
    int lda = p.lda[y], ldc = p.ldc[y], M = p.M[y], K = p.K[y], act = p.act[y];
    int m0 = blockIdx.x * 16;
    if (m0 >= M) return;
    __shared__ float As[16][132];
    int tid = threadIdx.x;
    int r = tid >> 4, g = tid & 15, c0 = g * 8;
    for (int c = g; c < K; c += 16) {
        float v = 0.f;
        if (m0 + r < M) v = A[(size_t)(m0 + r) * lda + c];
        As[r][c] = v;
    }
    __syncthreads();
    float acc[8];
    #pragma unroll
    for (int j = 0; j < 8; ++j) acc[j] = bias[c0 + j];
    for (int k = 0; k < K; ++k) {
        float a = As[r][k];
        const float4 w0 = *(const float4*)(W + (size_t)k * 128 + c0);
        const float4 w1 = *(const float4*)(W + (size_t)k * 128 + c0 + 4);
        acc[0] = fmaf(a, w0.x, acc[0]); acc[1] = fmaf(a, w0.y, acc[1]);
        acc[2] = fmaf(a, w0.z, acc[2]); acc[3] = fmaf(a, w0.w, acc[3]);
        acc[4] = fmaf(a, w1.x, acc[4]); acc[5] = fmaf(a, w1.y, acc[5]);
        acc[6] = fmaf(a, w1.z, acc[6]); acc[7] = fmaf(a, w1.w, acc[7]);
    }
    if (act == 1) {
        #pragma unroll
        for (int j = 0; j < 8; ++j) acc[j] = fmaxf(acc[j], 0.f);
    }
    if (m0 + r < M) {
        *(float4*)(C + (size_t)(m0 + r) * ldc + c0) = make_float4(acc[0], acc[1], acc[2], acc[3]);
        *(float4*)(C + (size_t)(m0 + r) * ldc + c0 + 4) = make_float4(acc[4], acc[5], acc[6], acc[7]);
    }
}

// ---------------------------------------------------------------------------
// mta attention, merged cls+main; scores bf16 in LDS (38 KB -> 4 blocks/CU).
__global__ void __launch_bounds__(256, 4)
mta_att_kernel(const float* qp_cls, const float* qp_main, const float* kp,
               const float* x, float* att_cls, float* att_mn) {
    int is_cls = (blockIdx.x >= 32);
    int qt = is_cls ? (blockIdx.x - 32) : blockIdx.x;
    int h = blockIdx.y, b = blockIdx.z;
    int tid = threadIdx.x;  // 256
    __shared__ float qs[16][68];   // reused as xv[64][17] in masked pass
    __shared__ float kv[64][68];
    __shared__ unsigned short sp[16][520];
    float* xv = &qs[0][0];
    int q0 = qt * 16;

    {
        int r = tid >> 4, c0 = (tid & 15) * 4;
        const float* qrow = is_cls ? (qp_cls + (size_t)(q0 + r) * 128 + h * 64)
                                   : (qp_main + (size_t)(b * 512 + q0 + r) * 128 + h * 64);
        float4 v = *(const float4*)(qrow + c0);
        qs[r][c0] = v.x * 0.125f; qs[r][c0 + 1] = v.y * 0.125f;
        qs[r][c0 + 2] = v.z * 0.125f; qs[r][c0 + 3] = v.w * 0.125f;
    }
    __syncthreads();

    int r = tid >> 4, kg = tid & 15;
    for (int kt = 0; kt < 8; ++kt) {
        int k0 = kt * 64;
        {
            int kk = tid >> 4, e0 = (tid & 15) * 4;
            #pragma unroll
            for (int it = 0; it < 4; ++it, kk += 16) {
                float4 v = *(const float4*)(kp + (size_t)(b * 512 + k0 + kk) * 128 + h * 64 + e0);
                *(float4*)&kv[kk][e0] = v;
            }
        }
        __syncthreads();
        float a[4] = {0.f, 0.f, 0.f, 0.f};
        #pragma unroll 4
        for (int e4 = 0; e4 < 64; e4 += 4) {
            float4 q4 = *(const float4*)&qs[r][e4];
            #pragma unroll
            for (int j = 0; j < 4; ++j) {
                float4 k4 = *(const float4*)&kv[kg + 16 * j][e4];
                a[j] = fmaf(q4.x, k4.x, a[j]);
                a[j] = fmaf(q4.y, k4.y, a[j]);
                a[j] = fmaf(q4.z, k4.z, a[j]);
                a[j] = fmaf(q4.w, k4.w, a[j]);
            }
        }
        #pragma unroll
        for (int j = 0; j < 4; ++j) sp[r][k0 + kg + 16 * j] = f2u(a[j]);
        __syncthreads();
    }

    int wv = tid >> 6, lane = tid & 63;
    for (int rr = wv; rr < 16; rr += 4) {
        float m = -1e30f;
        for (int k = lane; k < 512; k += 64) m = fmaxf(m, u2f(sp[rr][k]));
        m = wave_reduce_max(m);
        for (int k = lane; k < 512; k += 64) sp[rr][k] = f2u(expf(u2f(sp[rr][k]) - m));
    }

    int d = lane >> 3, sub = lane & 7;
    int qb = wv * 4;
    float num[4] = {0.f, 0.f, 0.f, 0.f}, den[4] = {0.f, 0.f, 0.f, 0.f};
    for (int kt = 0; kt < 8; ++kt) {
        int k0 = kt * 64;
        __syncthreads();
        {
            int kk = tid >> 2, c0 = (tid & 3) * 4;
            float4 v = *(const float4*)(x + (size_t)(b * 512 + k0 + kk) * 16 + c0);
            xv[kk * 17 + c0] = v.x; xv[kk * 17 + c0 + 1] = v.y;
            xv[kk * 17 + c0 + 2] = v.z; xv[kk * 17 + c0 + 3] = v.w;
        }
        __syncthreads();
        #pragma unroll
        for (int i = 0; i < 8; ++i) {
            int kk = sub + 8 * i;
            float mk = xv[kk * 17 + 8 + d];
            float vv = xv[kk * 17 + d];
            #pragma unroll
            for (int q = 0; q < 4; ++q) {
                float em = u2f(sp[qb + q][k0 + kk]) * mk;
                den[q] += em;
                num[q] = fmaf(em, vv, num[q]);
            }
        }
    }
    #pragma unroll
    for (int q = 0; q < 4; ++q) {
        #pragma unroll
        for (int off2 = 4; off2 >= 1; off2 >>= 1) {
            num[q] += __shfl_xor(num[q], off2);
            den[q] += __shfl_xor(den[q], off2);
        }
        if (sub == 0) {
            int row = q0 + qb + q;
            float* dst = is_cls ? (att_cls + (size_t)(b * 128 + row) * 32)
                                : (att_mn + (size_t)(b * 512 + row) * 32);
            dst[h * 16 + d] = num[q] / den[q];
            dst[h * 16 + 8 + d] = 1.0f;
        }
    }
}

// ---------------------------------------------------------------------------
// tblock attention (unchanged from R8): merged main+cls, bf16 p in LDS.
__global__ void __launch_bounds__(256, 3)
tb_att_kernel(const float* qp, const float* kp, const float* vp, float* outp) {
    int is_cls = (blockIdx.x >= 33);
    int qt = is_cls ? blockIdx.x - 33 : blockIdx.x;
    int h = blockIdx.y, b = blockIdx.z;
    int Lq = is_cls ? 129 : 513;
    int base = is_cls ? (4104 + b * 129) : (b * 513);
    int nkt = is_cls ? 3 : 9;
    int tid = threadIdx.x;  // 256
    __shared__ float qs[16][68];
    __shared__ float kv[64][68];
    __shared__ unsigned short sp[16][584];
    __shared__ float rinv[16];
    int q0 = qt * 16;

    {
        int r = tid >> 4, c0 = (tid & 15) * 4;
        int qr = q0 + r;
        float4 v = make_float4(0.f, 0.f, 0.f, 0.f);
        if (qr < Lq) v = *(const float4*)(qp + (size_t)(base + qr) * 128 + h * 64 + c0);
        qs[r][c0] = v.x * 0.125f; qs[r][c0 + 1] = v.y * 0.125f;
        qs[r][c0 + 2] = v.z * 0.125f; qs[r][c0 + 3] = v.w * 0.125f;
    }
    __syncthreads();

    int r = tid >> 4, kg = tid & 15;
    for (int kt = 0; kt < nkt; ++kt) {
        int k0 = kt * 64;
        {
            int kk = tid >> 4, e0 = (tid & 15) * 4;
            #pragma unroll
            for (int it = 0; it < 4; ++it, kk += 16) {
                int krow = k0 + kk;
                float4 v = make_float4(0.f, 0.f, 0.f, 0.f);
                if (krow < Lq) v = *(const float4*)(kp + (size_t)(base + krow) * 128 + h * 64 + e0);
                *(float4*)&kv[kk][e0] = v;
            }
        }
        __syncthreads();
        float a[4] = {0.f, 0.f, 0.f, 0.f};
        #pragma unroll 4
        for (int e4 = 0; e4 < 64; e4 += 4) {
            float4 q4 = *(const float4*)&qs[r][e4];
            #pragma unroll
            for (int j = 0; j < 4; ++j) {
                float4 k4 = *(const float4*)&kv[kg + 16 * j][e4];
                a[j] = fmaf(q4.x, k4.x, a[j]);
                a[j] = fmaf(q4.y, k4.y, a[j]);
                a[j] = fmaf(q4.z, k4.z, a[j]);
                a[j] = fmaf(q4.w, k4.w, a[j]);
            }
        }
        #pragma unroll
        for (int j = 0; j < 4; ++j) {
            int kb = k0 + kg + 16 * j;
            sp[r][kb] = f2u((kb < Lq) ? a[j] : -1e30f);
        }
        __syncthreads();
    }

    int wv = tid >> 6, lane = tid & 63;
    int kend = nkt * 64;
    for (int rr = wv; rr < 16; rr += 4) {
        float m = -1e30f;
        for (int k = lane; k < kend; k += 64) m = fmaxf(m, u2f(sp[rr][k]));
        m = wave_reduce_max(m);
        float sum = 0.f;
        for (int k = lane; k < kend; k += 64) {
            float e = expf(u2f(sp[rr][k]) - m);
            sp[rr][k] = f2u(e);
            sum += e;
        }
        sum = wave_reduce_sum(sum);
        if (lane == 0) rinv[rr] = 1.f / sum;
    }
    __syncthreads();

    int dg = tid & 15, d0 = dg * 4;
    float o0 = 0.f, o1 = 0.f, o2 = 0.f, o3 = 0.f;
    for (int kt = 0; kt < nkt; ++kt) {
        int k0 = kt * 64;
        __syncthreads();
        {
            int kk = tid >> 4, e0 = (tid & 15) * 4;
            #pragma unroll
            for (int it = 0; it < 4; ++it, kk += 16) {
                int krow = k0 + kk;
                float4 v = make_float4(0.f, 0.f, 0.f, 0.f);
                if (krow < Lq) v = *(const float4*)(vp + (size_t)(base + krow) * 128 + h * 64 + e0);
                *(float4*)&kv[kk][e0] = v;
            }
        }
        __syncthreads();
        #pragma unroll 4
        for (int kk = 0; kk < 64; kk += 4) {
            ushort4 pu = *(const ushort4*)&sp[r][k0 + kk];
            float p0 = u2f(pu.x), p1 = u2f(pu.y), p2 = u2f(pu.z), p3 = u2f(pu.w);
            float4 v0 = *(const float4*)&kv[kk][d0];
            float4 v1 = *(const float4*)&kv[kk + 1][d0];
            float4 v2 = *(const float4*)&kv[kk + 2][d0];
            float4 v3 = *(const float4*)&kv[kk + 3][d0];
            o0 = fmaf(p0, v0.x, fmaf(p1, v1.x, fmaf(p2, v2.x, fmaf(p3, v3.x, o0))));
            o1 = fmaf(p0, v0.y, fmaf(p1, v1.y, fmaf(p2, v2.y, fmaf(p3, v3.y, o1))));
            o2 = fmaf(p0, v0.z, fmaf(p1, v1.z, fmaf(p2, v2.z, fmaf(p3, v3.z, o2))));
            o3 = fmaf(p0, v0.w, fmaf(p1, v1.w, fmaf(p2, v2.w, fmaf(p3, v3.w, o3))));
        }
    }
    float inv = rinv[r];
    int qr = q0 + r;
    if (qr < Lq)
        *(float4*)(outp + (size_t)(base + qr) * 128 + h * 64 + d0) =
            make_float4(o0 * inv, o1 * inv, o2 * inv, o3 * inv);
}

// ---------------------------------------------------------------------------
__global__ void add_ln_kernel(const float* xin, const float* resid,
                              const float* g, const float* bt, float* out) {
    int row = blockIdx.x, j = threadIdx.x;
    size_t off = (size_t)row * 128 + j;
    float v = xin[off] + resid[off];
    __shared__ float red[2];
    int wave = j >> 6, lane = j & 63;
    float s = wave_reduce_sum(v);
    if (lane == 0) red[wave] = s;
    __syncthreads();
    float mean = (red[0] + red[1]) * 0.0078125f;
    float d = v - mean;
    __syncthreads();
    float s2 = wave_reduce_sum(d * d);
    if (lane == 0) red[wave] = s2;
    __syncthreads();
    float var = (red[0] + red[1]) * 0.0078125f;
    out[off] = d * rsqrtf(var + 1e-5f) * g[j] + bt[j];
}

// ---------------------------------------------------------------------------
__global__ void assemble_kernel(float* xin, const float* cls_emb, const float* mta_cls,
                                const float* mta_out, const float* pos) {
    int xr = blockIdx.x;  // 0..641
    int b = blockIdx.y;
    int j = threadIdx.x;  // 128
    if (xr < 513) {
        int r = xr;
        float v = (r == 0) ? cls_emb[j] : mta_out[(size_t)(b * 512 + r - 1) * 128 + j];
        v += pos[r * 128 + j];
        xin[(size_t)(b * 513 + r) * 128 + j] = v;
    } else {
        int r = xr - 513;
        float v = (r == 0) ? cls_emb[j] : mta_cls[(size_t)(b * 128 + r - 1) * 128 + j];
        xin[(size_t)(4104 + b * 129 + r) * 128 + j] = v;
    }
}

// ---------------------------------------------------------------------------
__global__ void finalize_kernel(const float* clsraw, const float* h2, float* out, int total) {
    int idx = blockIdx.x * 256 + threadIdx.x;
    if (idx >= total) return;
    float v;
    if (idx < 1024) {
        v = tanhf(clsraw[idx]);
    } else {
        int t = idx - 1024;
        int b = t >> 16;
        int rem = t & 65535;
        int i = rem >> 7, j = rem & 127;
        v = h2[((size_t)(b * 513 + 1 + i)) * 128 + j];
    }
    out[idx] = v;
}

// ---------------------------------------------------------------------------
extern "C" void kernel_launch(void* const* d_in, const int* in_sizes, int n_in,
                              void* d_out, int out_size, void* d_ws, size_t ws_size,
                              hipStream_t stream) {
    float* w = (float*)d_ws;
    size_t off = 0;
    auto alloc = [&](size_t n) {
        float* p = w + off;
        off += (n + 3) & ~(size_t)3;
        return p;
    };

    int* flag = (int*)alloc(4);

    ConvArgs ca;
    int nn = n_in < 32 ? n_in : 32;
    int max_n = 0;
    float* fin[32];
    for (int i = 0; i < nn; ++i) {
        ca.src[i] = d_in[i];
        ca.n[i] = in_sizes[i];
        fin[i] = alloc(in_sizes[i]);
        ca.dstoff[i] = (int)(fin[i] - w);
        if (in_sizes[i] > max_n) max_n = in_sizes[i];
    }
    for (int i = nn; i < 32; ++i) { ca.src[i] = nullptr; ca.n[i] = 0; ca.dstoff[i] = 0; }

    const float* x     = fin[0];
    const float* ts    = fin[1];
    const float* w_per = fin[2];  const float* b_per = fin[3];
    const float* w_lin = fin[4];  const float* b_lin = fin[5];
    const float* Wq_t  = fin[6];  const float* bq_t  = fin[7];
    const float* Wk_t  = fin[8];  const float* bk_t  = fin[9];
    const float* Wo_t  = fin[10]; const float* bo_t  = fin[11];
    const float* pos_emb = fin[12]; const float* cls_emb = fin[13];
    const float* tWq = fin[14]; const float* tbq = fin[15];
    const float* tWk = fin[16]; const float* tbk = fin[17];
    const float* tWv = fin[18]; const float* tbv = fin[19];
    const float* tWo = fin[20]; const float* tbo = fin[21];
    const float* ln1_g = fin[22]; const float* ln1_b = fin[23];
    const float* fW1 = fin[24]; const float* fb1 = fin[25];
    const float* fW2 = fin[26]; const float* fb2 = fin[27];
    const float* ln2_g = fin[28]; const float* ln2_b = fin[29];
    const float* pW = fin[30]; const float* pb = fin[31];

    // bf16 swizzled weights: 8 matrices x 16384 ushorts (8192 floats each)
    unsigned short* wsw[8];
    const float* wsrc[8] = {Wk_t, Wq_t, tWq, tWk, tWv, tWo, fW1, fW2};
    for (int i = 0; i < 8; ++i) wsw[i] = (unsigned short*)alloc(8192);

    float* key_e   = alloc(4096 * 128);
    float* cls_e   = alloc(128 * 128);
    float* qp_main = alloc(4096 * 128);
    float* kp_main = alloc(4096 * 128);   // adjacent to qp_main (mta_all overlay)
    float* qp_cls  = alloc(128 * 128);
    float* att_all = alloc(5120 * 32);
    float* att_cls = att_all;
    float* att_mn  = att_all + 1024 * 32;
    float* mta_all = qp_main;             // overlay: qp/kp dead after mta_att
    float* mta_cls = mta_all;
    float* mta_out = mta_all + 1024 * 128;
    float* xin     = alloc((size_t)NT_ * 128);
    float* tb_q    = alloc((size_t)NT_ * 128);
    float* tb_k    = alloc((size_t)NT_ * 128);
    float* tb_v    = alloc((size_t)NT_ * 128);
    float* tb_a    = alloc((size_t)NT_ * 128);
    float* tb_o    = tb_q;     // alias
    float* tb_x1   = alloc((size_t)NT_ * 128);
    float* tb_f1   = tb_k;     // alias
    float* tb_f2   = tb_v;     // alias
    float* x2      = alloc((size_t)NT_ * 128);
    float* clsraw  = alloc(8 * 128);
    (void)ws_size;

    detect_kernel<<<1, 1, 0, stream>>>((const unsigned short*)d_in[22], flag);
    convert_inputs_kernel<<<dim3((max_n + 255) / 256, 32), 256, 0, stream>>>(ca, w, flag);

    {   // weight swizzle
        PrepArgs pa;
        for (int i = 0; i < 8; ++i) { pa.src[i] = wsrc[i]; pa.dst[i] = wsw[i]; }
        prep_weights_kernel<<<dim3(64, 8), 256, 0, stream>>>(pa);
    }

    time_emb_kernel<<<4224, 128, 0, stream>>>(ts, w_per, b_per, w_lin, b_lin, key_e, cls_e);

    {   // mta projections (MFMA): k(4096), q(4096), q_cls(128)
        GemmM p{};
        p.A[0] = key_e; p.W[0] = wsw[0]; p.bias[0] = bk_t; p.C[0] = kp_main; p.M[0] = 4096; p.act[0] = 0;
        p.A[1] = key_e; p.W[1] = wsw[1]; p.bias[1] = bq_t; p.C[1] = qp_main; p.M[1] = 4096; p.act[1] = 0;
        p.A[2] = cls_e; p.W[2] = wsw[1]; p.bias[2] = bq_t; p.C[2] = qp_cls;  p.M[2] = 128;  p.act[2] = 0;
        gemm_mfma_kernel<<<dim3(256, 3), 256, 0, stream>>>(p);
    }

    mta_att_kernel<<<dim3(40, 2, 8), 256, 0, stream>>>(qp_cls, qp_main, kp_main, x, att_cls, att_mn);

    {   // mta out-projection (K=32, legacy path)
        GemmBatch p{};
        p.A[0] = att_all; p.W[0] = Wo_t; p.bias[0] = bo_t; p.C[0] = mta_all;
        p.lda[0] = 32; p.ldc[0] = 128; p.M[0] = 5120; p.K[0] = 32; p.act[0] = 0;
        gemm16b_kernel<<<dim3(320, 1), 256, 0, stream>>>(p);
    }

    assemble_kernel<<<dim3(642, 8), 128, 0, stream>>>(xin, cls_emb, mta_cls, mta_out, pos_emb);

    auto mfma_gemm1 = [&](const float* A, const unsigned short* W, const float* bias,
                          float* C, int M, int act) {
        GemmM p{};
        p.A[0] = A; p.W[0] = W; p.bias[0] = bias; p.C[0] = C; p.M[0] = M; p.act[0] = act;
        gemm_mfma_kernel<<<dim3((M + 15) / 16, 1), 256, 0, stream>>>(p);
    };

    // --- merged tblock over 5136 rows ---
    {   // QKV (MFMA, batched)
        GemmM p{};
        const unsigned short* Ws[3] = {wsw[2], wsw[3], wsw[4]};
        const float* bs[3] = {tbq, tbk, tbv};
        float* Cs[3] = {tb_q, tb_k, tb_v};
        for (int y = 0; y < 3; ++y) {
            p.A[y] = xin; p.W[y] = Ws[y]; p.bias[y] = bs[y]; p.C[y] = Cs[y];
            p.M[y] = NT_; p.act[y] = 0;
        }
        gemm_mfma_kernel<<<dim3((NT_ + 15) / 16, 3), 256, 0, stream>>>(p);
    }
    tb_att_kernel<<<dim3(42, 2, 8), 256, 0, stream>>>(tb_q, tb_k, tb_v, tb_a);
    mfma_gemm1(tb_a, wsw[5], tbo, tb_o, NT_, 0);
    add_ln_kernel<<<NT_, 128, 0, stream>>>(xin, tb_o, ln1_g, ln1_b, tb_x1);
    mfma_gemm1(tb_x1, wsw[6], fb1, tb_f1, NT_, 1);
    mfma_gemm1(tb_f1, wsw[7], fb2, tb_f2, NT_, 0);
    add_ln_kernel<<<NT_, 128, 0, stream>>>(tb_x1, tb_f2, ln2_g, ln2_b, x2);

    // cls pooling (legacy path, M=8)
    {
        GemmBatch p{};
        p.A[0] = x2 + (size_t)4104 * 128; p.W[0] = pW; p.bias[0] = pb; p.C[0] = clsraw;
        p.lda[0] = 129 * 128; p.ldc[0] = 128; p.M[0] = 8; p.K[0] = 128; p.act[0] = 0;
        gemm16b_kernel<<<dim3(1, 1), 256, 0, stream>>>(p);
    }

    finalize_kernel<<<(out_size + 255) / 256, 256, 0, stream>>>(clsraw, x2, (float*)d_out, out_size);
}

// Round 10
// 246.235 us; speedup vs baseline: 3.5995x; 1.1723x over previous
//
#include <hip/hip_runtime.h>
#include <hip/hip_bf16.h>
#include <math.h>

// TimeBERT forward on MI355X. Inputs fp32 (runtime bf16 detector kept).
// OUTPUT FP32: [cls_pooling (8,128) | last_hidden (8,512,128)].
//
// R10: attention matmuls -> MFMA 16x16x32_bf16.
//  tb_att: QK^T (K row-major B-frags) + PV (V transposed bf16 in LDS,
//  stride 76, b64-pair frag reads). sp stride 588 (b64-aligned, 2-way-free).
//  mta_att: MFMA pass A only; masked-sum pass unchanged (xv overlays K buf).

static constexpr int B_ = 8, L_ = 512, DIM_ = 8, ET_ = 128, HID_ = 128, H_ = 2;
static constexpr int NM_ = 8 * 513;           // 4104 main rows
static constexpr int NC_ = 8 * 129;           // 1032 cls rows
static constexpr int NT_ = NM_ + NC_;         // 5136 total

using bf = __hip_bfloat16;
typedef __attribute__((ext_vector_type(8))) short bf16x8;
typedef __attribute__((ext_vector_type(4))) short bf16x4;
typedef __attribute__((ext_vector_type(4))) float floatx4;

__device__ __forceinline__ float wave_reduce_sum(float v) {
    #pragma unroll
    for (int off = 32; off >= 1; off >>= 1) v += __shfl_xor(v, off);
    return v;
}
__device__ __forceinline__ float wave_reduce_max(float v) {
    #pragma unroll
    for (int off = 32; off >= 1; off >>= 1) v = fmaxf(v, __shfl_xor(v, off));
    return v;
}
__device__ __forceinline__ float u2f(unsigned short u) {
    return __uint_as_float(((unsigned)u) << 16);
}
// RNE float->bf16 (finite values)
__device__ __forceinline__ unsigned short f2u(float f) {
    unsigned u = __float_as_uint(f);
    return (unsigned short)((u + 0x7FFF + ((u >> 16) & 1)) >> 16);
}
__device__ __forceinline__ bf16x8 join8(bf16x4 lo, bf16x4 hi) {
    return __builtin_shufflevector(lo, hi, 0, 1, 2, 3, 4, 5, 6, 7);
}

// ---------------------------------------------------------------------------
__global__ void detect_kernel(const unsigned short* ln1_g_raw, int* flag) {
    if (threadIdx.x == 0 && blockIdx.x == 0)
        *flag = (ln1_g_raw[0] == 0x3F80u) ? 1 : 0;
}

struct ConvArgs {
    const void* src[32];
    int n[32];
    int dstoff[32];
};
__global__ void convert_inputs_kernel(ConvArgs a, float* dst, const int* flag) {
    int which = blockIdx.y;
    int n = a.n[which];
    int i = blockIdx.x * 256 + threadIdx.x;
    if (i >= n) return;
    float v;
    if (*flag) v = __bfloat162float(((const bf*)a.src[which])[i]);
    else       v = ((const float*)a.src[which])[i];
    dst[a.dstoff[which] + i] = v;
}

// ---------------------------------------------------------------------------
__global__ void time_emb_kernel(const float* ts, const float* w_per, const float* b_per,
                                const float* w_lin, const float* b_lin,
                                float* key_e, float* cls_e) {
    int row = blockIdx.x, j = threadIdx.x;  // 128 threads
    float t;
    float* out;
    if (row < 4096) { t = ts[row]; out = key_e + (size_t)row * 128; }
    else { t = (float)(row - 4096) * (1.0f / 127.0f); out = cls_e + (size_t)(row - 4096) * 128; }
    float v;
    if (j == 0) v = t * w_lin[0] + b_lin[0];
    else        v = sinf(t * w_per[j - 1] + b_per[j - 1]);
    out[j] = v;
}

// ---------------------------------------------------------------------------
// Pre-swizzle 128x128 fp32 weights into MFMA B-frag order, bf16.
struct PrepArgs { const float* src[8]; unsigned short* dst[8]; };
__global__ void prep_weights_kernel(PrepArgs p) {
    int m = blockIdx.y;
    const float* W = p.src[m];
    unsigned short* D = p.dst[m];
    int idx = blockIdx.x * 256 + threadIdx.x;   // 0..16383
    int c = idx >> 9;
    int l = (idx >> 3) & 63;
    int j = idx & 7;
    int k = (c >> 3) * 32 + (l >> 4) * 8 + j;
    int n = (c & 7) * 16 + (l & 15);
    D[idx] = f2u(W[k * 128 + n]);
}

// ---------------------------------------------------------------------------
// MFMA GEMM (unchanged from R9).
struct GemmM {
    const float* A[3]; const unsigned short* W[3]; const float* bias[3]; float* C[3];
    int M[3]; int act[3];
};
__global__ void __launch_bounds__(256)
gemm_mfma_kernel(GemmM p) {
    int y = blockIdx.y;
    const float* A = p.A[y]; const unsigned short* Wsw = p.W[y];
    const float* bias = p.bias[y]; float* C = p.C[y];
    int M = p.M[y], act = p.act[y];
    int m0 = blockIdx.x * 16;
    if (m0 >= M) return;
    __shared__ unsigned short As[16][136];
    int tid = threadIdx.x;
    {
        int r = tid >> 4, c0 = (tid & 15) * 8;
        float4 v0 = make_float4(0.f, 0.f, 0.f, 0.f), v1 = v0;
        if (m0 + r < M) {
            v0 = *(const float4*)(A + (size_t)(m0 + r) * 128 + c0);
            v1 = *(const float4*)(A + (size_t)(m0 + r) * 128 + c0 + 4);
        }
        *(ushort4*)&As[r][c0] = make_ushort4(f2u(v0.x), f2u(v0.y), f2u(v0.z), f2u(v0.w));
        *(ushort4*)&As[r][c0 + 4] = make_ushort4(f2u(v1.x), f2u(v1.y), f2u(v1.z), f2u(v1.w));
    }
    __syncthreads();

    int wv = tid >> 6, lane = tid & 63;
    floatx4 acc0 = {0.f, 0.f, 0.f, 0.f}, acc1 = acc0;
    int am = lane & 15, aq = lane >> 4;
    #pragma unroll
    for (int ks = 0; ks < 4; ++ks) {
        bf16x8 af = *(bf16x8*)&As[am][ks * 32 + aq * 8];
        const unsigned short* base = Wsw + ((size_t)ks * 8 + 2 * wv) * 512 + lane * 8;
        bf16x8 b0 = *(const bf16x8*)(base);
        bf16x8 b1 = *(const bf16x8*)(base + 512);
        acc0 = __builtin_amdgcn_mfma_f32_16x16x32_bf16(af, b0, acc0, 0, 0, 0);
        acc1 = __builtin_amdgcn_mfma_f32_16x16x32_bf16(af, b1, acc1, 0, 0, 0);
    }
    int col = lane & 15, rowb = (lane >> 4) * 4;
    #pragma unroll
    for (int t = 0; t < 2; ++t) {
        floatx4 acc = t ? acc1 : acc0;
        int n = wv * 32 + t * 16 + col;
        float bv = bias[n];
        #pragma unroll
        for (int rg = 0; rg < 4; ++rg) {
            int m = m0 + rowb + rg;
            if (m < M) {
                float o = acc[rg] + bv;
                if (act) o = fmaxf(o, 0.f);
                C[(size_t)m * 128 + n] = o;
            }
        }
    }
}

// ---------------------------------------------------------------------------
// Legacy VALU GEMM (K=32 mta-out, pooling).
struct GemmBatch {
    const float* A[3]; const float* W[3]; const float* bias[3]; float* C[3];
    int lda[3], ldc[3], M[3], K[3], act[3];
};
__global__ void gemm16b_kernel(GemmBatch p) {
    int y = blockIdx.y;
    const float* A = p.A[y]; const float* W = p.W[y]; const float* bias = p.bias[y];
    float* C = p.C[y];
    int lda = p.lda[y], ldc = p.ldc[y], M = p.M[y], K = p.K[y], act = p.act[y];
    int m0 = blockIdx.x * 16;
    if (m0 >= M) return;
    __shared__ float As[16][132];
    int tid = threadIdx.x;
    int r = tid >> 4, g = tid & 15, c0 = g * 8;
    for (int c = g; c < K; c += 16) {
        float v = 0.f;
        if (m0 + r < M) v = A[(size_t)(m0 + r) * lda + c];
        As[r][c] = v;
    }
    __syncthreads();
    float acc[8];
    #pragma unroll
    for (int j = 0; j < 8; ++j) acc[j] = bias[c0 + j];
    for (int k = 0; k < K; ++k) {
        float a = As[r][k];
        const float4 w0 = *(const float4*)(W + (size_t)k * 128 + c0);
        const float4 w1 = *(const float4*)(W + (size_t)k * 128 + c0 + 4);
        acc[0] = fmaf(a, w0.x, acc[0]); acc[1] = fmaf(a, w0.y, acc[1]);
        acc[2] = fmaf(a, w0.z, acc[2]); acc[3] = fmaf(a, w0.w, acc[3]);
        acc[4] = fmaf(a, w1.x, acc[4]); acc[5] = fmaf(a, w1.y, acc[5]);
        acc[6] = fmaf(a, w1.z, acc[6]); acc[7] = fmaf(a, w1.w, acc[7]);
    }
    if (act == 1) {
        #pragma unroll
        for (int j = 0; j < 8; ++j) acc[j] = fmaxf(acc[j], 0.f);
    }
    if (m0 + r < M) {
        *(float4*)(C + (size_t)(m0 + r) * ldc + c0) = make_float4(acc[0], acc[1], acc[2], acc[3]);
        *(float4*)(C + (size_t)(m0 + r) * ldc + c0 + 4) = make_float4(acc[4], acc[5], acc[6], acc[7]);
    }
}

// ---------------------------------------------------------------------------
// mta attention: MFMA QK^T pass + scalar masked-sum pass.
__global__ void __launch_bounds__(256)
mta_att_kernel(const float* qp_cls, const float* qp_main, const float* kp,
               const float* x, float* att_cls, float* att_mn) {
    int is_cls = (blockIdx.x >= 32);
    int qt = is_cls ? (blockIdx.x - 32) : blockIdx.x;
    int h = blockIdx.y, b = blockIdx.z;
    int tid = threadIdx.x, lane = tid & 63, wv = tid >> 6;
    __shared__ unsigned short Qs[16][72];
    __shared__ unsigned short KV[64][76];    // K tiles; reused as xv fp32[64][17]
    __shared__ unsigned short sp[16][520];
    float* xv = (float*)&KV[0][0];
    int q0 = qt * 16;

    {   // stage Q bf16 (*0.125)
        int r = tid >> 4, c0 = (tid & 15) * 4;
        const float* qrow = is_cls ? (qp_cls + (size_t)(q0 + r) * 128 + h * 64)
                                   : (qp_main + (size_t)(b * 512 + q0 + r) * 128 + h * 64);
        float4 v = *(const float4*)(qrow + c0);
        *(ushort4*)&Qs[r][c0] = make_ushort4(f2u(v.x * 0.125f), f2u(v.y * 0.125f),
                                             f2u(v.z * 0.125f), f2u(v.w * 0.125f));
    }
    __syncthreads();

    // preload Q A-frags (invariant over tiles)
    bf16x8 qf0, qf1;
    {
        int m = lane & 15, g = lane >> 4;
        qf0 = *(const bf16x8*)&Qs[m][g * 8];
        qf1 = *(const bf16x8*)&Qs[m][32 + g * 8];
    }

    // pass A: MFMA scores, 8 K-tiles of 64
    for (int kt = 0; kt < 8; ++kt) {
        int k0 = kt * 64;
        {   // stage K tile bf16
            int kk = tid >> 4, e0 = (tid & 15) * 4;
            #pragma unroll
            for (int it = 0; it < 4; ++it, kk += 16) {
                float4 v = *(const float4*)(kp + (size_t)(b * 512 + k0 + kk) * 128 + h * 64 + e0);
                *(ushort4*)&KV[kk][e0] = make_ushort4(f2u(v.x), f2u(v.y), f2u(v.z), f2u(v.w));
            }
        }
        __syncthreads();
        int kn = lane & 15, g = lane >> 4;
        floatx4 acc = {0.f, 0.f, 0.f, 0.f};
        {
            bf16x4 lo0 = *(const bf16x4*)&KV[wv * 16 + kn][g * 8];
            bf16x4 hi0 = *(const bf16x4*)&KV[wv * 16 + kn][g * 8 + 4];
            acc = __builtin_amdgcn_mfma_f32_16x16x32_bf16(qf0, join8(lo0, hi0), acc, 0, 0, 0);
            bf16x4 lo1 = *(const bf16x4*)&KV[wv * 16 + kn][32 + g * 8];
            bf16x4 hi1 = *(const bf16x4*)&KV[wv * 16 + kn][32 + g * 8 + 4];
            acc = __builtin_amdgcn_mfma_f32_16x16x32_bf16(qf1, join8(lo1, hi1), acc, 0, 0, 0);
        }
        int colk = k0 + wv * 16 + kn;
        #pragma unroll
        for (int rg = 0; rg < 4; ++rg) sp[g * 4 + rg][colk] = f2u(acc[rg]);
        __syncthreads();
    }

    // pass B: global-max + exp in place (ratio-identical to ref)
    for (int rr = wv; rr < 16; rr += 4) {
        float m = -1e30f;
        for (int k = lane; k < 512; k += 64) m = fmaxf(m, u2f(sp[rr][k]));
        m = wave_reduce_max(m);
        for (int k = lane; k < 512; k += 64) sp[rr][k] = f2u(expf(u2f(sp[rr][k]) - m));
    }

    // masked sums: wave -> 4 q-rows; lane = (d = lane>>3, sub = lane&7)
    int d = lane >> 3, sub = lane & 7;
    int qb = wv * 4;
    float num[4] = {0.f, 0.f, 0.f, 0.f}, den[4] = {0.f, 0.f, 0.f, 0.f};
    for (int kt = 0; kt < 8; ++kt) {
        int k0 = kt * 64;
        __syncthreads();
        {   // stage x tile 64x16 into xv (overlays KV)
            int kk = tid >> 2, c0 = (tid & 3) * 4;
            float4 v = *(const float4*)(x + (size_t)(b * 512 + k0 + kk) * 16 + c0);
            xv[kk * 17 + c0] = v.x; xv[kk * 17 + c0 + 1] = v.y;
            xv[kk * 17 + c0 + 2] = v.z; xv[kk * 17 + c0 + 3] = v.w;
        }
        __syncthreads();
        #pragma unroll
        for (int i = 0; i < 8; ++i) {
            int kk = sub + 8 * i;
            float mk = xv[kk * 17 + 8 + d];
            float vv = xv[kk * 17 + d];
            #pragma unroll
            for (int q = 0; q < 4; ++q) {
                float em = u2f(sp[qb + q][k0 + kk]) * mk;
                den[q] += em;
                num[q] = fmaf(em, vv, num[q]);
            }
        }
    }
    #pragma unroll
    for (int q = 0; q < 4; ++q) {
        #pragma unroll
        for (int off2 = 4; off2 >= 1; off2 >>= 1) {
            num[q] += __shfl_xor(num[q], off2);
            den[q] += __shfl_xor(den[q], off2);
        }
        if (sub == 0) {
            int row = q0 + qb + q;
            float* dst = is_cls ? (att_cls + (size_t)(b * 128 + row) * 32)
                                : (att_mn + (size_t)(b * 512 + row) * 32);
            dst[h * 16 + d] = num[q] / den[q];
            dst[h * 16 + 8 + d] = 1.0f;
        }
    }
}

// ---------------------------------------------------------------------------
// tblock attention: full MFMA (QK^T + PV). merged main(x<33)+cls(x>=33).
__global__ void __launch_bounds__(256)
tb_att_kernel(const float* qp, const float* kp, const float* vp, float* outp) {
    int is_cls = (blockIdx.x >= 33);
    int qt = is_cls ? blockIdx.x - 33 : blockIdx.x;
    int h = blockIdx.y, b = blockIdx.z;
    int Lq = is_cls ? 129 : 513;
    int base = is_cls ? (4104 + b * 129) : (b * 513);
    int nkt = is_cls ? 3 : 9;
    int tid = threadIdx.x, lane = tid & 63, wv = tid >> 6;
    __shared__ unsigned short Qs[16][72];
    __shared__ unsigned short KV[64][76];    // K tiles (pass A) / Vt tiles (pass C)
    __shared__ unsigned short sp[16][588];   // 588%4==0 (b64-aligned), 2-way-free
    __shared__ float rinv[16];
    int q0 = qt * 16;

    {   // stage Q bf16 (*0.125)
        int r = tid >> 4, c0 = (tid & 15) * 4;
        int qr = q0 + r;
        float4 v = make_float4(0.f, 0.f, 0.f, 0.f);
        if (qr < Lq) v = *(const float4*)(qp + (size_t)(base + qr) * 128 + h * 64 + c0);
        *(ushort4*)&Qs[r][c0] = make_ushort4(f2u(v.x * 0.125f), f2u(v.y * 0.125f),
                                             f2u(v.z * 0.125f), f2u(v.w * 0.125f));
    }
    __syncthreads();

    bf16x8 qf0, qf1;
    {
        int m = lane & 15, g = lane >> 4;
        qf0 = *(const bf16x8*)&Qs[m][g * 8];
        qf1 = *(const bf16x8*)&Qs[m][32 + g * 8];
    }

    // pass A: MFMA scores
    for (int kt = 0; kt < nkt; ++kt) {
        int k0 = kt * 64;
        {
            int kk = tid >> 4, e0 = (tid & 15) * 4;
            #pragma unroll
            for (int it = 0; it < 4; ++it, kk += 16) {
                int krow = k0 + kk;
                float4 v = make_float4(0.f, 0.f, 0.f, 0.f);
                if (krow < Lq) v = *(const float4*)(kp + (size_t)(base + krow) * 128 + h * 64 + e0);
                *(ushort4*)&KV[kk][e0] = make_ushort4(f2u(v.x), f2u(v.y), f2u(v.z), f2u(v.w));
            }
        }
        __syncthreads();
        int kn = lane & 15, g = lane >> 4;
        floatx4 acc = {0.f, 0.f, 0.f, 0.f};
        {
            bf16x4 lo0 = *(const bf16x4*)&KV[wv * 16 + kn][g * 8];
            bf16x4 hi0 = *(const bf16x4*)&KV[wv * 16 + kn][g * 8 + 4];
            acc = __builtin_amdgcn_mfma_f32_16x16x32_bf16(qf0, join8(lo0, hi0), acc, 0, 0, 0);
            bf16x4 lo1 = *(const bf16x4*)&KV[wv * 16 + kn][32 + g * 8];
            bf16x4 hi1 = *(const bf16x4*)&KV[wv * 16 + kn][32 + g * 8 + 4];
            acc = __builtin_amdgcn_mfma_f32_16x16x32_bf16(qf1, join8(lo1, hi1), acc, 0, 0, 0);
        }
        int colk = k0 + wv * 16 + kn;
        #pragma unroll
        for (int rg = 0; rg < 4; ++rg)
            sp[g * 4 + rg][colk] = f2u((colk < Lq) ? acc[rg] : -1e30f);
        __syncthreads();
    }

    // pass B: max + exp (unnormalized, bf16); rinv = 1/sum
    int kend = nkt * 64;
    for (int rr = wv; rr < 16; rr += 4) {
        float m = -1e30f;
        for (int k = lane; k < kend; k += 64) m = fmaxf(m, u2f(sp[rr][k]));
        m = wave_reduce_max(m);
        float sum = 0.f;
        for (int k = lane; k < kend; k += 64) {
            float e = expf(u2f(sp[rr][k]) - m);
            sp[rr][k] = f2u(e);
            sum += e;
        }
        sum = wave_reduce_sum(sum);
        if (lane == 0) rinv[rr] = 1.f / sum;
    }

    // pass C: PV via MFMA; V transposed bf16 into KV (Vt[d][k])
    floatx4 oacc = {0.f, 0.f, 0.f, 0.f};
    for (int kt = 0; kt < nkt; ++kt) {
        int k0 = kt * 64;
        __syncthreads();
        {   // stage Vt: read V rows coalesced, write transposed b16s
            int kk = tid >> 4, e0 = (tid & 15) * 4;
            #pragma unroll
            for (int it = 0; it < 4; ++it, kk += 16) {
                int krow = k0 + kk;
                float4 v = make_float4(0.f, 0.f, 0.f, 0.f);
                if (krow < Lq) v = *(const float4*)(vp + (size_t)(base + krow) * 128 + h * 64 + e0);
                KV[e0][kk] = f2u(v.x);
                KV[e0 + 1][kk] = f2u(v.y);
                KV[e0 + 2][kk] = f2u(v.z);
                KV[e0 + 3][kk] = f2u(v.w);
            }
        }
        __syncthreads();
        int dn = lane & 15, g = lane >> 4;
        #pragma unroll
        for (int c = 0; c < 2; ++c) {
            bf16x4 plo = *(const bf16x4*)&sp[lane & 15][k0 + c * 32 + g * 8];
            bf16x4 phi = *(const bf16x4*)&sp[lane & 15][k0 + c * 32 + g * 8 + 4];
            bf16x4 vlo = *(const bf16x4*)&KV[wv * 16 + dn][c * 32 + g * 8];
            bf16x4 vhi = *(const bf16x4*)&KV[wv * 16 + dn][c * 32 + g * 8 + 4];
            oacc = __builtin_amdgcn_mfma_f32_16x16x32_bf16(join8(plo, phi), join8(vlo, vhi), oacc, 0, 0, 0);
        }
    }
    // write out: col d = wv*16 + (lane&15); rows q = (lane>>4)*4 + rg
    int dcol = wv * 16 + (lane & 15), g = lane >> 4;
    #pragma unroll
    for (int rg = 0; rg < 4; ++rg) {
        int q = g * 4 + rg;
        int qr = q0 + q;
        if (qr < Lq)
            outp[(size_t)(base + qr) * 128 + h * 64 + dcol] = oacc[rg] * rinv[q];
    }
}

// ---------------------------------------------------------------------------
__global__ void add_ln_kernel(const float* xin, const float* resid,
                              const float* g, const float* bt, float* out) {
    int row = blockIdx.x, j = threadIdx.x;
    size_t off = (size_t)row * 128 + j;
    float v = xin[off] + resid[off];
    __shared__ float red[2];
    int wave = j >> 6, lane = j & 63;
    float s = wave_reduce_sum(v);
    if (lane == 0) red[wave] = s;
    __syncthreads();
    float mean = (red[0] + red[1]) * 0.0078125f;
    float d = v - mean;
    __syncthreads();
    float s2 = wave_reduce_sum(d * d);
    if (lane == 0) red[wave] = s2;
    __syncthreads();
    float var = (red[0] + red[1]) * 0.0078125f;
    out[off] = d * rsqrtf(var + 1e-5f) * g[j] + bt[j];
}

// ---------------------------------------------------------------------------
__global__ void assemble_kernel(float* xin, const float* cls_emb, const float* mta_cls,
                                const float* mta_out, const float* pos) {
    int xr = blockIdx.x;  // 0..641
    int b = blockIdx.y;
    int j = threadIdx.x;  // 128
    if (xr < 513) {
        int r = xr;
        float v = (r == 0) ? cls_emb[j] : mta_out[(size_t)(b * 512 + r - 1) * 128 + j];
        v += pos[r * 128 + j];
        xin[(size_t)(b * 513 + r) * 128 + j] = v;
    } else {
        int r = xr - 513;
        float v = (r == 0) ? cls_emb[j] : mta_cls[(size_t)(b * 128 + r - 1) * 128 + j];
        xin[(size_t)(4104 + b * 129 + r) * 128 + j] = v;
    }
}

// ---------------------------------------------------------------------------
__global__ void finalize_kernel(const float* clsraw, const float* h2, float* out, int total) {
    int idx = blockIdx.x * 256 + threadIdx.x;
    if (idx >= total) return;
    float v;
    if (idx < 1024) {
        v = tanhf(clsraw[idx]);
    } else {
        int t = idx - 1024;
        int b = t >> 16;
        int rem = t & 65535;
        int i = rem >> 7, j = rem & 127;
        v = h2[((size_t)(b * 513 + 1 + i)) * 128 + j];
    }
    out[idx] = v;
}

// ---------------------------------------------------------------------------
extern "C" void kernel_launch(void* const* d_in, const int* in_sizes, int n_in,
                              void* d_out, int out_size, void* d_ws, size_t ws_size,
                              hipStream_t stream) {
    float* w = (float*)d_ws;
    size_t off = 0;
    auto alloc = [&](size_t n) {
        float* p = w + off;
        off += (n + 3) & ~(size_t)3;
        return p;
    };

    int* flag = (int*)alloc(4);

    ConvArgs ca;
    int nn = n_in < 32 ? n_in : 32;
    int max_n = 0;
    float* fin[32];
    for (int i = 0; i < nn; ++i) {
        ca.src[i] = d_in[i];
        ca.n[i] = in_sizes[i];
        fin[i] = alloc(in_sizes[i]);
        ca.dstoff[i] = (int)(fin[i] - w);
        if (in_sizes[i] > max_n) max_n = in_sizes[i];
    }
    for (int i = nn; i < 32; ++i) { ca.src[i] = nullptr; ca.n[i] = 0; ca.dstoff[i] = 0; }

    const float* x     = fin[0];
    const float* ts    = fin[1];
    const float* w_per = fin[2];  const float* b_per = fin[3];
    const float* w_lin = fin[4];  const float* b_lin = fin[5];
    const float* Wq_t  = fin[6];  const float* bq_t  = fin[7];
    const float* Wk_t  = fin[8];  const float* bk_t  = fin[9];
    const float* Wo_t  = fin[10]; const float* bo_t  = fin[11];
    const float* pos_emb = fin[12]; const float* cls_emb = fin[13];
    const float* tWq = fin[14]; const float* tbq = fin[15];
    const float* tWk = fin[16]; const float* tbk = fin[17];
    const float* tWv = fin[18]; const float* tbv = fin[19];
    const float* tWo = fin[20]; const float* tbo = fin[21];
    const float* ln1_g = fin[22]; const float* ln1_b = fin[23];
    const float* fW1 = fin[24]; const float* fb1 = fin[25];
    const float* fW2 = fin[26]; const float* fb2 = fin[27];
    const float* ln2_g = fin[28]; const float* ln2_b = fin[29];
    const float* pW = fin[30]; const float* pb = fin[31];

    unsigned short* wsw[8];
    const float* wsrc[8] = {Wk_t, Wq_t, tWq, tWk, tWv, tWo, fW1, fW2};
    for (int i = 0; i < 8; ++i) wsw[i] = (unsigned short*)alloc(8192);

    float* key_e   = alloc(4096 * 128);
    float* cls_e   = alloc(128 * 128);
    float* qp_main = alloc(4096 * 128);
    float* kp_main = alloc(4096 * 128);   // adjacent to qp_main (mta_all overlay)
    float* qp_cls  = alloc(128 * 128);
    float* att_all = alloc(5120 * 32);
    float* att_cls = att_all;
    float* att_mn  = att_all + 1024 * 32;
    float* mta_all = qp_main;             // overlay: qp/kp dead after mta_att
    float* mta_cls = mta_all;
    float* mta_out = mta_all + 1024 * 128;
    float* xin     = alloc((size_t)NT_ * 128);
    float* tb_q    = alloc((size_t)NT_ * 128);
    float* tb_k    = alloc((size_t)NT_ * 128);
    float* tb_v    = alloc((size_t)NT_ * 128);
    float* tb_a    = alloc((size_t)NT_ * 128);
    float* tb_o    = tb_q;     // alias
    float* tb_x1   = alloc((size_t)NT_ * 128);
    float* tb_f1   = tb_k;     // alias
    float* tb_f2   = tb_v;     // alias
    float* x2      = alloc((size_t)NT_ * 128);
    float* clsraw  = alloc(8 * 128);
    (void)ws_size;

    detect_kernel<<<1, 1, 0, stream>>>((const unsigned short*)d_in[22], flag);
    convert_inputs_kernel<<<dim3((max_n + 255) / 256, 32), 256, 0, stream>>>(ca, w, flag);

    {
        PrepArgs pa;
        for (int i = 0; i < 8; ++i) { pa.src[i] = wsrc[i]; pa.dst[i] = wsw[i]; }
        prep_weights_kernel<<<dim3(64, 8), 256, 0, stream>>>(pa);
    }

    time_emb_kernel<<<4224, 128, 0, stream>>>(ts, w_per, b_per, w_lin, b_lin, key_e, cls_e);

    {   // mta projections (MFMA)
        GemmM p{};
        p.A[0] = key_e; p.W[0] = wsw[0]; p.bias[0] = bk_t; p.C[0] = kp_main; p.M[0] = 4096; p.act[0] = 0;
        p.A[1] = key_e; p.W[1] = wsw[1]; p.bias[1] = bq_t; p.C[1] = qp_main; p.M[1] = 4096; p.act[1] = 0;
        p.A[2] = cls_e; p.W[2] = wsw[1]; p.bias[2] = bq_t; p.C[2] = qp_cls;  p.M[2] = 128;  p.act[2] = 0;
        gemm_mfma_kernel<<<dim3(256, 3), 256, 0, stream>>>(p);
    }

    mta_att_kernel<<<dim3(40, 2, 8), 256, 0, stream>>>(qp_cls, qp_main, kp_main, x, att_cls, att_mn);

    {   // mta out-projection (K=32)
        GemmBatch p{};
        p.A[0] = att_all; p.W[0] = Wo_t; p.bias[0] = bo_t; p.C[0] = mta_all;
        p.lda[0] = 32; p.ldc[0] = 128; p.M[0] = 5120; p.K[0] = 32; p.act[0] = 0;
        gemm16b_kernel<<<dim3(320, 1), 256, 0, stream>>>(p);
    }

    assemble_kernel<<<dim3(642, 8), 128, 0, stream>>>(xin, cls_emb, mta_cls, mta_out, pos_emb);

    auto mfma_gemm1 = [&](const float* A, const unsigned short* W, const float* bias,
                          float* C, int M, int act) {
        GemmM p{};
        p.A[0] = A; p.W[0] = W; p.bias[0] = bias; p.C[0] = C; p.M[0] = M; p.act[0] = act;
        gemm_mfma_kernel<<<dim3((M + 15) / 16, 1), 256, 0, stream>>>(p);
    };

    {   // QKV (MFMA, batched)
        GemmM p{};
        const unsigned short* Ws[3] = {wsw[2], wsw[3], wsw[4]};
        const float* bs[3] = {tbq, tbk, tbv};
        float* Cs[3] = {tb_q, tb_k, tb_v};
        for (int y = 0; y < 3; ++y) {
            p.A[y] = xin; p.W[y] = Ws[y]; p.bias[y] = bs[y]; p.C[y] = Cs[y];
            p.M[y] = NT_; p.act[y] = 0;
        }
        gemm_mfma_kernel<<<dim3((NT_ + 15) / 16, 3), 256, 0, stream>>>(p);
    }
    tb_att_kernel<<<dim3(42, 2, 8), 256, 0, stream>>>(tb_q, tb_k, tb_v, tb_a);
    mfma_gemm1(tb_a, wsw[5], tbo, tb_o, NT_, 0);
    add_ln_kernel<<<NT_, 128, 0, stream>>>(xin, tb_o, ln1_g, ln1_b, tb_x1);
    mfma_gemm1(tb_x1, wsw[6], fb1, tb_f1, NT_, 1);
    mfma_gemm1(tb_f1, wsw[7], fb2, tb_f2, NT_, 0);
    add_ln_kernel<<<NT_, 128, 0, stream>>>(tb_x1, tb_f2, ln2_g, ln2_b, x2);

    {   // cls pooling
        GemmBatch p{};
        p.A[0] = x2 + (size_t)4104 * 128; p.W[0] = pW; p.bias[0] = pb; p.C[0] = clsraw;
        p.lda[0] = 129 * 128; p.ldc[0] = 128; p.M[0] = 8; p.K[0] = 128; p.act[0] = 0;
        gemm16b_kernel<<<dim3(1, 1), 256, 0, stream>>>(p);
    }

    finalize_kernel<<<(out_size + 255) / 256, 256, 0, stream>>>(clsraw, x2, (float*)d_out, out_size);
}

// Round 11
// 233.827 us; speedup vs baseline: 3.7905x; 1.0531x over previous
//
#include <hip/hip_runtime.h>
#include <hip/hip_bf16.h>
#include <math.h>

// TimeBERT forward on MI355X. Inputs fp32 (runtime bf16 detector kept).
// OUTPUT FP32: [cls_pooling (8,128) | last_hidden (8,512,128)].
//
// R11: epilogue fusions. (1) att-out GEMM + residual + LN1 -> x1;
// (2) FFN1+FFN2+residual+LN2 in one kernel (h1 via LDS bf16);
// (3) mta-out K=32 GEMM + assemble (row remap + pos) fused.
// Launches 17 -> 13.

static constexpr int B_ = 8, L_ = 512, DIM_ = 8, ET_ = 128, HID_ = 128, H_ = 2;
static constexpr int NM_ = 8 * 513;           // 4104 main rows
static constexpr int NC_ = 8 * 129;           // 1032 cls rows
static constexpr int NT_ = NM_ + NC_;         // 5136 total (= 321 * 16)

using bf = __hip_bfloat16;
typedef __attribute__((ext_vector_type(8))) short bf16x8;
typedef __attribute__((ext_vector_type(4))) short bf16x4;
typedef __attribute__((ext_vector_type(4))) float floatx4;

__device__ __forceinline__ float wave_reduce_sum(float v) {
    #pragma unroll
    for (int off = 32; off >= 1; off >>= 1) v += __shfl_xor(v, off);
    return v;
}
__device__ __forceinline__ float wave_reduce_max(float v) {
    #pragma unroll
    for (int off = 32; off >= 1; off >>= 1) v = fmaxf(v, __shfl_xor(v, off));
    return v;
}
__device__ __forceinline__ float u2f(unsigned short u) {
    return __uint_as_float(((unsigned)u) << 16);
}
__device__ __forceinline__ unsigned short f2u(float f) {   // RNE, finite
    unsigned u = __float_as_uint(f);
    return (unsigned short)((u + 0x7FFF + ((u >> 16) & 1)) >> 16);
}
__device__ __forceinline__ bf16x8 join8(bf16x4 lo, bf16x4 hi) {
    return __builtin_shufflevector(lo, hi, 0, 1, 2, 3, 4, 5, 6, 7);
}

// ---------------------------------------------------------------------------
__global__ void detect_kernel(const unsigned short* ln1_g_raw, int* flag) {
    if (threadIdx.x == 0 && blockIdx.x == 0)
        *flag = (ln1_g_raw[0] == 0x3F80u) ? 1 : 0;
}

struct ConvArgs {
    const void* src[32];
    int n[32];
    int dstoff[32];
};
__global__ void convert_inputs_kernel(ConvArgs a, float* dst, const int* flag) {
    int which = blockIdx.y;
    int n = a.n[which];
    int i = blockIdx.x * 256 + threadIdx.x;
    if (i >= n) return;
    float v;
    if (*flag) v = __bfloat162float(((const bf*)a.src[which])[i]);
    else       v = ((const float*)a.src[which])[i];
    dst[a.dstoff[which] + i] = v;
}

// ---------------------------------------------------------------------------
__global__ void time_emb_kernel(const float* ts, const float* w_per, const float* b_per,
                                const float* w_lin, const float* b_lin,
                                float* key_e, float* cls_e) {
    int row = blockIdx.x, j = threadIdx.x;  // 128 threads
    float t;
    float* out;
    if (row < 4096) { t = ts[row]; out = key_e + (size_t)row * 128; }
    else { t = (float)(row - 4096) * (1.0f / 127.0f); out = cls_e + (size_t)(row - 4096) * 128; }
    float v;
    if (j == 0) v = t * w_lin[0] + b_lin[0];
    else        v = sinf(t * w_per[j - 1] + b_per[j - 1]);
    out[j] = v;
}

// ---------------------------------------------------------------------------
struct PrepArgs { const float* src[8]; unsigned short* dst[8]; };
__global__ void prep_weights_kernel(PrepArgs p) {
    int m = blockIdx.y;
    const float* W = p.src[m];
    unsigned short* D = p.dst[m];
    int idx = blockIdx.x * 256 + threadIdx.x;   // 0..16383
    int c = idx >> 9;
    int l = (idx >> 3) & 63;
    int j = idx & 7;
    int k = (c >> 3) * 32 + (l >> 4) * 8 + j;
    int n = (c & 7) * 16 + (l & 15);
    D[idx] = f2u(W[k * 128 + n]);
}

// ---------------------------------------------------------------------------
// Plain MFMA GEMM (projections, QKV).
struct GemmM {
    const float* A[3]; const unsigned short* W[3]; const float* bias[3]; float* C[3];
    int M[3]; int act[3];
};
__global__ void __launch_bounds__(256)
gemm_mfma_kernel(GemmM p) {
    int y = blockIdx.y;
    const float* A = p.A[y]; const unsigned short* Wsw = p.W[y];
    const float* bias = p.bias[y]; float* C = p.C[y];
    int M = p.M[y], act = p.act[y];
    int m0 = blockIdx.x * 16;
    if (m0 >= M) return;
    __shared__ unsigned short As[16][136];
    int tid = threadIdx.x;
    {
        int r = tid >> 4, c0 = (tid & 15) * 8;
        float4 v0 = make_float4(0.f, 0.f, 0.f, 0.f), v1 = v0;
        if (m0 + r < M) {
            v0 = *(const float4*)(A + (size_t)(m0 + r) * 128 + c0);
            v1 = *(const float4*)(A + (size_t)(m0 + r) * 128 + c0 + 4);
        }
        *(ushort4*)&As[r][c0] = make_ushort4(f2u(v0.x), f2u(v0.y), f2u(v0.z), f2u(v0.w));
        *(ushort4*)&As[r][c0 + 4] = make_ushort4(f2u(v1.x), f2u(v1.y), f2u(v1.z), f2u(v1.w));
    }
    __syncthreads();

    int wv = tid >> 6, lane = tid & 63;
    floatx4 acc0 = {0.f, 0.f, 0.f, 0.f}, acc1 = acc0;
    int am = lane & 15, aq = lane >> 4;
    #pragma unroll
    for (int ks = 0; ks < 4; ++ks) {
        bf16x8 af = *(bf16x8*)&As[am][ks * 32 + aq * 8];
        const unsigned short* base = Wsw + ((size_t)ks * 8 + 2 * wv) * 512 + lane * 8;
        bf16x8 b0 = *(const bf16x8*)(base);
        bf16x8 b1 = *(const bf16x8*)(base + 512);
        acc0 = __builtin_amdgcn_mfma_f32_16x16x32_bf16(af, b0, acc0, 0, 0, 0);
        acc1 = __builtin_amdgcn_mfma_f32_16x16x32_bf16(af, b1, acc1, 0, 0, 0);
    }
    int col = lane & 15, rowb = (lane >> 4) * 4;
    #pragma unroll
    for (int t = 0; t < 2; ++t) {
        floatx4 acc = t ? acc1 : acc0;
        int n = wv * 32 + t * 16 + col;
        float bv = bias[n];
        #pragma unroll
        for (int rg = 0; rg < 4; ++rg) {
            int m = m0 + rowb + rg;
            if (m < M) {
                float o = acc[rg] + bv;
                if (act) o = fmaxf(o, 0.f);
                C[(size_t)m * 128 + n] = o;
            }
        }
    }
}

// ---------------------------------------------------------------------------
// Fused: C = LN( A@W + bias + resid ) * g + bt.  M must be multiple of 16.
__global__ void __launch_bounds__(256)
gemm_mfma_ln_kernel(const float* A, const unsigned short* Wsw, const float* bias,
                    const float* resid, const float* gam, const float* bet,
                    float* C, int M) {
    int m0 = blockIdx.x * 16;
    __shared__ unsigned short As[16][136];
    __shared__ float redS[4][4][4], redQ[4][4][4];
    __shared__ float smean[16], sinv[16];
    int tid = threadIdx.x;
    {
        int r = tid >> 4, c0 = (tid & 15) * 8;
        float4 v0 = *(const float4*)(A + (size_t)(m0 + r) * 128 + c0);
        float4 v1 = *(const float4*)(A + (size_t)(m0 + r) * 128 + c0 + 4);
        *(ushort4*)&As[r][c0] = make_ushort4(f2u(v0.x), f2u(v0.y), f2u(v0.z), f2u(v0.w));
        *(ushort4*)&As[r][c0 + 4] = make_ushort4(f2u(v1.x), f2u(v1.y), f2u(v1.z), f2u(v1.w));
    }
    __syncthreads();

    int wv = tid >> 6, lane = tid & 63;
    floatx4 acc0 = {0.f, 0.f, 0.f, 0.f}, acc1 = acc0;
    int am = lane & 15, aq = lane >> 4;
    #pragma unroll
    for (int ks = 0; ks < 4; ++ks) {
        bf16x8 af = *(bf16x8*)&As[am][ks * 32 + aq * 8];
        const unsigned short* base = Wsw + ((size_t)ks * 8 + 2 * wv) * 512 + lane * 8;
        bf16x8 b0 = *(const bf16x8*)(base);
        bf16x8 b1 = *(const bf16x8*)(base + 512);
        acc0 = __builtin_amdgcn_mfma_f32_16x16x32_bf16(af, b0, acc0, 0, 0, 0);
        acc1 = __builtin_amdgcn_mfma_f32_16x16x32_bf16(af, b1, acc1, 0, 0, 0);
    }

    int col = lane & 15, g = lane >> 4, rowb = g * 4;
    float ov[2][4];
    #pragma unroll
    for (int t = 0; t < 2; ++t) {
        int n = wv * 32 + t * 16 + col;
        float bv = bias[n];
        floatx4 acc = t ? acc1 : acc0;
        #pragma unroll
        for (int rg = 0; rg < 4; ++rg)
            ov[t][rg] = acc[rg] + bv + resid[(size_t)(m0 + rowb + rg) * 128 + n];
    }
    // row partials (32 cols per wave-group) -> LDS -> cross-wave reduce
    #pragma unroll
    for (int rg = 0; rg < 4; ++rg) {
        float s = ov[0][rg] + ov[1][rg];
        float q = ov[0][rg] * ov[0][rg] + ov[1][rg] * ov[1][rg];
        #pragma unroll
        for (int off = 8; off >= 1; off >>= 1) {
            s += __shfl_xor(s, off);
            q += __shfl_xor(q, off);
        }
        if ((lane & 15) == 0) { redS[wv][g][rg] = s; redQ[wv][g][rg] = q; }
    }
    __syncthreads();
    if (tid < 16) {
        int gg = tid >> 2, rg = tid & 3;
        float s = redS[0][gg][rg] + redS[1][gg][rg] + redS[2][gg][rg] + redS[3][gg][rg];
        float q = redQ[0][gg][rg] + redQ[1][gg][rg] + redQ[2][gg][rg] + redQ[3][gg][rg];
        float mean = s * 0.0078125f;
        float var = q * 0.0078125f - mean * mean;
        smean[tid] = mean;
        sinv[tid] = rsqrtf(var + 1e-5f);
    }
    __syncthreads();
    #pragma unroll
    for (int t = 0; t < 2; ++t) {
        int n = wv * 32 + t * 16 + col;
        float gm = gam[n], bb = bet[n];
        #pragma unroll
        for (int rg = 0; rg < 4; ++rg) {
            int row = rowb + rg;
            float o = (ov[t][rg] - smean[row]) * sinv[row] * gm + bb;
            C[(size_t)(m0 + row) * 128 + n] = o;
        }
    }
}

// ---------------------------------------------------------------------------
// Fused FFN: x2 = LN( relu(x1@W1+b1)@W2 + b2 + x1 ) * g + bt.
__global__ void __launch_bounds__(256)
ffn_ln_kernel(const float* x1, const unsigned short* W1, const float* b1,
              const unsigned short* W2, const float* b2,
              const float* gam, const float* bet, float* C, int M) {
    int m0 = blockIdx.x * 16;
    __shared__ float Xs[16][128];            // fp32 input / residual
    __shared__ unsigned short As[16][136];
    __shared__ unsigned short Hs[16][136];   // relu(h1) bf16
    __shared__ float redS[4][4][4], redQ[4][4][4];
    __shared__ float smean[16], sinv[16];
    int tid = threadIdx.x;
    {
        int r = tid >> 4, c0 = (tid & 15) * 8;
        float4 v0 = *(const float4*)(x1 + (size_t)(m0 + r) * 128 + c0);
        float4 v1 = *(const float4*)(x1 + (size_t)(m0 + r) * 128 + c0 + 4);
        *(float4*)&Xs[r][c0] = v0;
        *(float4*)&Xs[r][c0 + 4] = v1;
        *(ushort4*)&As[r][c0] = make_ushort4(f2u(v0.x), f2u(v0.y), f2u(v0.z), f2u(v0.w));
        *(ushort4*)&As[r][c0 + 4] = make_ushort4(f2u(v1.x), f2u(v1.y), f2u(v1.z), f2u(v1.w));
    }
    __syncthreads();

    int wv = tid >> 6, lane = tid & 63;
    int am = lane & 15, aq = lane >> 4;
    int col = lane & 15, g = lane >> 4, rowb = g * 4;

    // --- h1 = relu(x1@W1 + b1), bf16 into Hs ---
    {
        floatx4 acc0 = {0.f, 0.f, 0.f, 0.f}, acc1 = acc0;
        #pragma unroll
        for (int ks = 0; ks < 4; ++ks) {
            bf16x8 af = *(bf16x8*)&As[am][ks * 32 + aq * 8];
            const unsigned short* base = W1 + ((size_t)ks * 8 + 2 * wv) * 512 + lane * 8;
            bf16x8 bb0 = *(const bf16x8*)(base);
            bf16x8 bb1 = *(const bf16x8*)(base + 512);
            acc0 = __builtin_amdgcn_mfma_f32_16x16x32_bf16(af, bb0, acc0, 0, 0, 0);
            acc1 = __builtin_amdgcn_mfma_f32_16x16x32_bf16(af, bb1, acc1, 0, 0, 0);
        }
        #pragma unroll
        for (int t = 0; t < 2; ++t) {
            int n = wv * 32 + t * 16 + col;
            float bv = b1[n];
            floatx4 acc = t ? acc1 : acc0;
            #pragma unroll
            for (int rg = 0; rg < 4; ++rg)
                Hs[rowb + rg][n] = f2u(fmaxf(acc[rg] + bv, 0.f));
        }
    }
    __syncthreads();

    // --- out = h1@W2 + b2 + x1, then LN ---
    floatx4 acc0 = {0.f, 0.f, 0.f, 0.f}, acc1 = acc0;
    #pragma unroll
    for (int ks = 0; ks < 4; ++ks) {
        bf16x8 af = *(bf16x8*)&Hs[am][ks * 32 + aq * 8];
        const unsigned short* base = W2 + ((size_t)ks * 8 + 2 * wv) * 512 + lane * 8;
        bf16x8 bb0 = *(const bf16x8*)(base);
        bf16x8 bb1 = *(const bf16x8*)(base + 512);
        acc0 = __builtin_amdgcn_mfma_f32_16x16x32_bf16(af, bb0, acc0, 0, 0, 0);
        acc1 = __builtin_amdgcn_mfma_f32_16x16x32_bf16(af, bb1, acc1, 0, 0, 0);
    }
    float ov[2][4];
    #pragma unroll
    for (int t = 0; t < 2; ++t) {
        int n = wv * 32 + t * 16 + col;
        float bv = b2[n];
        floatx4 acc = t ? acc1 : acc0;
        #pragma unroll
        for (int rg = 0; rg < 4; ++rg)
            ov[t][rg] = acc[rg] + bv + Xs[rowb + rg][n];
    }
    #pragma unroll
    for (int rg = 0; rg < 4; ++rg) {
        float s = ov[0][rg] + ov[1][rg];
        float q = ov[0][rg] * ov[0][rg] + ov[1][rg] * ov[1][rg];
        #pragma unroll
        for (int off = 8; off >= 1; off >>= 1) {
            s += __shfl_xor(s, off);
            q += __shfl_xor(q, off);
        }
        if ((lane & 15) == 0) { redS[wv][g][rg] = s; redQ[wv][g][rg] = q; }
    }
    __syncthreads();
    if (tid < 16) {
        int gg = tid >> 2, rg = tid & 3;
        float s = redS[0][gg][rg] + redS[1][gg][rg] + redS[2][gg][rg] + redS[3][gg][rg];
        float q = redQ[0][gg][rg] + redQ[1][gg][rg] + redQ[2][gg][rg] + redQ[3][gg][rg];
        float mean = s * 0.0078125f;
        float var = q * 0.0078125f - mean * mean;
        smean[tid] = mean;
        sinv[tid] = rsqrtf(var + 1e-5f);
    }
    __syncthreads();
    #pragma unroll
    for (int t = 0; t < 2; ++t) {
        int n = wv * 32 + t * 16 + col;
        float gm = gam[n], bb = bet[n];
        #pragma unroll
        for (int rg = 0; rg < 4; ++rg) {
            int row = rowb + rg;
            C[(size_t)(m0 + row) * 128 + n] = (ov[t][rg] - smean[row]) * sinv[row] * gm + bb;
        }
    }
    (void)M;
}

// ---------------------------------------------------------------------------
// Fused mta-out projection (K=32) + assemble into xin (row remap + pos).
// Grid 321: blocks 0..319 = GEMM tiles over 5120 att rows; block 320 writes
// the 16 cls_emb rows.
__global__ void mta_out_assemble_kernel(const float* att, const float* W, const float* bias,
                                        const float* cls_emb, const float* pos, float* xin) {
    int tid = threadIdx.x;
    if (blockIdx.x == 320) {
        for (int e = tid; e < 16 * 128; e += 256) {
            int i = e >> 7, j = e & 127;
            int b = i >> 1;
            if ((i & 1) == 0) xin[(size_t)(b * 513) * 128 + j] = cls_emb[j] + pos[j];
            else              xin[(size_t)(4104 + b * 129) * 128 + j] = cls_emb[j];
        }
        return;
    }
    int m0 = blockIdx.x * 16;
    __shared__ float As[16][36];
    int r = tid >> 4, gq = tid & 15, c0 = gq * 8;
    if (gq < 2) {
        float4 v0 = *(const float4*)(att + (size_t)(m0 + r) * 32 + gq * 16);
        float4 v1 = *(const float4*)(att + (size_t)(m0 + r) * 32 + gq * 16 + 4);
        float4 v2 = *(const float4*)(att + (size_t)(m0 + r) * 32 + gq * 16 + 8);
        float4 v3 = *(const float4*)(att + (size_t)(m0 + r) * 32 + gq * 16 + 12);
        *(float4*)&As[r][gq * 16] = v0;
        *(float4*)&As[r][gq * 16 + 4] = v1;
        *(float4*)&As[r][gq * 16 + 8] = v2;
        *(float4*)&As[r][gq * 16 + 12] = v3;
    }
    __syncthreads();
    float acc[8];
    #pragma unroll
    for (int j = 0; j < 8; ++j) acc[j] = bias[c0 + j];
    #pragma unroll 8
    for (int k = 0; k < 32; ++k) {
        float a = As[r][k];
        const float4 w0 = *(const float4*)(W + (size_t)k * 128 + c0);
        const float4 w1 = *(const float4*)(W + (size_t)k * 128 + c0 + 4);
        acc[0] = fmaf(a, w0.x, acc[0]); acc[1] = fmaf(a, w0.y, acc[1]);
        acc[2] = fmaf(a, w0.z, acc[2]); acc[3] = fmaf(a, w0.w, acc[3]);
        acc[4] = fmaf(a, w1.x, acc[4]); acc[5] = fmaf(a, w1.y, acc[5]);
        acc[6] = fmaf(a, w1.z, acc[6]); acc[7] = fmaf(a, w1.w, acc[7]);
    }
    int m = m0 + r;
    size_t dstrow;
    if (m < 1024) {   // cls problem rows (no pos)
        int b = m >> 7, rr = m & 127;
        dstrow = (size_t)(4104 + b * 129 + 1 + rr);
    } else {          // main rows (+pos)
        int mm = m - 1024;
        int b = mm >> 9, rr = mm & 511;
        dstrow = (size_t)(b * 513 + 1 + rr);
        const float* pr = pos + (size_t)(1 + rr) * 128 + c0;
        float4 p0 = *(const float4*)(pr);
        float4 p1 = *(const float4*)(pr + 4);
        acc[0] += p0.x; acc[1] += p0.y; acc[2] += p0.z; acc[3] += p0.w;
        acc[4] += p1.x; acc[5] += p1.y; acc[6] += p1.z; acc[7] += p1.w;
    }
    *(float4*)(xin + dstrow * 128 + c0) = make_float4(acc[0], acc[1], acc[2], acc[3]);
    *(float4*)(xin + dstrow * 128 + c0 + 4) = make_float4(acc[4], acc[5], acc[6], acc[7]);
}

// ---------------------------------------------------------------------------
// mta attention (unchanged from R10).
__global__ void __launch_bounds__(256)
mta_att_kernel(const float* qp_cls, const float* qp_main, const float* kp,
               const float* x, float* att_cls, float* att_mn) {
    int is_cls = (blockIdx.x >= 32);
    int qt = is_cls ? (blockIdx.x - 32) : blockIdx.x;
    int h = blockIdx.y, b = blockIdx.z;
    int tid = threadIdx.x, lane = tid & 63, wv = tid >> 6;
    __shared__ unsigned short Qs[16][72];
    __shared__ unsigned short KV[64][76];
    __shared__ unsigned short sp[16][520];
    float* xv = (float*)&KV[0][0];
    int q0 = qt * 16;

    {
        int r = tid >> 4, c0 = (tid & 15) * 4;
        const float* qrow = is_cls ? (qp_cls + (size_t)(q0 + r) * 128 + h * 64)
                                   : (qp_main + (size_t)(b * 512 + q0 + r) * 128 + h * 64);
        float4 v = *(const float4*)(qrow + c0);
        *(ushort4*)&Qs[r][c0] = make_ushort4(f2u(v.x * 0.125f), f2u(v.y * 0.125f),
                                             f2u(v.z * 0.125f), f2u(v.w * 0.125f));
    }
    __syncthreads();

    bf16x8 qf0, qf1;
    {
        int m = lane & 15, g = lane >> 4;
        qf0 = *(const bf16x8*)&Qs[m][g * 8];
        qf1 = *(const bf16x8*)&Qs[m][32 + g * 8];
    }

    for (int kt = 0; kt < 8; ++kt) {
        int k0 = kt * 64;
        {
            int kk = tid >> 4, e0 = (tid & 15) * 4;
            #pragma unroll
            for (int it = 0; it < 4; ++it, kk += 16) {
                float4 v = *(const float4*)(kp + (size_t)(b * 512 + k0 + kk) * 128 + h * 64 + e0);
                *(ushort4*)&KV[kk][e0] = make_ushort4(f2u(v.x), f2u(v.y), f2u(v.z), f2u(v.w));
            }
        }
        __syncthreads();
        int kn = lane & 15, g = lane >> 4;
        floatx4 acc = {0.f, 0.f, 0.f, 0.f};
        {
            bf16x4 lo0 = *(const bf16x4*)&KV[wv * 16 + kn][g * 8];
            bf16x4 hi0 = *(const bf16x4*)&KV[wv * 16 + kn][g * 8 + 4];
            acc = __builtin_amdgcn_mfma_f32_16x16x32_bf16(qf0, join8(lo0, hi0), acc, 0, 0, 0);
            bf16x4 lo1 = *(const bf16x4*)&KV[wv * 16 + kn][32 + g * 8];
            bf16x4 hi1 = *(const bf16x4*)&KV[wv * 16 + kn][32 + g * 8 + 4];
            acc = __builtin_amdgcn_mfma_f32_16x16x32_bf16(qf1, join8(lo1, hi1), acc, 0, 0, 0);
        }
        int colk = k0 + wv * 16 + kn;
        #pragma unroll
        for (int rg = 0; rg < 4; ++rg) sp[g * 4 + rg][colk] = f2u(acc[rg]);
        __syncthreads();
    }

    for (int rr = wv; rr < 16; rr += 4) {
        float m = -1e30f;
        for (int k = lane; k < 512; k += 64) m = fmaxf(m, u2f(sp[rr][k]));
        m = wave_reduce_max(m);
        for (int k = lane; k < 512; k += 64) sp[rr][k] = f2u(expf(u2f(sp[rr][k]) - m));
    }

    int d = lane >> 3, sub = lane & 7;
    int qb = wv * 4;
    float num[4] = {0.f, 0.f, 0.f, 0.f}, den[4] = {0.f, 0.f, 0.f, 0.f};
    for (int kt = 0; kt < 8; ++kt) {
        int k0 = kt * 64;
        __syncthreads();
        {
            int kk = tid >> 2, c0 = (tid & 3) * 4;
            float4 v = *(const float4*)(x + (size_t)(b * 512 + k0 + kk) * 16 + c0);
            xv[kk * 17 + c0] = v.x; xv[kk * 17 + c0 + 1] = v.y;
            xv[kk * 17 + c0 + 2] = v.z; xv[kk * 17 + c0 + 3] = v.w;
        }
        __syncthreads();
        #pragma unroll
        for (int i = 0; i < 8; ++i) {
            int kk = sub + 8 * i;
            float mk = xv[kk * 17 + 8 + d];
            float vv = xv[kk * 17 + d];
            #pragma unroll
            for (int q = 0; q < 4; ++q) {
                float em = u2f(sp[qb + q][k0 + kk]) * mk;
                den[q] += em;
                num[q] = fmaf(em, vv, num[q]);
            }
        }
    }
    #pragma unroll
    for (int q = 0; q < 4; ++q) {
        #pragma unroll
        for (int off2 = 4; off2 >= 1; off2 >>= 1) {
            num[q] += __shfl_xor(num[q], off2);
            den[q] += __shfl_xor(den[q], off2);
        }
        if (sub == 0) {
            int row = q0 + qb + q;
            float* dst = is_cls ? (att_cls + (size_t)(b * 128 + row) * 32)
                                : (att_mn + (size_t)(b * 512 + row) * 32);
            dst[h * 16 + d] = num[q] / den[q];
            dst[h * 16 + 8 + d] = 1.0f;
        }
    }
}

// ---------------------------------------------------------------------------
// tblock attention (unchanged from R10).
__global__ void __launch_bounds__(256)
tb_att_kernel(const float* qp, const float* kp, const float* vp, float* outp) {
    int is_cls = (blockIdx.x >= 33);
    int qt = is_cls ? blockIdx.x - 33 : blockIdx.x;
    int h = blockIdx.y, b = blockIdx.z;
    int Lq = is_cls ? 129 : 513;
    int base = is_cls ? (4104 + b * 129) : (b * 513);
    int nkt = is_cls ? 3 : 9;
    int tid = threadIdx.x, lane = tid & 63, wv = tid >> 6;
    __shared__ unsigned short Qs[16][72];
    __shared__ unsigned short KV[64][76];
    __shared__ unsigned short sp[16][588];
    __shared__ float rinv[16];
    int q0 = qt * 16;

    {
        int r = tid >> 4, c0 = (tid & 15) * 4;
        int qr = q0 + r;
        float4 v = make_float4(0.f, 0.f, 0.f, 0.f);
        if (qr < Lq) v = *(const float4*)(qp + (size_t)(base + qr) * 128 + h * 64 + c0);
        *(ushort4*)&Qs[r][c0] = make_ushort4(f2u(v.x * 0.125f), f2u(v.y * 0.125f),
                                             f2u(v.z * 0.125f), f2u(v.w * 0.125f));
    }
    __syncthreads();

    bf16x8 qf0, qf1;
    {
        int m = lane & 15, g = lane >> 4;
        qf0 = *(const bf16x8*)&Qs[m][g * 8];
        qf1 = *(const bf16x8*)&Qs[m][32 + g * 8];
    }

    for (int kt = 0; kt < nkt; ++kt) {
        int k0 = kt * 64;
        {
            int kk = tid >> 4, e0 = (tid & 15) * 4;
            #pragma unroll
            for (int it = 0; it < 4; ++it, kk += 16) {
                int krow = k0 + kk;
                float4 v = make_float4(0.f, 0.f, 0.f, 0.f);
                if (krow < Lq) v = *(const float4*)(kp + (size_t)(base + krow) * 128 + h * 64 + e0);
                *(ushort4*)&KV[kk][e0] = make_ushort4(f2u(v.x), f2u(v.y), f2u(v.z), f2u(v.w));
            }
        }
        __syncthreads();
        int kn = lane & 15, g = lane >> 4;
        floatx4 acc = {0.f, 0.f, 0.f, 0.f};
        {
            bf16x4 lo0 = *(const bf16x4*)&KV[wv * 16 + kn][g * 8];
            bf16x4 hi0 = *(const bf16x4*)&KV[wv * 16 + kn][g * 8 + 4];
            acc = __builtin_amdgcn_mfma_f32_16x16x32_bf16(qf0, join8(lo0, hi0), acc, 0, 0, 0);
            bf16x4 lo1 = *(const bf16x4*)&KV[wv * 16 + kn][32 + g * 8];
            bf16x4 hi1 = *(const bf16x4*)&KV[wv * 16 + kn][32 + g * 8 + 4];
            acc = __builtin_amdgcn_mfma_f32_16x16x32_bf16(qf1, join8(lo1, hi1), acc, 0, 0, 0);
        }
        int colk = k0 + wv * 16 + kn;
        #pragma unroll
        for (int rg = 0; rg < 4; ++rg)
            sp[g * 4 + rg][colk] = f2u((colk < Lq) ? acc[rg] : -1e30f);
        __syncthreads();
    }

    int kend = nkt * 64;
    for (int rr = wv; rr < 16; rr += 4) {
        float m = -1e30f;
        for (int k = lane; k < kend; k += 64) m = fmaxf(m, u2f(sp[rr][k]));
        m = wave_reduce_max(m);
        float sum = 0.f;
        for (int k = lane; k < kend; k += 64) {
            float e = expf(u2f(sp[rr][k]) - m);
            sp[rr][k] = f2u(e);
            sum += e;
        }
        sum = wave_reduce_sum(sum);
        if (lane == 0) rinv[rr] = 1.f / sum;
    }

    floatx4 oacc = {0.f, 0.f, 0.f, 0.f};
    for (int kt = 0; kt < nkt; ++kt) {
        int k0 = kt * 64;
        __syncthreads();
        {
            int kk = tid >> 4, e0 = (tid & 15) * 4;
            #pragma unroll
            for (int it = 0; it < 4; ++it, kk += 16) {
                int krow = k0 + kk;
                float4 v = make_float4(0.f, 0.f, 0.f, 0.f);
                if (krow < Lq) v = *(const float4*)(vp + (size_t)(base + krow) * 128 + h * 64 + e0);
                KV[e0][kk] = f2u(v.x);
                KV[e0 + 1][kk] = f2u(v.y);
                KV[e0 + 2][kk] = f2u(v.z);
                KV[e0 + 3][kk] = f2u(v.w);
            }
        }
        __syncthreads();
        int dn = lane & 15, g = lane >> 4;
        #pragma unroll
        for (int c = 0; c < 2; ++c) {
            bf16x4 plo = *(const bf16x4*)&sp[lane & 15][k0 + c * 32 + g * 8];
            bf16x4 phi = *(const bf16x4*)&sp[lane & 15][k0 + c * 32 + g * 8 + 4];
            bf16x4 vlo = *(const bf16x4*)&KV[wv * 16 + dn][c * 32 + g * 8];
            bf16x4 vhi = *(const bf16x4*)&KV[wv * 16 + dn][c * 32 + g * 8 + 4];
            oacc = __builtin_amdgcn_mfma_f32_16x16x32_bf16(join8(plo, phi), join8(vlo, vhi), oacc, 0, 0, 0);
        }
    }
    int dcol = wv * 16 + (lane & 15), g = lane >> 4;
    #pragma unroll
    for (int rg = 0; rg < 4; ++rg) {
        int q = g * 4 + rg;
        int qr = q0 + q;
        if (qr < Lq)
            outp[(size_t)(base + qr) * 128 + h * 64 + dcol] = oacc[rg] * rinv[q];
    }
}

// ---------------------------------------------------------------------------
// Legacy VALU GEMM (pooling only).
struct GemmBatch {
    const float* A[3]; const float* W[3]; const float* bias[3]; float* C[3];
    int lda[3], ldc[3], M[3], K[3], act[3];
};
__global__ void gemm16b_kernel(GemmBatch p) {
    int y = blockIdx.y;
    const float* A = p.A[y]; const float* W = p.W[y]; const float* bias = p.bias[y];
    float* C = p.C[y];
    int lda = p.lda[y], ldc = p.ldc[y], M = p.M[y], K = p.K[y], act = p.act[y];
    int m0 = blockIdx.x * 16;
    if (m0 >= M) return;
    __shared__ float As[16][132];
    int tid = threadIdx.x;
    int r = tid >> 4, g = tid & 15, c0 = g * 8;
    for (int c = g; c < K; c += 16) {
        float v = 0.f;
        if (m0 + r < M) v = A[(size_t)(m0 + r) * lda + c];
        As[r][c] = v;
    }
    __syncthreads();
    float acc[8];
    #pragma unroll
    for (int j = 0; j < 8; ++j) acc[j] = bias[c0 + j];
    for (int k = 0; k < K; ++k) {
        float a = As[r][k];
        const float4 w0 = *(const float4*)(W + (size_t)k * 128 + c0);
        const float4 w1 = *(const float4*)(W + (size_t)k * 128 + c0 + 4);
        acc[0] = fmaf(a, w0.x, acc[0]); acc[1] = fmaf(a, w0.y, acc[1]);
        acc[2] = fmaf(a, w0.z, acc[2]); acc[3] = fmaf(a, w0.w, acc[3]);
        acc[4] = fmaf(a, w1.x, acc[4]); acc[5] = fmaf(a, w1.y, acc[5]);
        acc[6] = fmaf(a, w1.z, acc[6]); acc[7] = fmaf(a, w1.w, acc[7]);
    }
    if (act == 1) {
        #pragma unroll
        for (int j = 0; j < 8; ++j) acc[j] = fmaxf(acc[j], 0.f);
    }
    if (m0 + r < M) {
        *(float4*)(C + (size_t)(m0 + r) * ldc + c0) = make_float4(acc[0], acc[1], acc[2], acc[3]);
        *(float4*)(C + (size_t)(m0 + r) * ldc + c0 + 4) = make_float4(acc[4], acc[5], acc[6], acc[7]);
    }
}

// ---------------------------------------------------------------------------
__global__ void finalize_kernel(const float* clsraw, const float* h2, float* out, int total) {
    int idx = blockIdx.x * 256 + threadIdx.x;
    if (idx >= total) return;
    float v;
    if (idx < 1024) {
        v = tanhf(clsraw[idx]);
    } else {
        int t = idx - 1024;
        int b = t >> 16;
        int rem = t & 65535;
        int i = rem >> 7, j = rem & 127;
        v = h2[((size_t)(b * 513 + 1 + i)) * 128 + j];
    }
    out[idx] = v;
}

// ---------------------------------------------------------------------------
extern "C" void kernel_launch(void* const* d_in, const int* in_sizes, int n_in,
                              void* d_out, int out_size, void* d_ws, size_t ws_size,
                              hipStream_t stream) {
    float* w = (float*)d_ws;
    size_t off = 0;
    auto alloc = [&](size_t n) {
        float* p = w + off;
        off += (n + 3) & ~(size_t)3;
        return p;
    };

    int* flag = (int*)alloc(4);

    ConvArgs ca;
    int nn = n_in < 32 ? n_in : 32;
    int max_n = 0;
    float* fin[32];
    for (int i = 0; i < nn; ++i) {
        ca.src[i] = d_in[i];
        ca.n[i] = in_sizes[i];
        fin[i] = alloc(in_sizes[i]);
        ca.dstoff[i] = (int)(fin[i] - w);
        if (in_sizes[i] > max_n) max_n = in_sizes[i];
    }
    for (int i = nn; i < 32; ++i) { ca.src[i] = nullptr; ca.n[i] = 0; ca.dstoff[i] = 0; }

    const float* x     = fin[0];
    const float* ts    = fin[1];
    const float* w_per = fin[2];  const float* b_per = fin[3];
    const float* w_lin = fin[4];  const float* b_lin = fin[5];
    const float* Wq_t  = fin[6];  const float* bq_t  = fin[7];
    const float* Wk_t  = fin[8];  const float* bk_t  = fin[9];
    const float* Wo_t  = fin[10]; const float* bo_t  = fin[11];
    const float* pos_emb = fin[12]; const float* cls_emb = fin[13];
    const float* tWq = fin[14]; const float* tbq = fin[15];
    const float* tWk = fin[16]; const float* tbk = fin[17];
    const float* tWv = fin[18]; const float* tbv = fin[19];
    const float* tWo = fin[20]; const float* tbo = fin[21];
    const float* ln1_g = fin[22]; const float* ln1_b = fin[23];
    const float* fW1 = fin[24]; const float* fb1 = fin[25];
    const float* fW2 = fin[26]; const float* fb2 = fin[27];
    const float* ln2_g = fin[28]; const float* ln2_b = fin[29];
    const float* pW = fin[30]; const float* pb = fin[31];

    unsigned short* wsw[8];
    const float* wsrc[8] = {Wk_t, Wq_t, tWq, tWk, tWv, tWo, fW1, fW2};
    for (int i = 0; i < 8; ++i) wsw[i] = (unsigned short*)alloc(8192);

    float* key_e   = alloc(4096 * 128);
    float* cls_e   = alloc(128 * 128);
    float* qp_main = alloc(4096 * 128);
    float* kp_main = alloc(4096 * 128);
    float* qp_cls  = alloc(128 * 128);
    float* att_all = alloc(5120 * 32);
    float* att_cls = att_all;
    float* att_mn  = att_all + 1024 * 32;
    float* xin     = alloc((size_t)NT_ * 128);
    float* tb_q    = alloc((size_t)NT_ * 128);
    float* tb_k    = alloc((size_t)NT_ * 128);
    float* tb_v    = alloc((size_t)NT_ * 128);
    float* tb_a    = alloc((size_t)NT_ * 128);
    float* tb_x1   = alloc((size_t)NT_ * 128);
    float* x2      = alloc((size_t)NT_ * 128);
    float* clsraw  = alloc(8 * 128);
    (void)ws_size;

    detect_kernel<<<1, 1, 0, stream>>>((const unsigned short*)d_in[22], flag);
    convert_inputs_kernel<<<dim3((max_n + 255) / 256, 32), 256, 0, stream>>>(ca, w, flag);

    {
        PrepArgs pa;
        for (int i = 0; i < 8; ++i) { pa.src[i] = wsrc[i]; pa.dst[i] = wsw[i]; }
        prep_weights_kernel<<<dim3(64, 8), 256, 0, stream>>>(pa);
    }

    time_emb_kernel<<<4224, 128, 0, stream>>>(ts, w_per, b_per, w_lin, b_lin, key_e, cls_e);

    {   // mta projections (MFMA)
        GemmM p{};
        p.A[0] = key_e; p.W[0] = wsw[0]; p.bias[0] = bk_t; p.C[0] = kp_main; p.M[0] = 4096; p.act[0] = 0;
        p.A[1] = key_e; p.W[1] = wsw[1]; p.bias[1] = bq_t; p.C[1] = qp_main; p.M[1] = 4096; p.act[1] = 0;
        p.A[2] = cls_e; p.W[2] = wsw[1]; p.bias[2] = bq_t; p.C[2] = qp_cls;  p.M[2] = 128;  p.act[2] = 0;
        gemm_mfma_kernel<<<dim3(256, 3), 256, 0, stream>>>(p);
    }

    mta_att_kernel<<<dim3(40, 2, 8), 256, 0, stream>>>(qp_cls, qp_main, kp_main, x, att_cls, att_mn);

    // mta out-projection + assemble fused (321st block writes cls rows)
    mta_out_assemble_kernel<<<321, 256, 0, stream>>>(att_all, Wo_t, bo_t, cls_emb, pos_emb, xin);

    {   // QKV (MFMA, batched)
        GemmM p{};
        const unsigned short* Ws[3] = {wsw[2], wsw[3], wsw[4]};
        const float* bs[3] = {tbq, tbk, tbv};
        float* Cs[3] = {tb_q, tb_k, tb_v};
        for (int y = 0; y < 3; ++y) {
            p.A[y] = xin; p.W[y] = Ws[y]; p.bias[y] = bs[y]; p.C[y] = Cs[y];
            p.M[y] = NT_; p.act[y] = 0;
        }
        gemm_mfma_kernel<<<dim3((NT_ + 15) / 16, 3), 256, 0, stream>>>(p);
    }
    tb_att_kernel<<<dim3(42, 2, 8), 256, 0, stream>>>(tb_q, tb_k, tb_v, tb_a);

    // att-out + residual + LN1 fused -> x1
    gemm_mfma_ln_kernel<<<NT_ / 16, 256, 0, stream>>>(tb_a, wsw[5], tbo, xin, ln1_g, ln1_b, tb_x1, NT_);

    // FFN1+FFN2 + residual + LN2 fused -> x2
    ffn_ln_kernel<<<NT_ / 16, 256, 0, stream>>>(tb_x1, wsw[6], fb1, wsw[7], fb2, ln2_g, ln2_b, x2, NT_);

    {   // cls pooling
        GemmBatch p{};
        p.A[0] = x2 + (size_t)4104 * 128; p.W[0] = pW; p.bias[0] = pb; p.C[0] = clsraw;
        p.lda[0] = 129 * 128; p.ldc[0] = 128; p.M[0] = 8; p.K[0] = 128; p.act[0] = 0;
        gemm16b_kernel<<<dim3(1, 1), 256, 0, stream>>>(p);
    }

    finalize_kernel<<<(out_size + 255) / 256, 256, 0, stream>>>(clsraw, x2, (float*)d_out, out_size);
}

// Round 12
// 202.474 us; speedup vs baseline: 4.3774x; 1.1548x over previous
//
#include <hip/hip_runtime.h>
#include <hip/hip_bf16.h>
#include <math.h>

// TimeBERT forward on MI355X. Inputs fp32 (runtime bf16 detector kept, inline).
// OUTPUT FP32: [cls_pooling (8,128) | last_hidden (8,512,128)].
//
// R12: bf16 end-to-end between GEMMs and attention (GEMMs emit bf16; attention
// stages by pure ushort8 copy; 0.125 folded into Wq swizzle+bias — exact);
// prep_all mega-kernel replaces detect/convert/prep/time_emb. 10 launches.

static constexpr int NM_ = 8 * 513;           // 4104 main rows
static constexpr int NC_ = 8 * 129;           // 1032 cls rows
static constexpr int NT_ = NM_ + NC_;         // 5136 total (= 321 * 16)

using bf = __hip_bfloat16;
typedef __attribute__((ext_vector_type(8))) short bf16x8;
typedef __attribute__((ext_vector_type(4))) short bf16x4;
typedef __attribute__((ext_vector_type(4))) float floatx4;
typedef __attribute__((ext_vector_type(8))) unsigned short ushortx8;

__device__ __forceinline__ float wave_reduce_sum(float v) {
    #pragma unroll
    for (int off = 32; off >= 1; off >>= 1) v += __shfl_xor(v, off);
    return v;
}
__device__ __forceinline__ float wave_reduce_max(float v) {
    #pragma unroll
    for (int off = 32; off >= 1; off >>= 1) v = fmaxf(v, __shfl_xor(v, off));
    return v;
}
__device__ __forceinline__ float u2f(unsigned short u) {
    return __uint_as_float(((unsigned)u) << 16);
}
__device__ __forceinline__ unsigned short f2u(float f) {   // RNE, finite
    unsigned u = __float_as_uint(f);
    return (unsigned short)((u + 0x7FFF + ((u >> 16) & 1)) >> 16);
}
__device__ __forceinline__ bf16x8 join8(bf16x4 lo, bf16x4 hi) {
    return __builtin_shufflevector(lo, hi, 0, 1, 2, 3, 4, 5, 6, 7);
}
// dtype-agnostic input read (flag=1: bf16 raw, else fp32)
__device__ __forceinline__ float rdin(const void* p, int i, int flag) {
    return flag ? u2f(((const unsigned short*)p)[i]) : ((const float*)p)[i];
}

// ---------------------------------------------------------------------------
// prep_all: blocks [0,8224) convert 32 inputs -> fp32 ws; [8224,8736) swizzle
// 8 weight mats -> bf16 B-frag order (with per-matrix scale); [8736,10848)
// time embedding -> bf16 key_e/cls_e. Dtype flag computed inline per block.
struct PrepAll {
    const void* src[32]; int n[32]; int dstoff[32];
    const void* wsrc[8]; unsigned short* wdst[8]; float wscale[8];
    const void* ts; const void* w_per; const void* b_per;
    const void* w_lin; const void* b_lin;
    unsigned short* key_e16;        // 4224 rows x 128 (rows >=4096 = cls)
    const unsigned short* det;
};
__global__ void prep_all_kernel(PrepAll a, float* dst) {
    int flag = (a.det[0] == 0x3F80u) ? 1 : 0;
    int blk = blockIdx.x, tid = threadIdx.x;
    if (blk < 8224) {
        int which = blk / 257, bi = blk - which * 257;
        int i = bi * 256 + tid;
        if (i < a.n[which]) dst[a.dstoff[which] + i] = rdin(a.src[which], i, flag);
    } else if (blk < 8736) {
        int p = blk - 8224;
        int m = p >> 6;
        int idx = (p & 63) * 256 + tid;     // 0..16383
        int c = idx >> 9;
        int l = (idx >> 3) & 63;
        int j = idx & 7;
        int k = (c >> 3) * 32 + (l >> 4) * 8 + j;
        int n = (c & 7) * 16 + (l & 15);
        a.wdst[m][idx] = f2u(rdin(a.wsrc[m], k * 128 + n, flag) * a.wscale[m]);
    } else {
        int p = blk - 8736;
        int row = p * 2 + (tid >> 7), j = tid & 127;
        float t = (row < 4096) ? rdin(a.ts, row, flag)
                               : (float)(row - 4096) * (1.0f / 127.0f);
        float v;
        if (j == 0) v = t * rdin(a.w_lin, 0, flag) + rdin(a.b_lin, 0, flag);
        else        v = sinf(t * rdin(a.w_per, j - 1, flag) + rdin(a.b_per, j - 1, flag));
        a.key_e16[row * 128 + j] = f2u(v);
    }
}

// ---------------------------------------------------------------------------
// MFMA GEMM: C16[m,n] = bf16( act(A@W + bias*bscale) ). A fp32 or bf16.
struct GemmM {
    const void* A[3]; const unsigned short* W[3]; const float* bias[3];
    unsigned short* C[3];
    int M[3]; int act[3]; int abf[3]; float bscale[3];
};
__global__ void __launch_bounds__(256)
gemm_mfma_kernel(GemmM p) {
    int y = blockIdx.y;
    const unsigned short* Wsw = p.W[y];
    const float* bias = p.bias[y];
    unsigned short* C = p.C[y];
    int M = p.M[y], act = p.act[y], abf = p.abf[y];
    float bscale = p.bscale[y];
    int m0 = blockIdx.x * 16;
    if (m0 >= M) return;
    __shared__ unsigned short As[16][136];
    int tid = threadIdx.x;
    if (abf) {
        const unsigned short* A = (const unsigned short*)p.A[y];
        int r = tid >> 4, c0 = (tid & 15) * 8;
        ushortx8 v = {0, 0, 0, 0, 0, 0, 0, 0};
        if (m0 + r < M) v = *(const ushortx8*)(A + (size_t)(m0 + r) * 128 + c0);
        *(ushortx8*)&As[r][c0] = v;
    } else {
        const float* A = (const float*)p.A[y];
        int r = tid >> 4, c0 = (tid & 15) * 8;
        float4 v0 = make_float4(0.f, 0.f, 0.f, 0.f), v1 = v0;
        if (m0 + r < M) {
            v0 = *(const float4*)(A + (size_t)(m0 + r) * 128 + c0);
            v1 = *(const float4*)(A + (size_t)(m0 + r) * 128 + c0 + 4);
        }
        *(ushort4*)&As[r][c0] = make_ushort4(f2u(v0.x), f2u(v0.y), f2u(v0.z), f2u(v0.w));
        *(ushort4*)&As[r][c0 + 4] = make_ushort4(f2u(v1.x), f2u(v1.y), f2u(v1.z), f2u(v1.w));
    }
    __syncthreads();

    int wv = tid >> 6, lane = tid & 63;
    floatx4 acc0 = {0.f, 0.f, 0.f, 0.f}, acc1 = acc0;
    int am = lane & 15, aq = lane >> 4;
    #pragma unroll
    for (int ks = 0; ks < 4; ++ks) {
        bf16x8 af = *(bf16x8*)&As[am][ks * 32 + aq * 8];
        const unsigned short* base = Wsw + ((size_t)ks * 8 + 2 * wv) * 512 + lane * 8;
        bf16x8 b0 = *(const bf16x8*)(base);
        bf16x8 b1 = *(const bf16x8*)(base + 512);
        acc0 = __builtin_amdgcn_mfma_f32_16x16x32_bf16(af, b0, acc0, 0, 0, 0);
        acc1 = __builtin_amdgcn_mfma_f32_16x16x32_bf16(af, b1, acc1, 0, 0, 0);
    }
    int col = lane & 15, rowb = (lane >> 4) * 4;
    #pragma unroll
    for (int t = 0; t < 2; ++t) {
        floatx4 acc = t ? acc1 : acc0;
        int n = wv * 32 + t * 16 + col;
        float bv = bias[n] * bscale;
        #pragma unroll
        for (int rg = 0; rg < 4; ++rg) {
            int m = m0 + rowb + rg;
            if (m < M) {
                float o = acc[rg] + bv;
                if (act) o = fmaxf(o, 0.f);
                C[(size_t)m * 128 + n] = f2u(o);
            }
        }
    }
}

// ---------------------------------------------------------------------------
// Fused: x1 = LN( A16@W + bias + resid ) * g + bt. A bf16, resid/out fp32.
__global__ void __launch_bounds__(256)
gemm_mfma_ln_kernel(const unsigned short* A, const unsigned short* Wsw, const float* bias,
                    const float* resid, const float* gam, const float* bet,
                    float* C) {
    int m0 = blockIdx.x * 16;
    __shared__ unsigned short As[16][136];
    __shared__ float redS[4][4][4], redQ[4][4][4];
    __shared__ float smean[16], sinv[16];
    int tid = threadIdx.x;
    {
        int r = tid >> 4, c0 = (tid & 15) * 8;
        ushortx8 v = *(const ushortx8*)(A + (size_t)(m0 + r) * 128 + c0);
        *(ushortx8*)&As[r][c0] = v;
    }
    __syncthreads();

    int wv = tid >> 6, lane = tid & 63;
    floatx4 acc0 = {0.f, 0.f, 0.f, 0.f}, acc1 = acc0;
    int am = lane & 15, aq = lane >> 4;
    #pragma unroll
    for (int ks = 0; ks < 4; ++ks) {
        bf16x8 af = *(bf16x8*)&As[am][ks * 32 + aq * 8];
        const unsigned short* base = Wsw + ((size_t)ks * 8 + 2 * wv) * 512 + lane * 8;
        bf16x8 b0 = *(const bf16x8*)(base);
        bf16x8 b1 = *(const bf16x8*)(base + 512);
        acc0 = __builtin_amdgcn_mfma_f32_16x16x32_bf16(af, b0, acc0, 0, 0, 0);
        acc1 = __builtin_amdgcn_mfma_f32_16x16x32_bf16(af, b1, acc1, 0, 0, 0);
    }

    int col = lane & 15, g = lane >> 4, rowb = g * 4;
    float ov[2][4];
    #pragma unroll
    for (int t = 0; t < 2; ++t) {
        int n = wv * 32 + t * 16 + col;
        float bv = bias[n];
        floatx4 acc = t ? acc1 : acc0;
        #pragma unroll
        for (int rg = 0; rg < 4; ++rg)
            ov[t][rg] = acc[rg] + bv + resid[(size_t)(m0 + rowb + rg) * 128 + n];
    }
    #pragma unroll
    for (int rg = 0; rg < 4; ++rg) {
        float s = ov[0][rg] + ov[1][rg];
        float q = ov[0][rg] * ov[0][rg] + ov[1][rg] * ov[1][rg];
        #pragma unroll
        for (int off = 8; off >= 1; off >>= 1) {
            s += __shfl_xor(s, off);
            q += __shfl_xor(q, off);
        }
        if ((lane & 15) == 0) { redS[wv][g][rg] = s; redQ[wv][g][rg] = q; }
    }
    __syncthreads();
    if (tid < 16) {
        int gg = tid >> 2, rg = tid & 3;
        float s = redS[0][gg][rg] + redS[1][gg][rg] + redS[2][gg][rg] + redS[3][gg][rg];
        float q = redQ[0][gg][rg] + redQ[1][gg][rg] + redQ[2][gg][rg] + redQ[3][gg][rg];
        float mean = s * 0.0078125f;
        float var = q * 0.0078125f - mean * mean;
        smean[tid] = mean;
        sinv[tid] = rsqrtf(var + 1e-5f);
    }
    __syncthreads();
    #pragma unroll
    for (int t = 0; t < 2; ++t) {
        int n = wv * 32 + t * 16 + col;
        float gm = gam[n], bb = bet[n];
        #pragma unroll
        for (int rg = 0; rg < 4; ++rg) {
            int row = rowb + rg;
            C[(size_t)(m0 + row) * 128 + n] = (ov[t][rg] - smean[row]) * sinv[row] * gm + bb;
        }
    }
}

// ---------------------------------------------------------------------------
// Fused FFN: x2 = LN( relu(x1@W1+b1)@W2 + b2 + x1 ) * g + bt. x1 fp32.
__global__ void __launch_bounds__(256)
ffn_ln_kernel(const float* x1, const unsigned short* W1, const float* b1,
              const unsigned short* W2, const float* b2,
              const float* gam, const float* bet, float* C) {
    int m0 = blockIdx.x * 16;
    __shared__ float Xs[16][128];
    __shared__ unsigned short As[16][136];
    __shared__ unsigned short Hs[16][136];
    __shared__ float redS[4][4][4], redQ[4][4][4];
    __shared__ float smean[16], sinv[16];
    int tid = threadIdx.x;
    {
        int r = tid >> 4, c0 = (tid & 15) * 8;
        float4 v0 = *(const float4*)(x1 + (size_t)(m0 + r) * 128 + c0);
        float4 v1 = *(const float4*)(x1 + (size_t)(m0 + r) * 128 + c0 + 4);
        *(float4*)&Xs[r][c0] = v0;
        *(float4*)&Xs[r][c0 + 4] = v1;
        *(ushort4*)&As[r][c0] = make_ushort4(f2u(v0.x), f2u(v0.y), f2u(v0.z), f2u(v0.w));
        *(ushort4*)&As[r][c0 + 4] = make_ushort4(f2u(v1.x), f2u(v1.y), f2u(v1.z), f2u(v1.w));
    }
    __syncthreads();

    int wv = tid >> 6, lane = tid & 63;
    int am = lane & 15, aq = lane >> 4;
    int col = lane & 15, g = lane >> 4, rowb = g * 4;

    {
        floatx4 acc0 = {0.f, 0.f, 0.f, 0.f}, acc1 = acc0;
        #pragma unroll
        for (int ks = 0; ks < 4; ++ks) {
            bf16x8 af = *(bf16x8*)&As[am][ks * 32 + aq * 8];
            const unsigned short* base = W1 + ((size_t)ks * 8 + 2 * wv) * 512 + lane * 8;
            bf16x8 bb0 = *(const bf16x8*)(base);
            bf16x8 bb1 = *(const bf16x8*)(base + 512);
            acc0 = __builtin_amdgcn_mfma_f32_16x16x32_bf16(af, bb0, acc0, 0, 0, 0);
            acc1 = __builtin_amdgcn_mfma_f32_16x16x32_bf16(af, bb1, acc1, 0, 0, 0);
        }
        #pragma unroll
        for (int t = 0; t < 2; ++t) {
            int n = wv * 32 + t * 16 + col;
            float bv = b1[n];
            floatx4 acc = t ? acc1 : acc0;
            #pragma unroll
            for (int rg = 0; rg < 4; ++rg)
                Hs[rowb + rg][n] = f2u(fmaxf(acc[rg] + bv, 0.f));
        }
    }
    __syncthreads();

    floatx4 acc0 = {0.f, 0.f, 0.f, 0.f}, acc1 = acc0;
    #pragma unroll
    for (int ks = 0; ks < 4; ++ks) {
        bf16x8 af = *(bf16x8*)&Hs[am][ks * 32 + aq * 8];
        const unsigned short* base = W2 + ((size_t)ks * 8 + 2 * wv) * 512 + lane * 8;
        bf16x8 bb0 = *(const bf16x8*)(base);
        bf16x8 bb1 = *(const bf16x8*)(base + 512);
        acc0 = __builtin_amdgcn_mfma_f32_16x16x32_bf16(af, bb0, acc0, 0, 0, 0);
        acc1 = __builtin_amdgcn_mfma_f32_16x16x32_bf16(af, bb1, acc1, 0, 0, 0);
    }
    float ov[2][4];
    #pragma unroll
    for (int t = 0; t < 2; ++t) {
        int n = wv * 32 + t * 16 + col;
        float bv = b2[n];
        floatx4 acc = t ? acc1 : acc0;
        #pragma unroll
        for (int rg = 0; rg < 4; ++rg)
            ov[t][rg] = acc[rg] + bv + Xs[rowb + rg][n];
    }
    #pragma unroll
    for (int rg = 0; rg < 4; ++rg) {
        float s = ov[0][rg] + ov[1][rg];
        float q = ov[0][rg] * ov[0][rg] + ov[1][rg] * ov[1][rg];
        #pragma unroll
        for (int off = 8; off >= 1; off >>= 1) {
            s += __shfl_xor(s, off);
            q += __shfl_xor(q, off);
        }
        if ((lane & 15) == 0) { redS[wv][g][rg] = s; redQ[wv][g][rg] = q; }
    }
    __syncthreads();
    if (tid < 16) {
        int gg = tid >> 2, rg = tid & 3;
        float s = redS[0][gg][rg] + redS[1][gg][rg] + redS[2][gg][rg] + redS[3][gg][rg];
        float q = redQ[0][gg][rg] + redQ[1][gg][rg] + redQ[2][gg][rg] + redQ[3][gg][rg];
        float mean = s * 0.0078125f;
        float var = q * 0.0078125f - mean * mean;
        smean[tid] = mean;
        sinv[tid] = rsqrtf(var + 1e-5f);
    }
    __syncthreads();
    #pragma unroll
    for (int t = 0; t < 2; ++t) {
        int n = wv * 32 + t * 16 + col;
        float gm = gam[n], bb = bet[n];
        #pragma unroll
        for (int rg = 0; rg < 4; ++rg) {
            int row = rowb + rg;
            C[(size_t)(m0 + row) * 128 + n] = (ov[t][rg] - smean[row]) * sinv[row] * gm + bb;
        }
    }
}

// ---------------------------------------------------------------------------
// Fused mta-out projection (K=32) + assemble into xin (row remap + pos).
__global__ void mta_out_assemble_kernel(const float* att, const float* W, const float* bias,
                                        const float* cls_emb, const float* pos, float* xin) {
    int tid = threadIdx.x;
    if (blockIdx.x == 320) {
        for (int e = tid; e < 16 * 128; e += 256) {
            int i = e >> 7, j = e & 127;
            int b = i >> 1;
            if ((i & 1) == 0) xin[(size_t)(b * 513) * 128 + j] = cls_emb[j] + pos[j];
            else              xin[(size_t)(4104 + b * 129) * 128 + j] = cls_emb[j];
        }
        return;
    }
    int m0 = blockIdx.x * 16;
    __shared__ float As[16][36];
    int r = tid >> 4, gq = tid & 15, c0 = gq * 8;
    if (gq < 2) {
        const float* src = att + (size_t)(m0 + r) * 32 + gq * 16;
        *(float4*)&As[r][gq * 16]      = *(const float4*)(src);
        *(float4*)&As[r][gq * 16 + 4]  = *(const float4*)(src + 4);
        *(float4*)&As[r][gq * 16 + 8]  = *(const float4*)(src + 8);
        *(float4*)&As[r][gq * 16 + 12] = *(const float4*)(src + 12);
    }
    __syncthreads();
    float acc[8];
    #pragma unroll
    for (int j = 0; j < 8; ++j) acc[j] = bias[c0 + j];
    #pragma unroll 8
    for (int k = 0; k < 32; ++k) {
        float a = As[r][k];
        const float4 w0 = *(const float4*)(W + (size_t)k * 128 + c0);
        const float4 w1 = *(const float4*)(W + (size_t)k * 128 + c0 + 4);
        acc[0] = fmaf(a, w0.x, acc[0]); acc[1] = fmaf(a, w0.y, acc[1]);
        acc[2] = fmaf(a, w0.z, acc[2]); acc[3] = fmaf(a, w0.w, acc[3]);
        acc[4] = fmaf(a, w1.x, acc[4]); acc[5] = fmaf(a, w1.y, acc[5]);
        acc[6] = fmaf(a, w1.z, acc[6]); acc[7] = fmaf(a, w1.w, acc[7]);
    }
    int m = m0 + r;
    size_t dstrow;
    if (m < 1024) {
        int b = m >> 7, rr = m & 127;
        dstrow = (size_t)(4104 + b * 129 + 1 + rr);
    } else {
        int mm = m - 1024;
        int b = mm >> 9, rr = mm & 511;
        dstrow = (size_t)(b * 513 + 1 + rr);
        const float* pr = pos + (size_t)(1 + rr) * 128 + c0;
        float4 p0 = *(const float4*)(pr);
        float4 p1 = *(const float4*)(pr + 4);
        acc[0] += p0.x; acc[1] += p0.y; acc[2] += p0.z; acc[3] += p0.w;
        acc[4] += p1.x; acc[5] += p1.y; acc[6] += p1.z; acc[7] += p1.w;
    }
    *(float4*)(xin + dstrow * 128 + c0) = make_float4(acc[0], acc[1], acc[2], acc[3]);
    *(float4*)(xin + dstrow * 128 + c0 + 4) = make_float4(acc[4], acc[5], acc[6], acc[7]);
}

// ---------------------------------------------------------------------------
// mta attention: bf16 q/k inputs (scale pre-folded into Wq), MFMA QK^T,
// scalar masked-sum pass (x fp32).
__global__ void __launch_bounds__(256)
mta_att_kernel(const unsigned short* qp_cls, const unsigned short* qp_main,
               const unsigned short* kp, const float* x,
               float* att_cls, float* att_mn) {
    int is_cls = (blockIdx.x >= 32);
    int qt = is_cls ? (blockIdx.x - 32) : blockIdx.x;
    int h = blockIdx.y, b = blockIdx.z;
    int tid = threadIdx.x, lane = tid & 63, wv = tid >> 6;
    __shared__ unsigned short Qs[16][72];
    __shared__ unsigned short KV[64][72];    // reused as xv fp32[64*17]
    __shared__ unsigned short sp[16][520];
    float* xv = (float*)&KV[0][0];
    int q0 = qt * 16;

    if (tid < 128) {   // stage Q (pure copy)
        int r = tid >> 3, c0 = (tid & 7) * 8;
        const unsigned short* qrow = is_cls ? (qp_cls + (size_t)(q0 + r) * 128 + h * 64)
                                            : (qp_main + (size_t)(b * 512 + q0 + r) * 128 + h * 64);
        *(ushortx8*)&Qs[r][c0] = *(const ushortx8*)(qrow + c0);
    }
    __syncthreads();

    bf16x8 qf0, qf1;
    {
        int m = lane & 15, g = lane >> 4;
        qf0 = *(const bf16x8*)&Qs[m][g * 8];
        qf1 = *(const bf16x8*)&Qs[m][32 + g * 8];
    }

    for (int kt = 0; kt < 8; ++kt) {
        int k0 = kt * 64;
        {   // stage K (pure copy, b128)
            int kk = tid >> 3, e0 = (tid & 7) * 8;
            #pragma unroll
            for (int it = 0; it < 2; ++it, kk += 32)
                *(ushortx8*)&KV[kk][e0] =
                    *(const ushortx8*)(kp + (size_t)(b * 512 + k0 + kk) * 128 + h * 64 + e0);
        }
        __syncthreads();
        int kn = lane & 15, g = lane >> 4;
        floatx4 acc = {0.f, 0.f, 0.f, 0.f};
        {
            bf16x8 b0 = *(const bf16x8*)&KV[wv * 16 + kn][g * 8];
            acc = __builtin_amdgcn_mfma_f32_16x16x32_bf16(qf0, b0, acc, 0, 0, 0);
            bf16x8 b1 = *(const bf16x8*)&KV[wv * 16 + kn][32 + g * 8];
            acc = __builtin_amdgcn_mfma_f32_16x16x32_bf16(qf1, b1, acc, 0, 0, 0);
        }
        int colk = k0 + wv * 16 + kn;
        #pragma unroll
        for (int rg = 0; rg < 4; ++rg) sp[g * 4 + rg][colk] = f2u(acc[rg]);
        __syncthreads();
    }

    for (int rr = wv; rr < 16; rr += 4) {
        float m = -1e30f;
        for (int k = lane; k < 512; k += 64) m = fmaxf(m, u2f(sp[rr][k]));
        m = wave_reduce_max(m);
        for (int k = lane; k < 512; k += 64) sp[rr][k] = f2u(expf(u2f(sp[rr][k]) - m));
    }

    int d = lane >> 3, sub = lane & 7;
    int qb = wv * 4;
    float num[4] = {0.f, 0.f, 0.f, 0.f}, den[4] = {0.f, 0.f, 0.f, 0.f};
    for (int kt = 0; kt < 8; ++kt) {
        int k0 = kt * 64;
        __syncthreads();
        {
            int kk = tid >> 2, c0 = (tid & 3) * 4;
            float4 v = *(const float4*)(x + (size_t)(b * 512 + k0 + kk) * 16 + c0);
            xv[kk * 17 + c0] = v.x; xv[kk * 17 + c0 + 1] = v.y;
            xv[kk * 17 + c0 + 2] = v.z; xv[kk * 17 + c0 + 3] = v.w;
        }
        __syncthreads();
        #pragma unroll
        for (int i = 0; i < 8; ++i) {
            int kk = sub + 8 * i;
            float mk = xv[kk * 17 + 8 + d];
            float vv = xv[kk * 17 + d];
            #pragma unroll
            for (int q = 0; q < 4; ++q) {
                float em = u2f(sp[qb + q][k0 + kk]) * mk;
                den[q] += em;
                num[q] = fmaf(em, vv, num[q]);
            }
        }
    }
    #pragma unroll
    for (int q = 0; q < 4; ++q) {
        #pragma unroll
        for (int off2 = 4; off2 >= 1; off2 >>= 1) {
            num[q] += __shfl_xor(num[q], off2);
            den[q] += __shfl_xor(den[q], off2);
        }
        if (sub == 0) {
            int row = q0 + qb + q;
            float* dst = is_cls ? (att_cls + (size_t)(b * 128 + row) * 32)
                                : (att_mn + (size_t)(b * 512 + row) * 32);
            dst[h * 16 + d] = num[q] / den[q];
            dst[h * 16 + 8 + d] = 1.0f;
        }
    }
}

// ---------------------------------------------------------------------------
// tblock attention: bf16 q/k/v in, bf16 out; MFMA QK^T + PV.
__global__ void __launch_bounds__(256)
tb_att_kernel(const unsigned short* qp, const unsigned short* kp,
              const unsigned short* vp, unsigned short* outp) {
    int is_cls = (blockIdx.x >= 33);
    int qt = is_cls ? blockIdx.x - 33 : blockIdx.x;
    int h = blockIdx.y, b = blockIdx.z;
    int Lq = is_cls ? 129 : 513;
    int base = is_cls ? (4104 + b * 129) : (b * 513);
    int nkt = is_cls ? 3 : 9;
    int tid = threadIdx.x, lane = tid & 63, wv = tid >> 6;
    __shared__ unsigned short Qs[16][72];
    __shared__ unsigned short KV[64][72];
    __shared__ unsigned short sp[16][588];
    __shared__ float rinv[16];
    int q0 = qt * 16;

    if (tid < 128) {   // stage Q (pure copy)
        int r = tid >> 3, c0 = (tid & 7) * 8;
        int qr = q0 + r;
        ushortx8 v = {0, 0, 0, 0, 0, 0, 0, 0};
        if (qr < Lq) v = *(const ushortx8*)(qp + (size_t)(base + qr) * 128 + h * 64 + c0);
        *(ushortx8*)&Qs[r][c0] = v;
    }
    __syncthreads();

    bf16x8 qf0, qf1;
    {
        int m = lane & 15, g = lane >> 4;
        qf0 = *(const bf16x8*)&Qs[m][g * 8];
        qf1 = *(const bf16x8*)&Qs[m][32 + g * 8];
    }

    for (int kt = 0; kt < nkt; ++kt) {
        int k0 = kt * 64;
        {   // stage K (pure copy)
            int kk = tid >> 3, e0 = (tid & 7) * 8;
            #pragma unroll
            for (int it = 0; it < 2; ++it, kk += 32) {
                int krow = k0 + kk;
                ushortx8 v = {0, 0, 0, 0, 0, 0, 0, 0};
                if (krow < Lq) v = *(const ushortx8*)(kp + (size_t)(base + krow) * 128 + h * 64 + e0);
                *(ushortx8*)&KV[kk][e0] = v;
            }
        }
        __syncthreads();
        int kn = lane & 15, g = lane >> 4;
        floatx4 acc = {0.f, 0.f, 0.f, 0.f};
        {
            bf16x8 b0 = *(const bf16x8*)&KV[wv * 16 + kn][g * 8];
            acc = __builtin_amdgcn_mfma_f32_16x16x32_bf16(qf0, b0, acc, 0, 0, 0);
            bf16x8 b1 = *(const bf16x8*)&KV[wv * 16 + kn][32 + g * 8];
            acc = __builtin_amdgcn_mfma_f32_16x16x32_bf16(qf1, b1, acc, 0, 0, 0);
        }
        int colk = k0 + wv * 16 + kn;
        #pragma unroll
        for (int rg = 0; rg < 4; ++rg)
            sp[g * 4 + rg][colk] = f2u((colk < Lq) ? acc[rg] : -1e30f);
        __syncthreads();
    }

    int kend = nkt * 64;
    for (int rr = wv; rr < 16; rr += 4) {
        float m = -1e30f;
        for (int k = lane; k < kend; k += 64) m = fmaxf(m, u2f(sp[rr][k]));
        m = wave_reduce_max(m);
        float sum = 0.f;
        for (int k = lane; k < kend; k += 64) {
            float e = expf(u2f(sp[rr][k]) - m);
            sp[rr][k] = f2u(e);
            sum += e;
        }
        sum = wave_reduce_sum(sum);
        if (lane == 0) rinv[rr] = 1.f / sum;
    }

    // pass C: PV via MFMA; V transposed (Vt[d][k]) staged by ushort scatter
    floatx4 oacc = {0.f, 0.f, 0.f, 0.f};
    for (int kt = 0; kt < nkt; ++kt) {
        int k0 = kt * 64;
        __syncthreads();
        {
            int kk = tid & 31, e0 = (tid >> 5) * 8;
            #pragma unroll
            for (int it = 0; it < 2; ++it, kk += 32) {
                int krow = k0 + kk;
                ushortx8 v = {0, 0, 0, 0, 0, 0, 0, 0};
                if (krow < Lq) v = *(const ushortx8*)(vp + (size_t)(base + krow) * 128 + h * 64 + e0);
                #pragma unroll
                for (int j = 0; j < 8; ++j) KV[e0 + j][kk] = v[j];
            }
        }
        __syncthreads();
        int dn = lane & 15, g = lane >> 4;
        #pragma unroll
        for (int c = 0; c < 2; ++c) {
            bf16x4 plo = *(const bf16x4*)&sp[lane & 15][k0 + c * 32 + g * 8];
            bf16x4 phi = *(const bf16x4*)&sp[lane & 15][k0 + c * 32 + g * 8 + 4];
            bf16x8 vf = *(const bf16x8*)&KV[wv * 16 + dn][c * 32 + g * 8];
            oacc = __builtin_amdgcn_mfma_f32_16x16x32_bf16(join8(plo, phi), vf, oacc, 0, 0, 0);
        }
    }
    int dcol = wv * 16 + (lane & 15), g = lane >> 4;
    #pragma unroll
    for (int rg = 0; rg < 4; ++rg) {
        int q = g * 4 + rg;
        int qr = q0 + q;
        if (qr < Lq)
            outp[(size_t)(base + qr) * 128 + h * 64 + dcol] = f2u(oacc[rg] * rinv[q]);
    }
}

// ---------------------------------------------------------------------------
// Legacy VALU GEMM (pooling only).
__global__ void pool_gemm_kernel(const float* A, int lda, const float* W, const float* bias,
                                 float* C) {
    __shared__ float As[8][132];
    int tid = threadIdx.x;
    int r = tid >> 5, g = tid & 31;   // 8 rows, 32 col-groups of 4
    for (int c = g; c < 128; c += 32) As[r][c] = A[(size_t)r * lda + c];
    __syncthreads();
    int rr = tid >> 5, c0 = (tid & 31) * 4;
    float acc[4];
    #pragma unroll
    for (int j = 0; j < 4; ++j) acc[j] = bias[c0 + j];
    for (int k = 0; k < 128; ++k) {
        float a = As[rr][k];
        const float4 w0 = *(const float4*)(W + (size_t)k * 128 + c0);
        acc[0] = fmaf(a, w0.x, acc[0]); acc[1] = fmaf(a, w0.y, acc[1]);
        acc[2] = fmaf(a, w0.z, acc[2]); acc[3] = fmaf(a, w0.w, acc[3]);
    }
    *(float4*)(C + (size_t)rr * 128 + c0) = make_float4(acc[0], acc[1], acc[2], acc[3]);
}

// ---------------------------------------------------------------------------
__global__ void finalize_kernel(const float* clsraw, const float* h2, float* out, int total) {
    int idx = blockIdx.x * 256 + threadIdx.x;
    if (idx >= total) return;
    float v;
    if (idx < 1024) {
        v = tanhf(clsraw[idx]);
    } else {
        int t = idx - 1024;
        int b = t >> 16;
        int rem = t & 65535;
        int i = rem >> 7, j = rem & 127;
        v = h2[((size_t)(b * 513 + 1 + i)) * 128 + j];
    }
    out[idx] = v;
}

// ---------------------------------------------------------------------------
extern "C" void kernel_launch(void* const* d_in, const int* in_sizes, int n_in,
                              void* d_out, int out_size, void* d_ws, size_t ws_size,
                              hipStream_t stream) {
    float* w = (float*)d_ws;
    size_t off = 0;
    auto alloc = [&](size_t n) {
        float* p = w + off;
        off += (n + 3) & ~(size_t)3;
        return p;
    };
    auto allocU = [&](size_t n) { return (unsigned short*)alloc((n + 1) / 2); };

    PrepAll pa{};
    int nn = n_in < 32 ? n_in : 32;
    float* fin[32];
    for (int i = 0; i < nn; ++i) {
        pa.src[i] = d_in[i];
        pa.n[i] = in_sizes[i];
        fin[i] = alloc(in_sizes[i]);
        pa.dstoff[i] = (int)(fin[i] - w);
    }
    for (int i = nn; i < 32; ++i) { pa.src[i] = nullptr; pa.n[i] = 0; pa.dstoff[i] = 0; }

    const float* x       = fin[0];
    const float* bq_t    = fin[7];
    const float* bk_t    = fin[9];
    const float* Wo_t    = fin[10]; const float* bo_t = fin[11];
    const float* pos_emb = fin[12]; const float* cls_emb = fin[13];
    const float* tbq = fin[15]; const float* tbk = fin[17]; const float* tbv = fin[19];
    const float* tbo = fin[21];
    const float* ln1_g = fin[22]; const float* ln1_b = fin[23];
    const float* fb1 = fin[25]; const float* fb2 = fin[27];
    const float* ln2_g = fin[28]; const float* ln2_b = fin[29];
    const float* pW = fin[30]; const float* pb = fin[31];

    // swizzled bf16 weights (raw-source indices): Wk=8, Wq=6 (x0.125),
    // tWq=14 (x0.125), tWk=16, tWv=18, tWo=20, fW1=24, fW2=26
    const int widx[8] = {8, 6, 14, 16, 18, 20, 24, 26};
    unsigned short* wsw[8];
    for (int i = 0; i < 8; ++i) {
        wsw[i] = allocU(16384);
        pa.wsrc[i] = d_in[widx[i]];
        pa.wdst[i] = wsw[i];
        pa.wscale[i] = (i == 1 || i == 2) ? 0.125f : 1.0f;
    }
    pa.ts = d_in[1]; pa.w_per = d_in[2]; pa.b_per = d_in[3];
    pa.w_lin = d_in[4]; pa.b_lin = d_in[5];
    pa.det = (const unsigned short*)d_in[22];

    unsigned short* key_e16 = allocU(4224 * 128);
    unsigned short* cls_e16 = key_e16 + 4096 * 128;
    pa.key_e16 = key_e16;

    unsigned short* qp_main16 = allocU(4096 * 128);
    unsigned short* kp_main16 = allocU(4096 * 128);
    unsigned short* qp_cls16  = allocU(128 * 128);
    float* att_all = alloc(5120 * 32);
    float* att_cls = att_all;
    float* att_mn  = att_all + 1024 * 32;
    float* xin     = alloc((size_t)NT_ * 128);
    unsigned short* tbq16 = allocU((size_t)NT_ * 128);
    unsigned short* tbk16 = allocU((size_t)NT_ * 128);
    unsigned short* tbv16 = allocU((size_t)NT_ * 128);
    unsigned short* tba16 = allocU((size_t)NT_ * 128);
    float* tb_x1   = alloc((size_t)NT_ * 128);
    float* x2      = alloc((size_t)NT_ * 128);
    float* clsraw  = alloc(8 * 128);
    (void)ws_size;

    // 1: convert + weight swizzle + time embedding
    prep_all_kernel<<<10848, 256, 0, stream>>>(pa, w);

    // 2: mta projections (bf16 A, bf16 C; q scale folded)
    {
        GemmM p{};
        p.A[0] = key_e16; p.W[0] = wsw[0]; p.bias[0] = bk_t; p.C[0] = kp_main16;
        p.M[0] = 4096; p.act[0] = 0; p.abf[0] = 1; p.bscale[0] = 1.f;
        p.A[1] = key_e16; p.W[1] = wsw[1]; p.bias[1] = bq_t; p.C[1] = qp_main16;
        p.M[1] = 4096; p.act[1] = 0; p.abf[1] = 1; p.bscale[1] = 0.125f;
        p.A[2] = cls_e16; p.W[2] = wsw[1]; p.bias[2] = bq_t; p.C[2] = qp_cls16;
        p.M[2] = 128; p.act[2] = 0; p.abf[2] = 1; p.bscale[2] = 0.125f;
        gemm_mfma_kernel<<<dim3(256, 3), 256, 0, stream>>>(p);
    }

    // 3: mta attention
    mta_att_kernel<<<dim3(40, 2, 8), 256, 0, stream>>>(qp_cls16, qp_main16, kp_main16,
                                                       x, att_cls, att_mn);

    // 4: mta out-projection + assemble
    mta_out_assemble_kernel<<<321, 256, 0, stream>>>(att_all, Wo_t, bo_t, cls_emb, pos_emb, xin);

    // 5: QKV (fp32 A -> bf16 C; q scale folded into tWq)
    {
        GemmM p{};
        const unsigned short* Ws[3] = {wsw[2], wsw[3], wsw[4]};
        const float* bs[3] = {tbq, tbk, tbv};
        unsigned short* Cs[3] = {tbq16, tbk16, tbv16};
        float sc[3] = {0.125f, 1.f, 1.f};
        for (int y = 0; y < 3; ++y) {
            p.A[y] = xin; p.W[y] = Ws[y]; p.bias[y] = bs[y]; p.C[y] = Cs[y];
            p.M[y] = NT_; p.act[y] = 0; p.abf[y] = 0; p.bscale[y] = sc[y];
        }
        gemm_mfma_kernel<<<dim3((NT_ + 15) / 16, 3), 256, 0, stream>>>(p);
    }

    // 6: tblock attention (bf16 in/out)
    tb_att_kernel<<<dim3(42, 2, 8), 256, 0, stream>>>(tbq16, tbk16, tbv16, tba16);

    // 7: att-out + residual + LN1 -> x1
    gemm_mfma_ln_kernel<<<NT_ / 16, 256, 0, stream>>>(tba16, wsw[5], tbo, xin, ln1_g, ln1_b, tb_x1);

    // 8: FFN1+FFN2 + residual + LN2 -> x2
    ffn_ln_kernel<<<NT_ / 16, 256, 0, stream>>>(tb_x1, wsw[6], fb1, wsw[7], fb2, ln2_g, ln2_b, x2);

    // 9: cls pooling
    pool_gemm_kernel<<<1, 256, 0, stream>>>(x2 + (size_t)4104 * 128, 129 * 128, pW, pb, clsraw);

    // 10: outputs
    finalize_kernel<<<(out_size + 255) / 256, 256, 0, stream>>>(clsraw, x2, (float*)d_out, out_size);
}

// Round 13
// 197.272 us; speedup vs baseline: 4.4929x; 1.0264x over previous
//
#include <hip/hip_runtime.h>
#include <hip/hip_bf16.h>
#include <math.h>

// TimeBERT forward on MI355X. Inputs fp32 (runtime bf16 detector kept, inline).
// OUTPUT FP32: [cls_pooling (8,128) | last_hidden (8,512,128)].
//
// R13: (1) ffn_ln writes d_out directly (finalize removed; cls rows -> x2c);
// (2) pool+tanh merged; (3) mta masked-sum pass MFMA-ized (B=[m*v|m]);
// (4) prep_all skips conversions of raw-consumed inputs. 9 launches.

static constexpr int NM_ = 8 * 513;           // 4104 main rows
static constexpr int NC_ = 8 * 129;           // 1032 cls rows
static constexpr int NT_ = NM_ + NC_;         // 5136 total (= 321 * 16)

using bf = __hip_bfloat16;
typedef __attribute__((ext_vector_type(8))) short bf16x8;
typedef __attribute__((ext_vector_type(4))) short bf16x4;
typedef __attribute__((ext_vector_type(4))) float floatx4;
typedef __attribute__((ext_vector_type(8))) unsigned short ushortx8;

__device__ __forceinline__ float wave_reduce_sum(float v) {
    #pragma unroll
    for (int off = 32; off >= 1; off >>= 1) v += __shfl_xor(v, off);
    return v;
}
__device__ __forceinline__ float wave_reduce_max(float v) {
    #pragma unroll
    for (int off = 32; off >= 1; off >>= 1) v = fmaxf(v, __shfl_xor(v, off));
    return v;
}
__device__ __forceinline__ float u2f(unsigned short u) {
    return __uint_as_float(((unsigned)u) << 16);
}
__device__ __forceinline__ unsigned short f2u(float f) {   // RNE, finite
    unsigned u = __float_as_uint(f);
    return (unsigned short)((u + 0x7FFF + ((u >> 16) & 1)) >> 16);
}
__device__ __forceinline__ bf16x8 join8(bf16x4 lo, bf16x4 hi) {
    return __builtin_shufflevector(lo, hi, 0, 1, 2, 3, 4, 5, 6, 7);
}
__device__ __forceinline__ float rdin(const void* p, int i, int flag) {
    return flag ? u2f(((const unsigned short*)p)[i]) : ((const float*)p)[i];
}

// ---------------------------------------------------------------------------
// prep_all: blocks [0,8224) convert selected inputs -> fp32 ws; [8224,8736)
// swizzle 8 weight mats -> bf16 B-frag order (scaled); [8736,10848) time emb.
struct PrepAll {
    const void* src[32]; int n[32]; int dstoff[32]; int conv[32];
    const void* wsrc[8]; unsigned short* wdst[8]; float wscale[8];
    const void* ts; const void* w_per; const void* b_per;
    const void* w_lin; const void* b_lin;
    unsigned short* key_e16;        // 4224 rows x 128 (rows >=4096 = cls)
    const unsigned short* det;
};
__global__ void prep_all_kernel(PrepAll a, float* dst) {
    int flag = (a.det[0] == 0x3F80u) ? 1 : 0;
    int blk = blockIdx.x, tid = threadIdx.x;
    if (blk < 8224) {
        int which = blk / 257, bi = blk - which * 257;
        if (!a.conv[which]) return;
        int i = bi * 256 + tid;
        if (i < a.n[which]) dst[a.dstoff[which] + i] = rdin(a.src[which], i, flag);
    } else if (blk < 8736) {
        int p = blk - 8224;
        int m = p >> 6;
        int idx = (p & 63) * 256 + tid;     // 0..16383
        int c = idx >> 9;
        int l = (idx >> 3) & 63;
        int j = idx & 7;
        int k = (c >> 3) * 32 + (l >> 4) * 8 + j;
        int n = (c & 7) * 16 + (l & 15);
        a.wdst[m][idx] = f2u(rdin(a.wsrc[m], k * 128 + n, flag) * a.wscale[m]);
    } else {
        int p = blk - 8736;
        int row = p * 2 + (tid >> 7), j = tid & 127;
        float t = (row < 4096) ? rdin(a.ts, row, flag)
                               : (float)(row - 4096) * (1.0f / 127.0f);
        float v;
        if (j == 0) v = t * rdin(a.w_lin, 0, flag) + rdin(a.b_lin, 0, flag);
        else        v = sinf(t * rdin(a.w_per, j - 1, flag) + rdin(a.b_per, j - 1, flag));
        a.key_e16[row * 128 + j] = f2u(v);
    }
}

// ---------------------------------------------------------------------------
// MFMA GEMM: C16 = bf16( act(A@W + bias*bscale) ). A fp32 or bf16.
struct GemmM {
    const void* A[3]; const unsigned short* W[3]; const float* bias[3];
    unsigned short* C[3];
    int M[3]; int act[3]; int abf[3]; float bscale[3];
};
__global__ void __launch_bounds__(256)
gemm_mfma_kernel(GemmM p) {
    int y = blockIdx.y;
    const unsigned short* Wsw = p.W[y];
    const float* bias = p.bias[y];
    unsigned short* C = p.C[y];
    int M = p.M[y], act = p.act[y], abf = p.abf[y];
    float bscale = p.bscale[y];
    int m0 = blockIdx.x * 16;
    if (m0 >= M) return;
    __shared__ unsigned short As[16][136];
    int tid = threadIdx.x;
    if (abf) {
        const unsigned short* A = (const unsigned short*)p.A[y];
        int r = tid >> 4, c0 = (tid & 15) * 8;
        ushortx8 v = {0, 0, 0, 0, 0, 0, 0, 0};
        if (m0 + r < M) v = *(const ushortx8*)(A + (size_t)(m0 + r) * 128 + c0);
        *(ushortx8*)&As[r][c0] = v;
    } else {
        const float* A = (const float*)p.A[y];
        int r = tid >> 4, c0 = (tid & 15) * 8;
        float4 v0 = make_float4(0.f, 0.f, 0.f, 0.f), v1 = v0;
        if (m0 + r < M) {
            v0 = *(const float4*)(A + (size_t)(m0 + r) * 128 + c0);
            v1 = *(const float4*)(A + (size_t)(m0 + r) * 128 + c0 + 4);
        }
        *(ushort4*)&As[r][c0] = make_ushort4(f2u(v0.x), f2u(v0.y), f2u(v0.z), f2u(v0.w));
        *(ushort4*)&As[r][c0 + 4] = make_ushort4(f2u(v1.x), f2u(v1.y), f2u(v1.z), f2u(v1.w));
    }
    __syncthreads();

    int wv = tid >> 6, lane = tid & 63;
    floatx4 acc0 = {0.f, 0.f, 0.f, 0.f}, acc1 = acc0;
    int am = lane & 15, aq = lane >> 4;
    #pragma unroll
    for (int ks = 0; ks < 4; ++ks) {
        bf16x8 af = *(bf16x8*)&As[am][ks * 32 + aq * 8];
        const unsigned short* base = Wsw + ((size_t)ks * 8 + 2 * wv) * 512 + lane * 8;
        bf16x8 b0 = *(const bf16x8*)(base);
        bf16x8 b1 = *(const bf16x8*)(base + 512);
        acc0 = __builtin_amdgcn_mfma_f32_16x16x32_bf16(af, b0, acc0, 0, 0, 0);
        acc1 = __builtin_amdgcn_mfma_f32_16x16x32_bf16(af, b1, acc1, 0, 0, 0);
    }
    int col = lane & 15, rowb = (lane >> 4) * 4;
    #pragma unroll
    for (int t = 0; t < 2; ++t) {
        floatx4 acc = t ? acc1 : acc0;
        int n = wv * 32 + t * 16 + col;
        float bv = bias[n] * bscale;
        #pragma unroll
        for (int rg = 0; rg < 4; ++rg) {
            int m = m0 + rowb + rg;
            if (m < M) {
                float o = acc[rg] + bv;
                if (act) o = fmaxf(o, 0.f);
                C[(size_t)m * 128 + n] = f2u(o);
            }
        }
    }
}

// ---------------------------------------------------------------------------
// Fused: x1 = LN( A16@W + bias + resid ) * g + bt.
__global__ void __launch_bounds__(256)
gemm_mfma_ln_kernel(const unsigned short* A, const unsigned short* Wsw, const float* bias,
                    const float* resid, const float* gam, const float* bet,
                    float* C) {
    int m0 = blockIdx.x * 16;
    __shared__ unsigned short As[16][136];
    __shared__ float redS[4][4][4], redQ[4][4][4];
    __shared__ float smean[16], sinv[16];
    int tid = threadIdx.x;
    {
        int r = tid >> 4, c0 = (tid & 15) * 8;
        ushortx8 v = *(const ushortx8*)(A + (size_t)(m0 + r) * 128 + c0);
        *(ushortx8*)&As[r][c0] = v;
    }
    __syncthreads();

    int wv = tid >> 6, lane = tid & 63;
    floatx4 acc0 = {0.f, 0.f, 0.f, 0.f}, acc1 = acc0;
    int am = lane & 15, aq = lane >> 4;
    #pragma unroll
    for (int ks = 0; ks < 4; ++ks) {
        bf16x8 af = *(bf16x8*)&As[am][ks * 32 + aq * 8];
        const unsigned short* base = Wsw + ((size_t)ks * 8 + 2 * wv) * 512 + lane * 8;
        bf16x8 b0 = *(const bf16x8*)(base);
        bf16x8 b1 = *(const bf16x8*)(base + 512);
        acc0 = __builtin_amdgcn_mfma_f32_16x16x32_bf16(af, b0, acc0, 0, 0, 0);
        acc1 = __builtin_amdgcn_mfma_f32_16x16x32_bf16(af, b1, acc1, 0, 0, 0);
    }

    int col = lane & 15, g = lane >> 4, rowb = g * 4;
    float ov[2][4];
    #pragma unroll
    for (int t = 0; t < 2; ++t) {
        int n = wv * 32 + t * 16 + col;
        float bv = bias[n];
        floatx4 acc = t ? acc1 : acc0;
        #pragma unroll
        for (int rg = 0; rg < 4; ++rg)
            ov[t][rg] = acc[rg] + bv + resid[(size_t)(m0 + rowb + rg) * 128 + n];
    }
    #pragma unroll
    for (int rg = 0; rg < 4; ++rg) {
        float s = ov[0][rg] + ov[1][rg];
        float q = ov[0][rg] * ov[0][rg] + ov[1][rg] * ov[1][rg];
        #pragma unroll
        for (int off = 8; off >= 1; off >>= 1) {
            s += __shfl_xor(s, off);
            q += __shfl_xor(q, off);
        }
        if ((lane & 15) == 0) { redS[wv][g][rg] = s; redQ[wv][g][rg] = q; }
    }
    __syncthreads();
    if (tid < 16) {
        int gg = tid >> 2, rg = tid & 3;
        float s = redS[0][gg][rg] + redS[1][gg][rg] + redS[2][gg][rg] + redS[3][gg][rg];
        float q = redQ[0][gg][rg] + redQ[1][gg][rg] + redQ[2][gg][rg] + redQ[3][gg][rg];
        float mean = s * 0.0078125f;
        float var = q * 0.0078125f - mean * mean;
        smean[tid] = mean;
        sinv[tid] = rsqrtf(var + 1e-5f);
    }
    __syncthreads();
    #pragma unroll
    for (int t = 0; t < 2; ++t) {
        int n = wv * 32 + t * 16 + col;
        float gm = gam[n], bb = bet[n];
        #pragma unroll
        for (int rg = 0; rg < 4; ++rg) {
            int row = rowb + rg;
            C[(size_t)(m0 + row) * 128 + n] = (ov[t][rg] - smean[row]) * sinv[row] * gm + bb;
        }
    }
}

// ---------------------------------------------------------------------------
// Fused FFN + direct output: val = LN( relu(x1@W1+b1)@W2 + b2 + x1 )*g + bt.
// Main rows (m<4104, r>=1) -> d_out[1024 + b*65536 + (r-1)*128 + n];
// cls rows r==0 -> x2c[b*128+n]; all other rows discarded.
__global__ void __launch_bounds__(256)
ffn_ln_kernel(const float* x1, const unsigned short* W1, const float* b1,
              const unsigned short* W2, const float* b2,
              const float* gam, const float* bet, float* dout, float* x2c) {
    int m0 = blockIdx.x * 16;
    __shared__ float Xs[16][128];
    __shared__ unsigned short As[16][136];
    __shared__ unsigned short Hs[16][136];
    __shared__ float redS[4][4][4], redQ[4][4][4];
    __shared__ float smean[16], sinv[16];
    int tid = threadIdx.x;
    {
        int r = tid >> 4, c0 = (tid & 15) * 8;
        float4 v0 = *(const float4*)(x1 + (size_t)(m0 + r) * 128 + c0);
        float4 v1 = *(const float4*)(x1 + (size_t)(m0 + r) * 128 + c0 + 4);
        *(float4*)&Xs[r][c0] = v0;
        *(float4*)&Xs[r][c0 + 4] = v1;
        *(ushort4*)&As[r][c0] = make_ushort4(f2u(v0.x), f2u(v0.y), f2u(v0.z), f2u(v0.w));
        *(ushort4*)&As[r][c0 + 4] = make_ushort4(f2u(v1.x), f2u(v1.y), f2u(v1.z), f2u(v1.w));
    }
    __syncthreads();

    int wv = tid >> 6, lane = tid & 63;
    int am = lane & 15, aq = lane >> 4;
    int col = lane & 15, g = lane >> 4, rowb = g * 4;

    {
        floatx4 acc0 = {0.f, 0.f, 0.f, 0.f}, acc1 = acc0;
        #pragma unroll
        for (int ks = 0; ks < 4; ++ks) {
            bf16x8 af = *(bf16x8*)&As[am][ks * 32 + aq * 8];
            const unsigned short* base = W1 + ((size_t)ks * 8 + 2 * wv) * 512 + lane * 8;
            bf16x8 bb0 = *(const bf16x8*)(base);
            bf16x8 bb1 = *(const bf16x8*)(base + 512);
            acc0 = __builtin_amdgcn_mfma_f32_16x16x32_bf16(af, bb0, acc0, 0, 0, 0);
            acc1 = __builtin_amdgcn_mfma_f32_16x16x32_bf16(af, bb1, acc1, 0, 0, 0);
        }
        #pragma unroll
        for (int t = 0; t < 2; ++t) {
            int n = wv * 32 + t * 16 + col;
            float bv = b1[n];
            floatx4 acc = t ? acc1 : acc0;
            #pragma unroll
            for (int rg = 0; rg < 4; ++rg)
                Hs[rowb + rg][n] = f2u(fmaxf(acc[rg] + bv, 0.f));
        }
    }
    __syncthreads();

    floatx4 acc0 = {0.f, 0.f, 0.f, 0.f}, acc1 = acc0;
    #pragma unroll
    for (int ks = 0; ks < 4; ++ks) {
        bf16x8 af = *(bf16x8*)&Hs[am][ks * 32 + aq * 8];
        const unsigned short* base = W2 + ((size_t)ks * 8 + 2 * wv) * 512 + lane * 8;
        bf16x8 bb0 = *(const bf16x8*)(base);
        bf16x8 bb1 = *(const bf16x8*)(base + 512);
        acc0 = __builtin_amdgcn_mfma_f32_16x16x32_bf16(af, bb0, acc0, 0, 0, 0);
        acc1 = __builtin_amdgcn_mfma_f32_16x16x32_bf16(af, bb1, acc1, 0, 0, 0);
    }
    float ov[2][4];
    #pragma unroll
    for (int t = 0; t < 2; ++t) {
        int n = wv * 32 + t * 16 + col;
        float bv = b2[n];
        floatx4 acc = t ? acc1 : acc0;
        #pragma unroll
        for (int rg = 0; rg < 4; ++rg)
            ov[t][rg] = acc[rg] + bv + Xs[rowb + rg][n];
    }
    #pragma unroll
    for (int rg = 0; rg < 4; ++rg) {
        float s = ov[0][rg] + ov[1][rg];
        float q = ov[0][rg] * ov[0][rg] + ov[1][rg] * ov[1][rg];
        #pragma unroll
        for (int off = 8; off >= 1; off >>= 1) {
            s += __shfl_xor(s, off);
            q += __shfl_xor(q, off);
        }
        if ((lane & 15) == 0) { redS[wv][g][rg] = s; redQ[wv][g][rg] = q; }
    }
    __syncthreads();
    if (tid < 16) {
        int gg = tid >> 2, rg = tid & 3;
        float s = redS[0][gg][rg] + redS[1][gg][rg] + redS[2][gg][rg] + redS[3][gg][rg];
        float q = redQ[0][gg][rg] + redQ[1][gg][rg] + redQ[2][gg][rg] + redQ[3][gg][rg];
        float mean = s * 0.0078125f;
        float var = q * 0.0078125f - mean * mean;
        smean[tid] = mean;
        sinv[tid] = rsqrtf(var + 1e-5f);
    }
    __syncthreads();
    #pragma unroll
    for (int t = 0; t < 2; ++t) {
        int n = wv * 32 + t * 16 + col;
        float gm = gam[n], bb = bet[n];
        #pragma unroll
        for (int rg = 0; rg < 4; ++rg) {
            int row = rowb + rg;
            int m = m0 + row;
            float val = (ov[t][rg] - smean[row]) * sinv[row] * gm + bb;
            if (m < NM_) {
                int b = m / 513, r = m - b * 513;
                if (r >= 1)
                    dout[1024 + (size_t)b * 65536 + (size_t)(r - 1) * 128 + n] = val;
            } else {
                int mc = m - NM_;
                int b = mc / 129, r = mc - b * 129;
                if (r == 0) x2c[b * 128 + n] = val;
            }
        }
    }
}

// ---------------------------------------------------------------------------
// Fused mta-out projection (K=32) + assemble into xin (row remap + pos).
__global__ void mta_out_assemble_kernel(const float* att, const float* W, const float* bias,
                                        const float* cls_emb, const float* pos, float* xin) {
    int tid = threadIdx.x;
    if (blockIdx.x == 320) {
        for (int e = tid; e < 16 * 128; e += 256) {
            int i = e >> 7, j = e & 127;
            int b = i >> 1;
            if ((i & 1) == 0) xin[(size_t)(b * 513) * 128 + j] = cls_emb[j] + pos[j];
            else              xin[(size_t)(4104 + b * 129) * 128 + j] = cls_emb[j];
        }
        return;
    }
    int m0 = blockIdx.x * 16;
    __shared__ float As[16][36];
    int r = tid >> 4, gq = tid & 15, c0 = gq * 8;
    if (gq < 2) {
        const float* src = att + (size_t)(m0 + r) * 32 + gq * 16;
        *(float4*)&As[r][gq * 16]      = *(const float4*)(src);
        *(float4*)&As[r][gq * 16 + 4]  = *(const float4*)(src + 4);
        *(float4*)&As[r][gq * 16 + 8]  = *(const float4*)(src + 8);
        *(float4*)&As[r][gq * 16 + 12] = *(const float4*)(src + 12);
    }
    __syncthreads();
    float acc[8];
    #pragma unroll
    for (int j = 0; j < 8; ++j) acc[j] = bias[c0 + j];
    #pragma unroll 8
    for (int k = 0; k < 32; ++k) {
        float a = As[r][k];
        const float4 w0 = *(const float4*)(W + (size_t)k * 128 + c0);
        const float4 w1 = *(const float4*)(W + (size_t)k * 128 + c0 + 4);
        acc[0] = fmaf(a, w0.x, acc[0]); acc[1] = fmaf(a, w0.y, acc[1]);
        acc[2] = fmaf(a, w0.z, acc[2]); acc[3] = fmaf(a, w0.w, acc[3]);
        acc[4] = fmaf(a, w1.x, acc[4]); acc[5] = fmaf(a, w1.y, acc[5]);
        acc[6] = fmaf(a, w1.z, acc[6]); acc[7] = fmaf(a, w1.w, acc[7]);
    }
    int m = m0 + r;
    size_t dstrow;
    if (m < 1024) {
        int b = m >> 7, rr = m & 127;
        dstrow = (size_t)(4104 + b * 129 + 1 + rr);
    } else {
        int mm = m - 1024;
        int b = mm >> 9, rr = mm & 511;
        dstrow = (size_t)(b * 513 + 1 + rr);
        const float* pr = pos + (size_t)(1 + rr) * 128 + c0;
        float4 p0 = *(const float4*)(pr);
        float4 p1 = *(const float4*)(pr + 4);
        acc[0] += p0.x; acc[1] += p0.y; acc[2] += p0.z; acc[3] += p0.w;
        acc[4] += p1.x; acc[5] += p1.y; acc[6] += p1.z; acc[7] += p1.w;
    }
    *(float4*)(xin + dstrow * 128 + c0) = make_float4(acc[0], acc[1], acc[2], acc[3]);
    *(float4*)(xin + dstrow * 128 + c0 + 4) = make_float4(acc[4], acc[5], acc[6], acc[7]);
}

// ---------------------------------------------------------------------------
// mta attention, fully MFMA: QK^T scores + masked sums as P@[m*v | m].
__global__ void __launch_bounds__(256)
mta_att_kernel(const unsigned short* qp_cls, const unsigned short* qp_main,
               const unsigned short* kp, const float* x,
               float* att_cls, float* att_mn) {
    int is_cls = (blockIdx.x >= 32);
    int qt = is_cls ? (blockIdx.x - 32) : blockIdx.x;
    int h = blockIdx.y, b = blockIdx.z;
    int tid = threadIdx.x, lane = tid & 63, wv = tid >> 6;
    __shared__ unsigned short Qs[16][72];
    __shared__ unsigned short KV[64][72];    // K tiles; later xv fp32 + redC/Cfull
    __shared__ unsigned short sp[16][520];
    __shared__ unsigned short Bt[16][520];   // [col c][k] = c<8 ? m*v : m (bf16)
    float* xv = (float*)&KV[0][0];
    int q0 = qt * 16;

    if (tid < 128) {   // stage Q (pure copy; scale folded into Wq)
        int r = tid >> 3, c0 = (tid & 7) * 8;
        const unsigned short* qrow = is_cls ? (qp_cls + (size_t)(q0 + r) * 128 + h * 64)
                                            : (qp_main + (size_t)(b * 512 + q0 + r) * 128 + h * 64);
        *(ushortx8*)&Qs[r][c0] = *(const ushortx8*)(qrow + c0);
    }
    __syncthreads();

    bf16x8 qf0, qf1;
    {
        int m = lane & 15, g = lane >> 4;
        qf0 = *(const bf16x8*)&Qs[m][g * 8];
        qf1 = *(const bf16x8*)&Qs[m][32 + g * 8];
    }

    // pass A: MFMA scores
    for (int kt = 0; kt < 8; ++kt) {
        int k0 = kt * 64;
        {
            int kk = tid >> 3, e0 = (tid & 7) * 8;
            #pragma unroll
            for (int it = 0; it < 2; ++it, kk += 32)
                *(ushortx8*)&KV[kk][e0] =
                    *(const ushortx8*)(kp + (size_t)(b * 512 + k0 + kk) * 128 + h * 64 + e0);
        }
        __syncthreads();
        int kn = lane & 15, g = lane >> 4;
        floatx4 acc = {0.f, 0.f, 0.f, 0.f};
        {
            bf16x8 b0 = *(const bf16x8*)&KV[wv * 16 + kn][g * 8];
            acc = __builtin_amdgcn_mfma_f32_16x16x32_bf16(qf0, b0, acc, 0, 0, 0);
            bf16x8 b1 = *(const bf16x8*)&KV[wv * 16 + kn][32 + g * 8];
            acc = __builtin_amdgcn_mfma_f32_16x16x32_bf16(qf1, b1, acc, 0, 0, 0);
        }
        int colk = k0 + wv * 16 + kn;
        #pragma unroll
        for (int rg = 0; rg < 4; ++rg) sp[g * 4 + rg][colk] = f2u(acc[rg]);
        __syncthreads();
    }

    // pass B: global-max + exp in place (ratio-identical to ref)
    for (int rr = wv; rr < 16; rr += 4) {
        float m = -1e30f;
        for (int k = lane; k < 512; k += 64) m = fmaxf(m, u2f(sp[rr][k]));
        m = wave_reduce_max(m);
        for (int k = lane; k < 512; k += 64) sp[rr][k] = f2u(expf(u2f(sp[rr][k]) - m));
    }

    // build Bt over all 512 keys: col c<8 -> x[k][c]*x[k][8+c]; c>=8 -> x[k][c]
    for (int kt = 0; kt < 8; ++kt) {
        int k0 = kt * 64;
        __syncthreads();
        {
            int kk = tid >> 2, c0 = (tid & 3) * 4;
            float4 v = *(const float4*)(x + (size_t)(b * 512 + k0 + kk) * 16 + c0);
            xv[kk * 17 + c0] = v.x; xv[kk * 17 + c0 + 1] = v.y;
            xv[kk * 17 + c0 + 2] = v.z; xv[kk * 17 + c0 + 3] = v.w;
        }
        __syncthreads();
        {
            int c = tid & 15, k4 = (tid >> 4) * 4;
            #pragma unroll
            for (int i = 0; i < 4; ++i) {
                int k = k4 + i;
                float val = (c < 8) ? xv[k * 17 + c] * xv[k * 17 + 8 + c]
                                    : xv[k * 17 + c];
                Bt[c][k0 + k] = f2u(val);
            }
        }
    }
    __syncthreads();

    // masked sums via MFMA: wave wv handles chunks {wv, wv+4, wv+8, wv+12}
    floatx4 macc = {0.f, 0.f, 0.f, 0.f};
    {
        int mq = lane & 15, g = lane >> 4;
        #pragma unroll
        for (int cc = 0; cc < 4; ++cc) {
            int koff = (wv + cc * 4) * 32;
            bf16x8 af = *(const bf16x8*)&sp[mq][koff + g * 8];
            bf16x8 bfv = *(const bf16x8*)&Bt[mq][koff + g * 8];
            macc = __builtin_amdgcn_mfma_f32_16x16x32_bf16(af, bfv, macc, 0, 0, 0);
        }
    }
    // cross-wave reduce (overlay KV region: redC 4KB, Cfull 1KB after it)
    float* redC = (float*)&KV[0][0];
    float* Cfull = redC + 1024;
    #pragma unroll
    for (int rg = 0; rg < 4; ++rg) redC[(wv * 64 + lane) * 4 + rg] = macc[rg];
    __syncthreads();
    {
        int l = tid >> 2, rg = tid & 3;
        float s = redC[l * 4 + rg] + redC[(64 + l) * 4 + rg]
                + redC[(128 + l) * 4 + rg] + redC[(192 + l) * 4 + rg];
        int row = (l >> 4) * 4 + rg, c = l & 15;
        Cfull[row * 16 + c] = s;
    }
    __syncthreads();
    if (tid < 128) {
        int r = tid >> 3, c = tid & 7;
        float num = Cfull[r * 16 + c];
        float den = Cfull[r * 16 + 8 + c];
        int row = q0 + r;
        float* dst = is_cls ? (att_cls + (size_t)(b * 128 + row) * 32)
                            : (att_mn + (size_t)(b * 512 + row) * 32);
        dst[h * 16 + c] = num / den;
        dst[h * 16 + 8 + c] = 1.0f;
    }
}

// ---------------------------------------------------------------------------
// tblock attention (unchanged from R12): bf16 in/out, MFMA QK^T + PV.
__global__ void __launch_bounds__(256)
tb_att_kernel(const unsigned short* qp, const unsigned short* kp,
              const unsigned short* vp, unsigned short* outp) {
    int is_cls = (blockIdx.x >= 33);
    int qt = is_cls ? blockIdx.x - 33 : blockIdx.x;
    int h = blockIdx.y, b = blockIdx.z;
    int Lq = is_cls ? 129 : 513;
    int base = is_cls ? (4104 + b * 129) : (b * 513);
    int nkt = is_cls ? 3 : 9;
    int tid = threadIdx.x, lane = tid & 63, wv = tid >> 6;
    __shared__ unsigned short Qs[16][72];
    __shared__ unsigned short KV[64][72];
    __shared__ unsigned short sp[16][588];
    __shared__ float rinv[16];
    int q0 = qt * 16;

    if (tid < 128) {
        int r = tid >> 3, c0 = (tid & 7) * 8;
        int qr = q0 + r;
        ushortx8 v = {0, 0, 0, 0, 0, 0, 0, 0};
        if (qr < Lq) v = *(const ushortx8*)(qp + (size_t)(base + qr) * 128 + h * 64 + c0);
        *(ushortx8*)&Qs[r][c0] = v;
    }
    __syncthreads();

    bf16x8 qf0, qf1;
    {
        int m = lane & 15, g = lane >> 4;
        qf0 = *(const bf16x8*)&Qs[m][g * 8];
        qf1 = *(const bf16x8*)&Qs[m][32 + g * 8];
    }

    for (int kt = 0; kt < nkt; ++kt) {
        int k0 = kt * 64;
        {
            int kk = tid >> 3, e0 = (tid & 7) * 8;
            #pragma unroll
            for (int it = 0; it < 2; ++it, kk += 32) {
                int krow = k0 + kk;
                ushortx8 v = {0, 0, 0, 0, 0, 0, 0, 0};
                if (krow < Lq) v = *(const ushortx8*)(kp + (size_t)(base + krow) * 128 + h * 64 + e0);
                *(ushortx8*)&KV[kk][e0] = v;
            }
        }
        __syncthreads();
        int kn = lane & 15, g = lane >> 4;
        floatx4 acc = {0.f, 0.f, 0.f, 0.f};
        {
            bf16x8 b0 = *(const bf16x8*)&KV[wv * 16 + kn][g * 8];
            acc = __builtin_amdgcn_mfma_f32_16x16x32_bf16(qf0, b0, acc, 0, 0, 0);
            bf16x8 b1 = *(const bf16x8*)&KV[wv * 16 + kn][32 + g * 8];
            acc = __builtin_amdgcn_mfma_f32_16x16x32_bf16(qf1, b1, acc, 0, 0, 0);
        }
        int colk = k0 + wv * 16 + kn;
        #pragma unroll
        for (int rg = 0; rg < 4; ++rg)
            sp[g * 4 + rg][colk] = f2u((colk < Lq) ? acc[rg] : -1e30f);
        __syncthreads();
    }

    int kend = nkt * 64;
    for (int rr = wv; rr < 16; rr += 4) {
        float m = -1e30f;
        for (int k = lane; k < kend; k += 64) m = fmaxf(m, u2f(sp[rr][k]));
        m = wave_reduce_max(m);
        float sum = 0.f;
        for (int k = lane; k < kend; k += 64) {
            float e = expf(u2f(sp[rr][k]) - m);
            sp[rr][k] = f2u(e);
            sum += e;
        }
        sum = wave_reduce_sum(sum);
        if (lane == 0) rinv[rr] = 1.f / sum;
    }

    floatx4 oacc = {0.f, 0.f, 0.f, 0.f};
    for (int kt = 0; kt < nkt; ++kt) {
        int k0 = kt * 64;
        __syncthreads();
        {
            int kk = tid & 31, e0 = (tid >> 5) * 8;
            #pragma unroll
            for (int it = 0; it < 2; ++it, kk += 32) {
                int krow = k0 + kk;
                ushortx8 v = {0, 0, 0, 0, 0, 0, 0, 0};
                if (krow < Lq) v = *(const ushortx8*)(vp + (size_t)(base + krow) * 128 + h * 64 + e0);
                #pragma unroll
                for (int j = 0; j < 8; ++j) KV[e0 + j][kk] = v[j];
            }
        }
        __syncthreads();
        int dn = lane & 15, g = lane >> 4;
        #pragma unroll
        for (int c = 0; c < 2; ++c) {
            bf16x4 plo = *(const bf16x4*)&sp[lane & 15][k0 + c * 32 + g * 8];
            bf16x4 phi = *(const bf16x4*)&sp[lane & 15][k0 + c * 32 + g * 8 + 4];
            bf16x8 vf = *(const bf16x8*)&KV[wv * 16 + dn][c * 32 + g * 8];
            oacc = __builtin_amdgcn_mfma_f32_16x16x32_bf16(join8(plo, phi), vf, oacc, 0, 0, 0);
        }
    }
    int dcol = wv * 16 + (lane & 15), g = lane >> 4;
    #pragma unroll
    for (int rg = 0; rg < 4; ++rg) {
        int q = g * 4 + rg;
        int qr = q0 + q;
        if (qr < Lq)
            outp[(size_t)(base + qr) * 128 + h * 64 + dcol] = f2u(oacc[rg] * rinv[q]);
    }
}

// ---------------------------------------------------------------------------
// Pooling GEMM + tanh -> d_out[0:1024]. One block.
__global__ void pool_tanh_kernel(const float* x2c, const float* W, const float* bias,
                                 float* dout) {
    __shared__ float As[8][132];
    int tid = threadIdx.x;
    int r = tid >> 5, g = tid & 31;
    for (int c = g; c < 128; c += 32) As[r][c] = x2c[(size_t)r * 128 + c];
    __syncthreads();
    int rr = tid >> 5, c0 = (tid & 31) * 4;
    float acc[4];
    #pragma unroll
    for (int j = 0; j < 4; ++j) acc[j] = bias[c0 + j];
    for (int k = 0; k < 128; ++k) {
        float a = As[rr][k];
        const float4 w0 = *(const float4*)(W + (size_t)k * 128 + c0);
        acc[0] = fmaf(a, w0.x, acc[0]); acc[1] = fmaf(a, w0.y, acc[1]);
        acc[2] = fmaf(a, w0.z, acc[2]); acc[3] = fmaf(a, w0.w, acc[3]);
    }
    *(float4*)(dout + (size_t)rr * 128 + c0) =
        make_float4(tanhf(acc[0]), tanhf(acc[1]), tanhf(acc[2]), tanhf(acc[3]));
}

// ---------------------------------------------------------------------------
extern "C" void kernel_launch(void* const* d_in, const int* in_sizes, int n_in,
                              void* d_out, int out_size, void* d_ws, size_t ws_size,
                              hipStream_t stream) {
    float* w = (float*)d_ws;
    size_t off = 0;
    auto alloc = [&](size_t n) {
        float* p = w + off;
        off += (n + 3) & ~(size_t)3;
        return p;
    };
    auto allocU = [&](size_t n) { return (unsigned short*)alloc((n + 1) / 2); };

    PrepAll pa{};
    int nn = n_in < 32 ? n_in : 32;
    float* fin[32];
    // inputs needing fp32 conversion (others consumed raw or via swizzle)
    const int needconv[32] = {1,0,0,0,0,0, 0,1, 0,1, 1,1, 1,1, 0,1, 0,1, 0,1,
                              0,1, 1,1, 0,1, 0,1, 1,1, 1,1};
    for (int i = 0; i < nn; ++i) {
        pa.src[i] = d_in[i];
        pa.n[i] = in_sizes[i];
        fin[i] = alloc(in_sizes[i]);
        pa.dstoff[i] = (int)(fin[i] - w);
        pa.conv[i] = needconv[i];
    }
    for (int i = nn; i < 32; ++i) { pa.src[i] = nullptr; pa.n[i] = 0; pa.dstoff[i] = 0; pa.conv[i] = 0; }

    const float* x       = fin[0];
    const float* bq_t    = fin[7];
    const float* bk_t    = fin[9];
    const float* Wo_t    = fin[10]; const float* bo_t = fin[11];
    const float* pos_emb = fin[12]; const float* cls_emb = fin[13];
    const float* tbq = fin[15]; const float* tbk = fin[17]; const float* tbv = fin[19];
    const float* tbo = fin[21];
    const float* ln1_g = fin[22]; const float* ln1_b = fin[23];
    const float* fb1 = fin[25]; const float* fb2 = fin[27];
    const float* ln2_g = fin[28]; const float* ln2_b = fin[29];
    const float* pW = fin[30]; const float* pb = fin[31];

    const int widx[8] = {8, 6, 14, 16, 18, 20, 24, 26};
    unsigned short* wsw[8];
    for (int i = 0; i < 8; ++i) {
        wsw[i] = allocU(16384);
        pa.wsrc[i] = d_in[widx[i]];
        pa.wdst[i] = wsw[i];
        pa.wscale[i] = (i == 1 || i == 2) ? 0.125f : 1.0f;
    }
    pa.ts = d_in[1]; pa.w_per = d_in[2]; pa.b_per = d_in[3];
    pa.w_lin = d_in[4]; pa.b_lin = d_in[5];
    pa.det = (const unsigned short*)d_in[22];

    unsigned short* key_e16 = allocU(4224 * 128);
    unsigned short* cls_e16 = key_e16 + 4096 * 128;
    pa.key_e16 = key_e16;

    unsigned short* qp_main16 = allocU(4096 * 128);
    unsigned short* kp_main16 = allocU(4096 * 128);
    unsigned short* qp_cls16  = allocU(128 * 128);
    float* att_all = alloc(5120 * 32);
    float* att_cls = att_all;
    float* att_mn  = att_all + 1024 * 32;
    float* xin     = alloc((size_t)NT_ * 128);
    unsigned short* tbq16 = allocU((size_t)NT_ * 128);
    unsigned short* tbk16 = allocU((size_t)NT_ * 128);
    unsigned short* tbv16 = allocU((size_t)NT_ * 128);
    unsigned short* tba16 = allocU((size_t)NT_ * 128);
    float* tb_x1   = alloc((size_t)NT_ * 128);
    float* x2c     = alloc(8 * 128);
    (void)ws_size;

    float* outf = (float*)d_out;

    // 1: convert + weight swizzle + time embedding
    prep_all_kernel<<<10848, 256, 0, stream>>>(pa, w);

    // 2: mta projections
    {
        GemmM p{};
        p.A[0] = key_e16; p.W[0] = wsw[0]; p.bias[0] = bk_t; p.C[0] = kp_main16;
        p.M[0] = 4096; p.act[0] = 0; p.abf[0] = 1; p.bscale[0] = 1.f;
        p.A[1] = key_e16; p.W[1] = wsw[1]; p.bias[1] = bq_t; p.C[1] = qp_main16;
        p.M[1] = 4096; p.act[1] = 0; p.abf[1] = 1; p.bscale[1] = 0.125f;
        p.A[2] = cls_e16; p.W[2] = wsw[1]; p.bias[2] = bq_t; p.C[2] = qp_cls16;
        p.M[2] = 128; p.act[2] = 0; p.abf[2] = 1; p.bscale[2] = 0.125f;
        gemm_mfma_kernel<<<dim3(256, 3), 256, 0, stream>>>(p);
    }

    // 3: mta attention (full MFMA)
    mta_att_kernel<<<dim3(40, 2, 8), 256, 0, stream>>>(qp_cls16, qp_main16, kp_main16,
                                                       x, att_cls, att_mn);

    // 4: mta out-projection + assemble
    mta_out_assemble_kernel<<<321, 256, 0, stream>>>(att_all, Wo_t, bo_t, cls_emb, pos_emb, xin);

    // 5: QKV
    {
        GemmM p{};
        const unsigned short* Ws[3] = {wsw[2], wsw[3], wsw[4]};
        const float* bs[3] = {tbq, tbk, tbv};
        unsigned short* Cs[3] = {tbq16, tbk16, tbv16};
        float sc[3] = {0.125f, 1.f, 1.f};
        for (int y = 0; y < 3; ++y) {
            p.A[y] = xin; p.W[y] = Ws[y]; p.bias[y] = bs[y]; p.C[y] = Cs[y];
            p.M[y] = NT_; p.act[y] = 0; p.abf[y] = 0; p.bscale[y] = sc[y];
        }
        gemm_mfma_kernel<<<dim3((NT_ + 15) / 16, 3), 256, 0, stream>>>(p);
    }

    // 6: tblock attention
    tb_att_kernel<<<dim3(42, 2, 8), 256, 0, stream>>>(tbq16, tbk16, tbv16, tba16);

    // 7: att-out + residual + LN1 -> x1
    gemm_mfma_ln_kernel<<<NT_ / 16, 256, 0, stream>>>(tba16, wsw[5], tbo, xin, ln1_g, ln1_b, tb_x1);

    // 8: FFN + LN2 -> d_out (body) + x2c (cls rows)
    ffn_ln_kernel<<<NT_ / 16, 256, 0, stream>>>(tb_x1, wsw[6], fb1, wsw[7], fb2,
                                                ln2_g, ln2_b, outf, x2c);

    // 9: pooling + tanh -> d_out[0:1024]
    pool_tanh_kernel<<<1, 256, 0, stream>>>(x2c, pW, pb, outf);
}

// Round 14
// 189.131 us; speedup vs baseline: 4.6863x; 1.0430x over previous
//
#include <hip/hip_runtime.h>
#include <hip/hip_bf16.h>
#include <math.h>

// TimeBERT forward on MI355X. Inputs fp32 (runtime bf16 detector, inline).
// OUTPUT FP32: [cls_pooling (8,128) | last_hidden (8,512,128)].
//
// R14: tile-local stage merging. (A) mta-out+assemble+QKV in one kernel
// (xin tile built in-block via inverse row map); (B) attn-out+LN1+FFN+LN2+pool
// in one kernel (x1 through LDS, pooled cls rows in-block). 6 launches.

static constexpr int NM_ = 8 * 513;           // 4104 main rows
static constexpr int NC_ = 8 * 129;           // 1032 cls rows
static constexpr int NT_ = NM_ + NC_;         // 5136 total (= 321 * 16)

using bf = __hip_bfloat16;
typedef __attribute__((ext_vector_type(8))) short bf16x8;
typedef __attribute__((ext_vector_type(4))) short bf16x4;
typedef __attribute__((ext_vector_type(4))) float floatx4;
typedef __attribute__((ext_vector_type(8))) unsigned short ushortx8;

__device__ __forceinline__ float wave_reduce_sum(float v) {
    #pragma unroll
    for (int off = 32; off >= 1; off >>= 1) v += __shfl_xor(v, off);
    return v;
}
__device__ __forceinline__ float wave_reduce_max(float v) {
    #pragma unroll
    for (int off = 32; off >= 1; off >>= 1) v = fmaxf(v, __shfl_xor(v, off));
    return v;
}
__device__ __forceinline__ float u2f(unsigned short u) {
    return __uint_as_float(((unsigned)u) << 16);
}
__device__ __forceinline__ unsigned short f2u(float f) {   // RNE, finite
    unsigned u = __float_as_uint(f);
    return (unsigned short)((u + 0x7FFF + ((u >> 16) & 1)) >> 16);
}
__device__ __forceinline__ bf16x8 join8(bf16x4 lo, bf16x4 hi) {
    return __builtin_shufflevector(lo, hi, 0, 1, 2, 3, 4, 5, 6, 7);
}
__device__ __forceinline__ float rdin(const void* p, int i, int flag) {
    return flag ? u2f(((const unsigned short*)p)[i]) : ((const float*)p)[i];
}

// ---------------------------------------------------------------------------
// prep_all: [0,8224) convert selected inputs -> fp32; [8224,8736) weight
// swizzle -> bf16 B-frag (scaled); [8736,10848) time embedding -> bf16.
struct PrepAll {
    const void* src[32]; int n[32]; int dstoff[32]; int conv[32];
    const void* wsrc[8]; unsigned short* wdst[8]; float wscale[8];
    const void* ts; const void* w_per; const void* b_per;
    const void* w_lin; const void* b_lin;
    unsigned short* key_e16;
    const unsigned short* det;
};
__global__ void prep_all_kernel(PrepAll a, float* dst) {
    int flag = (a.det[0] == 0x3F80u) ? 1 : 0;
    int blk = blockIdx.x, tid = threadIdx.x;
    if (blk < 8224) {
        int which = blk / 257, bi = blk - which * 257;
        if (!a.conv[which]) return;
        int i = bi * 256 + tid;
        if (i < a.n[which]) dst[a.dstoff[which] + i] = rdin(a.src[which], i, flag);
    } else if (blk < 8736) {
        int p = blk - 8224;
        int m = p >> 6;
        int idx = (p & 63) * 256 + tid;
        int c = idx >> 9;
        int l = (idx >> 3) & 63;
        int j = idx & 7;
        int k = (c >> 3) * 32 + (l >> 4) * 8 + j;
        int n = (c & 7) * 16 + (l & 15);
        a.wdst[m][idx] = f2u(rdin(a.wsrc[m], k * 128 + n, flag) * a.wscale[m]);
    } else {
        int p = blk - 8736;
        int row = p * 2 + (tid >> 7), j = tid & 127;
        float t = (row < 4096) ? rdin(a.ts, row, flag)
                               : (float)(row - 4096) * (1.0f / 127.0f);
        float v;
        if (j == 0) v = t * rdin(a.w_lin, 0, flag) + rdin(a.b_lin, 0, flag);
        else        v = sinf(t * rdin(a.w_per, j - 1, flag) + rdin(a.b_per, j - 1, flag));
        a.key_e16[row * 128 + j] = f2u(v);
    }
}

// ---------------------------------------------------------------------------
// MFMA GEMM (projections): C16 = bf16(A16@W + bias*bscale).
struct GemmM {
    const void* A[3]; const unsigned short* W[3]; const float* bias[3];
    unsigned short* C[3];
    int M[3]; float bscale[3];
};
__global__ void __launch_bounds__(256)
gemm_mfma_kernel(GemmM p) {
    int y = blockIdx.y;
    const unsigned short* Wsw = p.W[y];
    const float* bias = p.bias[y];
    unsigned short* C = p.C[y];
    int M = p.M[y];
    float bscale = p.bscale[y];
    int m0 = blockIdx.x * 16;
    if (m0 >= M) return;
    __shared__ unsigned short As[16][136];
    int tid = threadIdx.x;
    {
        const unsigned short* A = (const unsigned short*)p.A[y];
        int r = tid >> 4, c0 = (tid & 15) * 8;
        ushortx8 v = {0, 0, 0, 0, 0, 0, 0, 0};
        if (m0 + r < M) v = *(const ushortx8*)(A + (size_t)(m0 + r) * 128 + c0);
        *(ushortx8*)&As[r][c0] = v;
    }
    __syncthreads();

    int wv = tid >> 6, lane = tid & 63;
    floatx4 acc0 = {0.f, 0.f, 0.f, 0.f}, acc1 = acc0;
    int am = lane & 15, aq = lane >> 4;
    #pragma unroll
    for (int ks = 0; ks < 4; ++ks) {
        bf16x8 af = *(bf16x8*)&As[am][ks * 32 + aq * 8];
        const unsigned short* base = Wsw + ((size_t)ks * 8 + 2 * wv) * 512 + lane * 8;
        bf16x8 b0 = *(const bf16x8*)(base);
        bf16x8 b1 = *(const bf16x8*)(base + 512);
        acc0 = __builtin_amdgcn_mfma_f32_16x16x32_bf16(af, b0, acc0, 0, 0, 0);
        acc1 = __builtin_amdgcn_mfma_f32_16x16x32_bf16(af, b1, acc1, 0, 0, 0);
    }
    int col = lane & 15, rowb = (lane >> 4) * 4;
    #pragma unroll
    for (int t = 0; t < 2; ++t) {
        floatx4 acc = t ? acc1 : acc0;
        int n = wv * 32 + t * 16 + col;
        float bv = bias[n] * bscale;
        #pragma unroll
        for (int rg = 0; rg < 4; ++rg) {
            int m = m0 + rowb + rg;
            if (m < M) C[(size_t)m * 128 + n] = f2u(acc[rg] + bv);
        }
    }
}

// ---------------------------------------------------------------------------
// Merged A: mta-out projection (K=32, inverse row map) + assemble + QKV MFMA.
// Grid 321 tiles over xin rows.
__global__ void __launch_bounds__(256)
mta_qkv_kernel(const float* att, const float* Wo, const float* bo,
               const float* cls_emb, const float* pos, float* xin,
               const unsigned short* Wq, const unsigned short* Wk, const unsigned short* Wv,
               const float* bq, const float* bk, const float* bv_,
               unsigned short* outq, unsigned short* outk, unsigned short* outv) {
    int m0 = blockIdx.x * 16;
    __shared__ float As32[16][36];
    __shared__ unsigned short As[16][136];
    int tid = threadIdx.x;
    int r = tid >> 4, g = tid & 15, c0 = g * 8;

    // inverse row map for R = m0 + r
    int R = m0 + r;
    int srow, prow;
    if (R < NM_) {
        int b = R / 513, rr = R - b * 513;
        srow = (rr == 0) ? -1 : 1024 + b * 512 + (rr - 1);
        prow = rr;
    } else {
        int mc = R - NM_;
        int b = mc / 129, rr = mc - b * 129;
        srow = (rr == 0) ? -1 : b * 128 + (rr - 1);
        prow = -1;
    }
    if (g < 2 && srow >= 0) {
        const float* src = att + (size_t)srow * 32 + g * 16;
        *(float4*)&As32[r][g * 16]      = *(const float4*)(src);
        *(float4*)&As32[r][g * 16 + 4]  = *(const float4*)(src + 4);
        *(float4*)&As32[r][g * 16 + 8]  = *(const float4*)(src + 8);
        *(float4*)&As32[r][g * 16 + 12] = *(const float4*)(src + 12);
    }
    __syncthreads();

    float acc[8];
    if (srow < 0) {
        #pragma unroll
        for (int j = 0; j < 8; ++j) acc[j] = cls_emb[c0 + j];
    } else {
        #pragma unroll
        for (int j = 0; j < 8; ++j) acc[j] = bo[c0 + j];
        #pragma unroll 8
        for (int k = 0; k < 32; ++k) {
            float a = As32[r][k];
            const float4 w0 = *(const float4*)(Wo + (size_t)k * 128 + c0);
            const float4 w1 = *(const float4*)(Wo + (size_t)k * 128 + c0 + 4);
            acc[0] = fmaf(a, w0.x, acc[0]); acc[1] = fmaf(a, w0.y, acc[1]);
            acc[2] = fmaf(a, w0.z, acc[2]); acc[3] = fmaf(a, w0.w, acc[3]);
            acc[4] = fmaf(a, w1.x, acc[4]); acc[5] = fmaf(a, w1.y, acc[5]);
            acc[6] = fmaf(a, w1.z, acc[6]); acc[7] = fmaf(a, w1.w, acc[7]);
        }
    }
    if (prow >= 0) {
        const float* pr = pos + (size_t)prow * 128 + c0;
        float4 p0 = *(const float4*)(pr);
        float4 p1 = *(const float4*)(pr + 4);
        acc[0] += p0.x; acc[1] += p0.y; acc[2] += p0.z; acc[3] += p0.w;
        acc[4] += p1.x; acc[5] += p1.y; acc[6] += p1.z; acc[7] += p1.w;
    }
    *(float4*)(xin + (size_t)R * 128 + c0) = make_float4(acc[0], acc[1], acc[2], acc[3]);
    *(float4*)(xin + (size_t)R * 128 + c0 + 4) = make_float4(acc[4], acc[5], acc[6], acc[7]);
    *(ushort4*)&As[r][c0] = make_ushort4(f2u(acc[0]), f2u(acc[1]), f2u(acc[2]), f2u(acc[3]));
    *(ushort4*)&As[r][c0 + 4] = make_ushort4(f2u(acc[4]), f2u(acc[5]), f2u(acc[6]), f2u(acc[7]));
    __syncthreads();

    // QKV MFMA (q: weights+bias pre-scaled by 0.125)
    int wv = tid >> 6, lane = tid & 63;
    int am = lane & 15, aq = lane >> 4;
    int col = lane & 15, rowb = (lane >> 4) * 4;
    const unsigned short* Ws[3] = {Wq, Wk, Wv};
    const float* bs[3] = {bq, bk, bv_};
    float bsc[3] = {0.125f, 1.f, 1.f};
    unsigned short* Cs[3] = {outq, outk, outv};
    #pragma unroll
    for (int y = 0; y < 3; ++y) {
        floatx4 acc0 = {0.f, 0.f, 0.f, 0.f}, acc1 = acc0;
        #pragma unroll
        for (int ks = 0; ks < 4; ++ks) {
            bf16x8 af = *(bf16x8*)&As[am][ks * 32 + aq * 8];
            const unsigned short* base = Ws[y] + ((size_t)ks * 8 + 2 * wv) * 512 + lane * 8;
            bf16x8 b0 = *(const bf16x8*)(base);
            bf16x8 b1 = *(const bf16x8*)(base + 512);
            acc0 = __builtin_amdgcn_mfma_f32_16x16x32_bf16(af, b0, acc0, 0, 0, 0);
            acc1 = __builtin_amdgcn_mfma_f32_16x16x32_bf16(af, b1, acc1, 0, 0, 0);
        }
        #pragma unroll
        for (int t = 0; t < 2; ++t) {
            floatx4 a2 = t ? acc1 : acc0;
            int n = wv * 32 + t * 16 + col;
            float bvv = bs[y][n] * bsc[y];
            #pragma unroll
            for (int rg = 0; rg < 4; ++rg)
                Cs[y][(size_t)(m0 + rowb + rg) * 128 + n] = f2u(a2[rg] + bvv);
        }
    }
}

// ---------------------------------------------------------------------------
// Merged B: attn-out MFMA + resid + LN1 -> x1 (LDS) -> FFN1 -> FFN2 + resid
// + LN2 -> d_out (main rows) ; pooled cls rows (+tanh) -> d_out[0:1024].
__global__ void __launch_bounds__(256)
attnout_ffn_kernel(const unsigned short* A, const unsigned short* Wao, const float* bao,
                   const float* resid, const float* g1, const float* b1ln,
                   const unsigned short* W1, const float* fb1,
                   const unsigned short* W2, const float* fb2,
                   const float* g2, const float* b2ln,
                   const float* pW, const float* pb, float* dout) {
    int m0 = blockIdx.x * 16;
    __shared__ unsigned short As[16][136];
    __shared__ float Xs[16][128];
    __shared__ unsigned short Hs[16][136];
    __shared__ float redS[4][4][4], redQ[4][4][4];
    __shared__ float smean[16], sinv[16];
    __shared__ float x2row[128];
    __shared__ int poolb;
    int tid = threadIdx.x;
    if (tid == 0) poolb = -1;
    {
        int r = tid >> 4, c0 = (tid & 15) * 8;
        *(ushortx8*)&As[r][c0] = *(const ushortx8*)(A + (size_t)(m0 + r) * 128 + c0);
    }
    __syncthreads();

    int wv = tid >> 6, lane = tid & 63;
    int am = lane & 15, aq = lane >> 4;
    int col = lane & 15, g = lane >> 4, rowb = g * 4;

    // --- attn-out MFMA + bias + resid ---
    float ov[2][4];
    {
        floatx4 acc0 = {0.f, 0.f, 0.f, 0.f}, acc1 = acc0;
        #pragma unroll
        for (int ks = 0; ks < 4; ++ks) {
            bf16x8 af = *(bf16x8*)&As[am][ks * 32 + aq * 8];
            const unsigned short* base = Wao + ((size_t)ks * 8 + 2 * wv) * 512 + lane * 8;
            bf16x8 bb0 = *(const bf16x8*)(base);
            bf16x8 bb1 = *(const bf16x8*)(base + 512);
            acc0 = __builtin_amdgcn_mfma_f32_16x16x32_bf16(af, bb0, acc0, 0, 0, 0);
            acc1 = __builtin_amdgcn_mfma_f32_16x16x32_bf16(af, bb1, acc1, 0, 0, 0);
        }
        #pragma unroll
        for (int t = 0; t < 2; ++t) {
            int n = wv * 32 + t * 16 + col;
            float bv = bao[n];
            floatx4 acc = t ? acc1 : acc0;
            #pragma unroll
            for (int rg = 0; rg < 4; ++rg)
                ov[t][rg] = acc[rg] + bv + resid[(size_t)(m0 + rowb + rg) * 128 + n];
        }
    }
    // --- LN1 ---
    #pragma unroll
    for (int rg = 0; rg < 4; ++rg) {
        float s = ov[0][rg] + ov[1][rg];
        float q = ov[0][rg] * ov[0][rg] + ov[1][rg] * ov[1][rg];
        #pragma unroll
        for (int off = 8; off >= 1; off >>= 1) {
            s += __shfl_xor(s, off);
            q += __shfl_xor(q, off);
        }
        if ((lane & 15) == 0) { redS[wv][g][rg] = s; redQ[wv][g][rg] = q; }
    }
    __syncthreads();
    if (tid < 16) {
        int gg = tid >> 2, rg = tid & 3;
        float s = redS[0][gg][rg] + redS[1][gg][rg] + redS[2][gg][rg] + redS[3][gg][rg];
        float q = redQ[0][gg][rg] + redQ[1][gg][rg] + redQ[2][gg][rg] + redQ[3][gg][rg];
        float mean = s * 0.0078125f;
        float var = q * 0.0078125f - mean * mean;
        smean[tid] = mean;
        sinv[tid] = rsqrtf(var + 1e-5f);
    }
    __syncthreads();
    #pragma unroll
    for (int t = 0; t < 2; ++t) {
        int n = wv * 32 + t * 16 + col;
        float gm = g1[n], bb = b1ln[n];
        #pragma unroll
        for (int rg = 0; rg < 4; ++rg) {
            int row = rowb + rg;
            float val = (ov[t][rg] - smean[row]) * sinv[row] * gm + bb;
            Xs[row][n] = val;
            As[row][n] = f2u(val);
        }
    }
    __syncthreads();

    // --- FFN1 -> Hs (relu bf16) ---
    {
        floatx4 acc0 = {0.f, 0.f, 0.f, 0.f}, acc1 = acc0;
        #pragma unroll
        for (int ks = 0; ks < 4; ++ks) {
            bf16x8 af = *(bf16x8*)&As[am][ks * 32 + aq * 8];
            const unsigned short* base = W1 + ((size_t)ks * 8 + 2 * wv) * 512 + lane * 8;
            bf16x8 bb0 = *(const bf16x8*)(base);
            bf16x8 bb1 = *(const bf16x8*)(base + 512);
            acc0 = __builtin_amdgcn_mfma_f32_16x16x32_bf16(af, bb0, acc0, 0, 0, 0);
            acc1 = __builtin_amdgcn_mfma_f32_16x16x32_bf16(af, bb1, acc1, 0, 0, 0);
        }
        #pragma unroll
        for (int t = 0; t < 2; ++t) {
            int n = wv * 32 + t * 16 + col;
            float bv = fb1[n];
            floatx4 acc = t ? acc1 : acc0;
            #pragma unroll
            for (int rg = 0; rg < 4; ++rg)
                Hs[rowb + rg][n] = f2u(fmaxf(acc[rg] + bv, 0.f));
        }
    }
    __syncthreads();

    // --- FFN2 + resid(Xs) + LN2 ---
    floatx4 acc0 = {0.f, 0.f, 0.f, 0.f}, acc1 = acc0;
    #pragma unroll
    for (int ks = 0; ks < 4; ++ks) {
        bf16x8 af = *(bf16x8*)&Hs[am][ks * 32 + aq * 8];
        const unsigned short* base = W2 + ((size_t)ks * 8 + 2 * wv) * 512 + lane * 8;
        bf16x8 bb0 = *(const bf16x8*)(base);
        bf16x8 bb1 = *(const bf16x8*)(base + 512);
        acc0 = __builtin_amdgcn_mfma_f32_16x16x32_bf16(af, bb0, acc0, 0, 0, 0);
        acc1 = __builtin_amdgcn_mfma_f32_16x16x32_bf16(af, bb1, acc1, 0, 0, 0);
    }
    #pragma unroll
    for (int t = 0; t < 2; ++t) {
        int n = wv * 32 + t * 16 + col;
        float bv = fb2[n];
        floatx4 acc = t ? acc1 : acc0;
        #pragma unroll
        for (int rg = 0; rg < 4; ++rg)
            ov[t][rg] = acc[rg] + bv + Xs[rowb + rg][n];
    }
    #pragma unroll
    for (int rg = 0; rg < 4; ++rg) {
        float s = ov[0][rg] + ov[1][rg];
        float q = ov[0][rg] * ov[0][rg] + ov[1][rg] * ov[1][rg];
        #pragma unroll
        for (int off = 8; off >= 1; off >>= 1) {
            s += __shfl_xor(s, off);
            q += __shfl_xor(q, off);
        }
        if ((lane & 15) == 0) { redS[wv][g][rg] = s; redQ[wv][g][rg] = q; }
    }
    __syncthreads();
    if (tid < 16) {
        int gg = tid >> 2, rg = tid & 3;
        float s = redS[0][gg][rg] + redS[1][gg][rg] + redS[2][gg][rg] + redS[3][gg][rg];
        float q = redQ[0][gg][rg] + redQ[1][gg][rg] + redQ[2][gg][rg] + redQ[3][gg][rg];
        float mean = s * 0.0078125f;
        float var = q * 0.0078125f - mean * mean;
        smean[tid] = mean;
        sinv[tid] = rsqrtf(var + 1e-5f);
    }
    __syncthreads();
    #pragma unroll
    for (int t = 0; t < 2; ++t) {
        int n = wv * 32 + t * 16 + col;
        float gm = g2[n], bb = b2ln[n];
        #pragma unroll
        for (int rg = 0; rg < 4; ++rg) {
            int row = rowb + rg;
            int m = m0 + row;
            float val = (ov[t][rg] - smean[row]) * sinv[row] * gm + bb;
            if (m < NM_) {
                int b = m / 513, r = m - b * 513;
                if (r >= 1)
                    dout[1024 + (size_t)b * 65536 + (size_t)(r - 1) * 128 + n] = val;
            } else {
                int mc = m - NM_;
                int b = mc / 129, r = mc - b * 129;
                if (r == 0) {
                    x2row[n] = val;
                    if (n == 0) poolb = b;
                }
            }
        }
    }
    __syncthreads();
    // --- pooling for the (<=1) cls row in this tile ---
    if (poolb >= 0 && tid < 128) {
        float acc = pb[tid];
        for (int k = 0; k < 128; ++k) acc = fmaf(x2row[k], pW[(size_t)k * 128 + tid], acc);
        dout[(size_t)poolb * 128 + tid] = tanhf(acc);
    }
}

// ---------------------------------------------------------------------------
// mta attention (unchanged from R13): full MFMA.
__global__ void __launch_bounds__(256)
mta_att_kernel(const unsigned short* qp_cls, const unsigned short* qp_main,
               const unsigned short* kp, const float* x,
               float* att_cls, float* att_mn) {
    int is_cls = (blockIdx.x >= 32);
    int qt = is_cls ? (blockIdx.x - 32) : blockIdx.x;
    int h = blockIdx.y, b = blockIdx.z;
    int tid = threadIdx.x, lane = tid & 63, wv = tid >> 6;
    __shared__ unsigned short Qs[16][72];
    __shared__ unsigned short KV[64][72];
    __shared__ unsigned short sp[16][520];
    __shared__ unsigned short Bt[16][520];
    float* xv = (float*)&KV[0][0];
    int q0 = qt * 16;

    if (tid < 128) {
        int r = tid >> 3, c0 = (tid & 7) * 8;
        const unsigned short* qrow = is_cls ? (qp_cls + (size_t)(q0 + r) * 128 + h * 64)
                                            : (qp_main + (size_t)(b * 512 + q0 + r) * 128 + h * 64);
        *(ushortx8*)&Qs[r][c0] = *(const ushortx8*)(qrow + c0);
    }
    __syncthreads();

    bf16x8 qf0, qf1;
    {
        int m = lane & 15, g = lane >> 4;
        qf0 = *(const bf16x8*)&Qs[m][g * 8];
        qf1 = *(const bf16x8*)&Qs[m][32 + g * 8];
    }

    for (int kt = 0; kt < 8; ++kt) {
        int k0 = kt * 64;
        {
            int kk = tid >> 3, e0 = (tid & 7) * 8;
            #pragma unroll
            for (int it = 0; it < 2; ++it, kk += 32)
                *(ushortx8*)&KV[kk][e0] =
                    *(const ushortx8*)(kp + (size_t)(b * 512 + k0 + kk) * 128 + h * 64 + e0);
        }
        __syncthreads();
        int kn = lane & 15, g = lane >> 4;
        floatx4 acc = {0.f, 0.f, 0.f, 0.f};
        {
            bf16x8 b0 = *(const bf16x8*)&KV[wv * 16 + kn][g * 8];
            acc = __builtin_amdgcn_mfma_f32_16x16x32_bf16(qf0, b0, acc, 0, 0, 0);
            bf16x8 b1 = *(const bf16x8*)&KV[wv * 16 + kn][32 + g * 8];
            acc = __builtin_amdgcn_mfma_f32_16x16x32_bf16(qf1, b1, acc, 0, 0, 0);
        }
        int colk = k0 + wv * 16 + kn;
        #pragma unroll
        for (int rg = 0; rg < 4; ++rg) sp[g * 4 + rg][colk] = f2u(acc[rg]);
        __syncthreads();
    }

    for (int rr = wv; rr < 16; rr += 4) {
        float m = -1e30f;
        for (int k = lane; k < 512; k += 64) m = fmaxf(m, u2f(sp[rr][k]));
        m = wave_reduce_max(m);
        for (int k = lane; k < 512; k += 64) sp[rr][k] = f2u(expf(u2f(sp[rr][k]) - m));
    }

    for (int kt = 0; kt < 8; ++kt) {
        int k0 = kt * 64;
        __syncthreads();
        {
            int kk = tid >> 2, c0 = (tid & 3) * 4;
            float4 v = *(const float4*)(x + (size_t)(b * 512 + k0 + kk) * 16 + c0);
            xv[kk * 17 + c0] = v.x; xv[kk * 17 + c0 + 1] = v.y;
            xv[kk * 17 + c0 + 2] = v.z; xv[kk * 17 + c0 + 3] = v.w;
        }
        __syncthreads();
        {
            int c = tid & 15, k4 = (tid >> 4) * 4;
            #pragma unroll
            for (int i = 0; i < 4; ++i) {
                int k = k4 + i;
                float val = (c < 8) ? xv[k * 17 + c] * xv[k * 17 + 8 + c]
                                    : xv[k * 17 + c];
                Bt[c][k0 + k] = f2u(val);
            }
        }
    }
    __syncthreads();

    floatx4 macc = {0.f, 0.f, 0.f, 0.f};
    {
        int mq = lane & 15, g = lane >> 4;
        #pragma unroll
        for (int cc = 0; cc < 4; ++cc) {
            int koff = (wv + cc * 4) * 32;
            bf16x8 af = *(const bf16x8*)&sp[mq][koff + g * 8];
            bf16x8 bfv = *(const bf16x8*)&Bt[mq][koff + g * 8];
            macc = __builtin_amdgcn_mfma_f32_16x16x32_bf16(af, bfv, macc, 0, 0, 0);
        }
    }
    float* redC = (float*)&KV[0][0];
    float* Cfull = redC + 1024;
    #pragma unroll
    for (int rg = 0; rg < 4; ++rg) redC[(wv * 64 + lane) * 4 + rg] = macc[rg];
    __syncthreads();
    {
        int l = tid >> 2, rg = tid & 3;
        float s = redC[l * 4 + rg] + redC[(64 + l) * 4 + rg]
                + redC[(128 + l) * 4 + rg] + redC[(192 + l) * 4 + rg];
        int row = (l >> 4) * 4 + rg, c = l & 15;
        Cfull[row * 16 + c] = s;
    }
    __syncthreads();
    if (tid < 128) {
        int r = tid >> 3, c = tid & 7;
        float num = Cfull[r * 16 + c];
        float den = Cfull[r * 16 + 8 + c];
        int row = q0 + r;
        float* dst = is_cls ? (att_cls + (size_t)(b * 128 + row) * 32)
                            : (att_mn + (size_t)(b * 512 + row) * 32);
        dst[h * 16 + c] = num / den;
        dst[h * 16 + 8 + c] = 1.0f;
    }
}

// ---------------------------------------------------------------------------
// tblock attention (unchanged from R13): bf16 in/out, MFMA QK^T + PV.
__global__ void __launch_bounds__(256)
tb_att_kernel(const unsigned short* qp, const unsigned short* kp,
              const unsigned short* vp, unsigned short* outp) {
    int is_cls = (blockIdx.x >= 33);
    int qt = is_cls ? blockIdx.x - 33 : blockIdx.x;
    int h = blockIdx.y, b = blockIdx.z;
    int Lq = is_cls ? 129 : 513;
    int base = is_cls ? (4104 + b * 129) : (b * 513);
    int nkt = is_cls ? 3 : 9;
    int tid = threadIdx.x, lane = tid & 63, wv = tid >> 6;
    __shared__ unsigned short Qs[16][72];
    __shared__ unsigned short KV[64][72];
    __shared__ unsigned short sp[16][588];
    __shared__ float rinv[16];
    int q0 = qt * 16;

    if (tid < 128) {
        int r = tid >> 3, c0 = (tid & 7) * 8;
        int qr = q0 + r;
        ushortx8 v = {0, 0, 0, 0, 0, 0, 0, 0};
        if (qr < Lq) v = *(const ushortx8*)(qp + (size_t)(base + qr) * 128 + h * 64 + c0);
        *(ushortx8*)&Qs[r][c0] = v;
    }
    __syncthreads();

    bf16x8 qf0, qf1;
    {
        int m = lane & 15, g = lane >> 4;
        qf0 = *(const bf16x8*)&Qs[m][g * 8];
        qf1 = *(const bf16x8*)&Qs[m][32 + g * 8];
    }

    for (int kt = 0; kt < nkt; ++kt) {
        int k0 = kt * 64;
        {
            int kk = tid >> 3, e0 = (tid & 7) * 8;
            #pragma unroll
            for (int it = 0; it < 2; ++it, kk += 32) {
                int krow = k0 + kk;
                ushortx8 v = {0, 0, 0, 0, 0, 0, 0, 0};
                if (krow < Lq) v = *(const ushortx8*)(kp + (size_t)(base + krow) * 128 + h * 64 + e0);
                *(ushortx8*)&KV[kk][e0] = v;
            }
        }
        __syncthreads();
        int kn = lane & 15, g = lane >> 4;
        floatx4 acc = {0.f, 0.f, 0.f, 0.f};
        {
            bf16x8 b0 = *(const bf16x8*)&KV[wv * 16 + kn][g * 8];
            acc = __builtin_amdgcn_mfma_f32_16x16x32_bf16(qf0, b0, acc, 0, 0, 0);
            bf16x8 b1 = *(const bf16x8*)&KV[wv * 16 + kn][32 + g * 8];
            acc = __builtin_amdgcn_mfma_f32_16x16x32_bf16(qf1, b1, acc, 0, 0, 0);
        }
        int colk = k0 + wv * 16 + kn;
        #pragma unroll
        for (int rg = 0; rg < 4; ++rg)
            sp[g * 4 + rg][colk] = f2u((colk < Lq) ? acc[rg] : -1e30f);
        __syncthreads();
    }

    int kend = nkt * 64;
    for (int rr = wv; rr < 16; rr += 4) {
        float m = -1e30f;
        for (int k = lane; k < kend; k += 64) m = fmaxf(m, u2f(sp[rr][k]));
        m = wave_reduce_max(m);
        float sum = 0.f;
        for (int k = lane; k < kend; k += 64) {
            float e = expf(u2f(sp[rr][k]) - m);
            sp[rr][k] = f2u(e);
            sum += e;
        }
        sum = wave_reduce_sum(sum);
        if (lane == 0) rinv[rr] = 1.f / sum;
    }

    floatx4 oacc = {0.f, 0.f, 0.f, 0.f};
    for (int kt = 0; kt < nkt; ++kt) {
        int k0 = kt * 64;
        __syncthreads();
        {
            int kk = tid & 31, e0 = (tid >> 5) * 8;
            #pragma unroll
            for (int it = 0; it < 2; ++it, kk += 32) {
                int krow = k0 + kk;
                ushortx8 v = {0, 0, 0, 0, 0, 0, 0, 0};
                if (krow < Lq) v = *(const ushortx8*)(vp + (size_t)(base + krow) * 128 + h * 64 + e0);
                #pragma unroll
                for (int j = 0; j < 8; ++j) KV[e0 + j][kk] = v[j];
            }
        }
        __syncthreads();
        int dn = lane & 15, g = lane >> 4;
        #pragma unroll
        for (int c = 0; c < 2; ++c) {
            bf16x4 plo = *(const bf16x4*)&sp[lane & 15][k0 + c * 32 + g * 8];
            bf16x4 phi = *(const bf16x4*)&sp[lane & 15][k0 + c * 32 + g * 8 + 4];
            bf16x8 vf = *(const bf16x8*)&KV[wv * 16 + dn][c * 32 + g * 8];
            oacc = __builtin_amdgcn_mfma_f32_16x16x32_bf16(join8(plo, phi), vf, oacc, 0, 0, 0);
        }
    }
    int dcol = wv * 16 + (lane & 15), g = lane >> 4;
    #pragma unroll
    for (int rg = 0; rg < 4; ++rg) {
        int q = g * 4 + rg;
        int qr = q0 + q;
        if (qr < Lq)
            outp[(size_t)(base + qr) * 128 + h * 64 + dcol] = f2u(oacc[rg] * rinv[q]);
    }
}

// ---------------------------------------------------------------------------
extern "C" void kernel_launch(void* const* d_in, const int* in_sizes, int n_in,
                              void* d_out, int out_size, void* d_ws, size_t ws_size,
                              hipStream_t stream) {
    float* w = (float*)d_ws;
    size_t off = 0;
    auto alloc = [&](size_t n) {
        float* p = w + off;
        off += (n + 3) & ~(size_t)3;
        return p;
    };
    auto allocU = [&](size_t n) { return (unsigned short*)alloc((n + 1) / 2); };

    PrepAll pa{};
    int nn = n_in < 32 ? n_in : 32;
    float* fin[32];
    const int needconv[32] = {1,0,0,0,0,0, 0,1, 0,1, 1,1, 1,1, 0,1, 0,1, 0,1,
                              0,1, 1,1, 0,1, 0,1, 1,1, 1,1};
    for (int i = 0; i < nn; ++i) {
        pa.src[i] = d_in[i];
        pa.n[i] = in_sizes[i];
        fin[i] = alloc(in_sizes[i]);
        pa.dstoff[i] = (int)(fin[i] - w);
        pa.conv[i] = needconv[i];
    }
    for (int i = nn; i < 32; ++i) { pa.src[i] = nullptr; pa.n[i] = 0; pa.dstoff[i] = 0; pa.conv[i] = 0; }

    const float* x       = fin[0];
    const float* bq_t    = fin[7];
    const float* bk_t    = fin[9];
    const float* Wo_t    = fin[10]; const float* bo_t = fin[11];
    const float* pos_emb = fin[12]; const float* cls_emb = fin[13];
    const float* tbq = fin[15]; const float* tbk = fin[17]; const float* tbv = fin[19];
    const float* tbo = fin[21];
    const float* ln1_g = fin[22]; const float* ln1_b = fin[23];
    const float* fb1 = fin[25]; const float* fb2 = fin[27];
    const float* ln2_g = fin[28]; const float* ln2_b = fin[29];
    const float* pW = fin[30]; const float* pb = fin[31];

    const int widx[8] = {8, 6, 14, 16, 18, 20, 24, 26};
    unsigned short* wsw[8];
    for (int i = 0; i < 8; ++i) {
        wsw[i] = allocU(16384);
        pa.wsrc[i] = d_in[widx[i]];
        pa.wdst[i] = wsw[i];
        pa.wscale[i] = (i == 1 || i == 2) ? 0.125f : 1.0f;
    }
    pa.ts = d_in[1]; pa.w_per = d_in[2]; pa.b_per = d_in[3];
    pa.w_lin = d_in[4]; pa.b_lin = d_in[5];
    pa.det = (const unsigned short*)d_in[22];

    unsigned short* key_e16 = allocU(4224 * 128);
    unsigned short* cls_e16 = key_e16 + 4096 * 128;
    pa.key_e16 = key_e16;

    unsigned short* qp_main16 = allocU(4096 * 128);
    unsigned short* kp_main16 = allocU(4096 * 128);
    unsigned short* qp_cls16  = allocU(128 * 128);
    float* att_all = alloc(5120 * 32);
    float* att_cls = att_all;
    float* att_mn  = att_all + 1024 * 32;
    float* xin     = alloc((size_t)NT_ * 128);
    unsigned short* tbq16 = allocU((size_t)NT_ * 128);
    unsigned short* tbk16 = allocU((size_t)NT_ * 128);
    unsigned short* tbv16 = allocU((size_t)NT_ * 128);
    unsigned short* tba16 = allocU((size_t)NT_ * 128);
    (void)ws_size;

    float* outf = (float*)d_out;

    // 1: convert + weight swizzle + time embedding
    prep_all_kernel<<<10848, 256, 0, stream>>>(pa, w);

    // 2: mta projections
    {
        GemmM p{};
        p.A[0] = key_e16; p.W[0] = wsw[0]; p.bias[0] = bk_t; p.C[0] = kp_main16;
        p.M[0] = 4096; p.bscale[0] = 1.f;
        p.A[1] = key_e16; p.W[1] = wsw[1]; p.bias[1] = bq_t; p.C[1] = qp_main16;
        p.M[1] = 4096; p.bscale[1] = 0.125f;
        p.A[2] = cls_e16; p.W[2] = wsw[1]; p.bias[2] = bq_t; p.C[2] = qp_cls16;
        p.M[2] = 128; p.bscale[2] = 0.125f;
        gemm_mfma_kernel<<<dim3(256, 3), 256, 0, stream>>>(p);
    }

    // 3: mta attention
    mta_att_kernel<<<dim3(40, 2, 8), 256, 0, stream>>>(qp_cls16, qp_main16, kp_main16,
                                                       x, att_cls, att_mn);

    // 4: mta-out + assemble + QKV (merged)
    mta_qkv_kernel<<<321, 256, 0, stream>>>(att_all, Wo_t, bo_t, cls_emb, pos_emb, xin,
                                            wsw[2], wsw[3], wsw[4], tbq, tbk, tbv,
                                            tbq16, tbk16, tbv16);

    // 5: tblock attention
    tb_att_kernel<<<dim3(42, 2, 8), 256, 0, stream>>>(tbq16, tbk16, tbv16, tba16);

    // 6: attn-out + LN1 + FFN + LN2 + pool (merged) -> d_out
    attnout_ffn_kernel<<<321, 256, 0, stream>>>(tba16, wsw[5], tbo, xin, ln1_g, ln1_b,
                                                wsw[6], fb1, wsw[7], fb2, ln2_g, ln2_b,
                                                pW, pb, outf);
}